// Round 1
// baseline (1970.409 us; speedup 1.0000x reference)
//
#include <hip/hip_runtime.h>
#include <hip/hip_bf16.h>
#include <math.h>

#define BB 8
#define NN 1024
#define FF 256
#define HH 8
#define OO 64
#define CC 256
#define NEGV -9e15f

// ---------- helpers ----------
__device__ __forceinline__ float lrelu(float v, float a) { return v > 0.f ? v : a * v; }

// ---------- x copy ----------
__global__ void k_copy(const float* __restrict__ src, float* __restrict__ dst) {
    int i = blockIdx.x * 256 + threadIdx.x;
    dst[i] = src[i];
}

// ---------- h = per-head projection: h[b,hd,n,o] = sum_f x[b,n,f] * Wa[hd,f,o]
__global__ void k_proj(const float* __restrict__ x, const float* __restrict__ Wa,
                       float* __restrict__ h) {
    int n = blockIdx.x, b = blockIdx.y, t = threadIdx.x;
    __shared__ float xs[FF];
    xs[t] = x[(size_t)(b * NN + n) * FF + t];
    __syncthreads();
    for (int c = t; c < HH * OO; c += 256) {
        int hd = c >> 6, o = c & 63;
        const float* W = Wa + (size_t)hd * FF * OO + o;
        float acc = 0.f;
#pragma unroll 8
        for (int f = 0; f < FF; ++f) acc += xs[f] * W[(size_t)f * OO];
        h[(((size_t)b * HH + hd) * NN + n) * OO + o] = acc;
    }
}

// ---------- f1/f2 dots: f1[b,hd,n] = h[b,hd,n,:] . a_att[hd,:64]
__global__ void k_fdots(const float* __restrict__ h, const float* __restrict__ aatt,
                        float* __restrict__ f1, float* __restrict__ f2) {
    int idx = blockIdx.x * 256 + threadIdx.x;  // (b*H+hd)*N + n
    int hd = (idx >> 10) & 7;
    const float* hr = h + (size_t)idx * OO;
    const float* a = aatt + hd * 2 * OO;
    float s1 = 0.f, s2 = 0.f;
#pragma unroll 8
    for (int o = 0; o < OO; ++o) {
        float v = hr[o];
        s1 += v * a[o];
        s2 += v * a[OO + o];
    }
    f1[idx] = s1;
    f2[idx] = s2;
}

// ---------- att softmax stats per (b,n) for all 8 heads ----------
__global__ void k_att_stats(const int* __restrict__ adj, const float* __restrict__ f1,
                            const float* __restrict__ f2, float* __restrict__ mx,
                            float* __restrict__ dn) {
    int n = blockIdx.x, b = blockIdx.y, t = threadIdx.x;
    int lane = t & 63, w = t >> 6;
    const int* arow = adj + ((size_t)b * NN + n) * NN;
    float fl[HH], m8[HH], s8[HH];
#pragma unroll
    for (int hd = 0; hd < HH; ++hd) {
        fl[hd] = f1[((size_t)b * HH + hd) * NN + n];
        m8[hd] = -3.4e38f;
        s8[hd] = 0.f;
    }
    for (int m = t; m < NN; m += 256) {
        int a = arow[m];
#pragma unroll
        for (int hd = 0; hd < HH; ++hd) {
            float v;
            if (a > 0) v = lrelu(fl[hd] + f2[((size_t)b * HH + hd) * NN + m], 0.2f);
            else v = NEGV;
            m8[hd] = fmaxf(m8[hd], v);
        }
    }
    __shared__ float red[4][HH];
#pragma unroll
    for (int hd = 0; hd < HH; ++hd)
        for (int off = 32; off; off >>= 1) m8[hd] = fmaxf(m8[hd], __shfl_xor(m8[hd], off));
    if (lane == 0)
        for (int hd = 0; hd < HH; ++hd) red[w][hd] = m8[hd];
    __syncthreads();
    float rm[HH];
#pragma unroll
    for (int hd = 0; hd < HH; ++hd)
        rm[hd] = fmaxf(fmaxf(red[0][hd], red[1][hd]), fmaxf(red[2][hd], red[3][hd]));
    __syncthreads();
    for (int m = t; m < NN; m += 256) {
        int a = arow[m];
#pragma unroll
        for (int hd = 0; hd < HH; ++hd) {
            float v;
            if (a > 0) v = lrelu(fl[hd] + f2[((size_t)b * HH + hd) * NN + m], 0.2f);
            else v = NEGV;
            s8[hd] += __expf(v - rm[hd]);
        }
    }
#pragma unroll
    for (int hd = 0; hd < HH; ++hd)
        for (int off = 32; off; off >>= 1) s8[hd] += __shfl_xor(s8[hd], off);
    if (lane == 0)
        for (int hd = 0; hd < HH; ++hd) red[w][hd] = s8[hd];
    __syncthreads();
    if (t < HH) {
        float sm = red[0][t] + red[1][t] + red[2][t] + red[3][t];
        mx[((size_t)b * HH + t) * NN + n] = rm[t];
        dn[((size_t)b * HH + t) * NN + n] = sm;
    }
}

// ---------- hp = elu(A @ h); y = lrelu(hp, 0.01), heads concatenated ----------
__global__ void k_att_pv(const int* __restrict__ adj, const float* __restrict__ f1,
                         const float* __restrict__ f2, const float* __restrict__ mx,
                         const float* __restrict__ dn, const float* __restrict__ h,
                         float* __restrict__ y) {
    int tile = blockIdx.x;          // n-tile, 16 rows
    int bh = blockIdx.y;            // b*H+hd
    int b = bh >> 3, hd = bh & 7;
    int t = threadIdx.x;
    int col = t & 63, r0 = t >> 6;
    __shared__ float As[16][64];
    __shared__ float hs[64][64];
    __shared__ float f1s[16], mxs[16], ids[16];
    int n0 = tile * 16;
    if (t < 16) {
        f1s[t] = f1[(size_t)bh * NN + n0 + t];
        mxs[t] = mx[(size_t)bh * NN + n0 + t];
        ids[t] = 1.0f / dn[(size_t)bh * NN + n0 + t];
    }
    __syncthreads();
    float acc[4] = {0.f, 0.f, 0.f, 0.f};
    const float* hbase = h + (size_t)bh * NN * OO;
    const float* f2b = f2 + (size_t)bh * NN;
    for (int m0 = 0; m0 < NN; m0 += 64) {
        for (int e = t; e < 16 * 64; e += 256) {
            int r = e >> 6, i = e & 63;
            int a = adj[(((size_t)b * NN) + n0 + r) * NN + m0 + i];
            float v = (a > 0) ? lrelu(f1s[r] + f2b[m0 + i], 0.2f) : NEGV;
            As[r][i] = __expf(v - mxs[r]) * ids[r];
        }
        for (int e = t; e < 64 * 64; e += 256) {
            int i = e >> 6, o = e & 63;
            hs[i][o] = hbase[(size_t)(m0 + i) * OO + o];
        }
        __syncthreads();
#pragma unroll
        for (int i = 0; i < 64; ++i) {
            float hv = hs[i][col];
            acc[0] += As[r0][i] * hv;
            acc[1] += As[r0 + 4][i] * hv;
            acc[2] += As[r0 + 8][i] * hv;
            acc[3] += As[r0 + 12][i] * hv;
        }
        __syncthreads();
    }
#pragma unroll
    for (int j = 0; j < 4; ++j) {
        int n = n0 + r0 + 4 * j;
        float v = acc[j];
        float e = v > 0.f ? v : expm1f(v);
        float yv = e > 0.f ? e : 0.01f * e;
        y[((size_t)b * NN + n) * (HH * OO) + hd * OO + col] = yv;
    }
}

// ---------- ho = y @ W_out, plus g1/g2 dots fused ----------
__global__ void k_outproj(const float* __restrict__ y, const float* __restrict__ Wo,
                          const float* __restrict__ ao, float* __restrict__ ho,
                          float* __restrict__ g1, float* __restrict__ g2) {
    int n = blockIdx.x, b = blockIdx.y, t = threadIdx.x;
    __shared__ float ys[512];
    ys[t] = y[((size_t)b * NN + n) * 512 + t];
    ys[t + 256] = y[((size_t)b * NN + n) * 512 + t + 256];
    __syncthreads();
    float acc = 0.f;
#pragma unroll 8
    for (int f = 0; f < 512; ++f) acc += ys[f] * Wo[(size_t)f * CC + t];
    ho[((size_t)b * NN + n) * CC + t] = acc;
    float p1 = acc * ao[t], p2 = acc * ao[CC + t];
    for (int off = 32; off; off >>= 1) {
        p1 += __shfl_xor(p1, off);
        p2 += __shfl_xor(p2, off);
    }
    __shared__ float r1[4], r2[4];
    int lane = t & 63, w = t >> 6;
    if (lane == 0) { r1[w] = p1; r2[w] = p2; }
    __syncthreads();
    if (t == 0) {
        g1[b * NN + n] = r1[0] + r1[1] + r1[2] + r1[3];
        g2[b * NN + n] = r2[0] + r2[1] + r2[2] + r2[3];
    }
}

// ---------- out-layer softmax stats ----------
__global__ void k_out_stats(const int* __restrict__ adj, const float* __restrict__ g1,
                            const float* __restrict__ g2, float* __restrict__ mxo,
                            float* __restrict__ dno) {
    int n = blockIdx.x, b = blockIdx.y, t = threadIdx.x;
    int lane = t & 63, w = t >> 6;
    const int* arow = adj + ((size_t)b * NN + n) * NN;
    float gl = g1[b * NN + n];
    float mm = -3.4e38f, ss = 0.f;
    for (int m = t; m < NN; m += 256) {
        int a = arow[m];
        float v = (a > 0) ? lrelu(gl + g2[b * NN + m], 0.2f) : NEGV;
        mm = fmaxf(mm, v);
    }
    for (int off = 32; off; off >>= 1) mm = fmaxf(mm, __shfl_xor(mm, off));
    __shared__ float red[4];
    if (lane == 0) red[w] = mm;
    __syncthreads();
    float rm = fmaxf(fmaxf(red[0], red[1]), fmaxf(red[2], red[3]));
    __syncthreads();
    for (int m = t; m < NN; m += 256) {
        int a = arow[m];
        float v = (a > 0) ? lrelu(gl + g2[b * NN + m], 0.2f) : NEGV;
        ss += __expf(v - rm);
    }
    for (int off = 32; off; off >>= 1) ss += __shfl_xor(ss, off);
    if (lane == 0) red[w] = ss;
    __syncthreads();
    if (t == 0) {
        mxo[b * NN + n] = rm;
        dno[b * NN + n] = red[0] + red[1] + red[2] + red[3];
    }
}

// ---------- t = x + elu(Ao @ ho) ----------
__global__ void k_out_pv(const int* __restrict__ adj, const float* __restrict__ g1,
                         const float* __restrict__ g2, const float* __restrict__ mxo,
                         const float* __restrict__ dno, const float* __restrict__ ho,
                         const float* __restrict__ xin, float* __restrict__ tout) {
    int tile = blockIdx.x;  // n-tile (16 rows)
    int ct = blockIdx.y;    // col-tile (64 cols)
    int b = blockIdx.z;
    int t = threadIdx.x;
    int col = t & 63, r0 = t >> 6;
    __shared__ float As[16][64];
    __shared__ float hs[64][64];
    __shared__ float g1s[16], mxs[16], ids[16];
    int n0 = tile * 16;
    if (t < 16) {
        g1s[t] = g1[(size_t)b * NN + n0 + t];
        mxs[t] = mxo[(size_t)b * NN + n0 + t];
        ids[t] = 1.0f / dno[(size_t)b * NN + n0 + t];
    }
    __syncthreads();
    float acc[4] = {0.f, 0.f, 0.f, 0.f};
    const float* g2b = g2 + (size_t)b * NN;
    for (int m0 = 0; m0 < NN; m0 += 64) {
        for (int e = t; e < 16 * 64; e += 256) {
            int r = e >> 6, i = e & 63;
            int a = adj[(((size_t)b * NN) + n0 + r) * NN + m0 + i];
            float v = (a > 0) ? lrelu(g1s[r] + g2b[m0 + i], 0.2f) : NEGV;
            As[r][i] = __expf(v - mxs[r]) * ids[r];
        }
        for (int e = t; e < 64 * 64; e += 256) {
            int i = e >> 6, o = e & 63;
            hs[i][o] = ho[((size_t)b * NN + m0 + i) * CC + ct * 64 + o];
        }
        __syncthreads();
#pragma unroll
        for (int i = 0; i < 64; ++i) {
            float hv = hs[i][col];
            acc[0] += As[r0][i] * hv;
            acc[1] += As[r0 + 4][i] * hv;
            acc[2] += As[r0 + 8][i] * hv;
            acc[3] += As[r0 + 12][i] * hv;
        }
        __syncthreads();
    }
#pragma unroll
    for (int j = 0; j < 4; ++j) {
        int n = n0 + r0 + 4 * j;
        float v = acc[j];
        float e = v > 0.f ? v : expm1f(v);
        size_t idx = ((size_t)b * NN + n) * CC + ct * 64 + col;
        tout[idx] = xin[idx] + e;
    }
}

// ---------- mask + layernorm ----------
__global__ void k_mask_ln(const float* __restrict__ tin, const int* __restrict__ mask,
                          const float* __restrict__ lw, const float* __restrict__ lb,
                          float* __restrict__ xout) {
    int n = blockIdx.x, b = blockIdx.y, t = threadIdx.x;
    int lane = t & 63, w = t >> 6;
    float v = (mask[b * NN + n] == 0) ? 0.f : tin[((size_t)b * NN + n) * CC + t];
    __shared__ float r1[4], r2[4];
    float s = v;
    for (int off = 32; off; off >>= 1) s += __shfl_xor(s, off);
    if (lane == 0) r1[w] = s;
    __syncthreads();
    float mu = (r1[0] + r1[1] + r1[2] + r1[3]) * (1.0f / CC);
    float d = v - mu;
    float q = d * d;
    for (int off = 32; off; off >>= 1) q += __shfl_xor(q, off);
    if (lane == 0) r2[w] = q;
    __syncthreads();
    float var = (r2[0] + r2[1] + r2[2] + r2[3]) * (1.0f / CC);
    xout[((size_t)b * NN + n) * CC + t] = d * rsqrtf(var + 1e-5f) * lw[t] + lb[t];
}

// ---------- final relu outputs ----------
__global__ void k_relu_out(const float* __restrict__ xb, float* __restrict__ out) {
    int idx = blockIdx.x * 256 + threadIdx.x;
    float v = xb[idx];
    v = v > 0.f ? v : 0.f;
    out[idx] = v;
    int c = idx & 255;
    int bn = idx >> 8;
    int n = bn & 1023;
    int b = bn >> 10;
    if (n == 0) out[(size_t)BB * NN * CC + b * CC + c] = v;
}

extern "C" void kernel_launch(void* const* d_in, const int* in_sizes, int n_in,
                              void* d_out, int out_size, void* d_ws, size_t ws_size,
                              hipStream_t stream) {
    const float* x = (const float*)d_in[0];
    const int* adj = (const int*)d_in[1];
    const int* mask = (const int*)d_in[2];
    const float* W_att = (const float*)d_in[3];
    const float* a_att = (const float*)d_in[4];
    const float* W_out = (const float*)d_in[5];
    const float* a_out = (const float*)d_in[6];
    const float* ln_w = (const float*)d_in[7];
    const float* ln_b = (const float*)d_in[8];
    float* out = (float*)d_out;

    float* ws = (float*)d_ws;
    float* xbuf = ws;                         // 2,097,152
    float* h    = xbuf + 2097152;             // 4,194,304
    float* f1   = h + 4194304;                // 65,536
    float* f2   = f1 + 65536;                 // 65,536
    float* mx   = f2 + 65536;                 // 65,536
    float* dn   = mx + 65536;                 // 65,536
    float* y    = dn + 65536;                 // 4,194,304 (t aliases this)
    float* tbuf = y;
    float* ho   = y + 4194304;                // 2,097,152
    float* g1   = ho + 2097152;               // 8,192
    float* g2   = g1 + 8192;                  // 8,192
    float* mxo  = g2 + 8192;                  // 8,192
    float* dno  = mxo + 8192;                 // 8,192

    k_copy<<<8192, 256, 0, stream>>>(x, xbuf);

    for (int layer = 0; layer < 2; ++layer) {
        k_proj<<<dim3(NN, BB), 256, 0, stream>>>(xbuf, W_att, h);
        k_fdots<<<256, 256, 0, stream>>>(h, a_att, f1, f2);
        k_att_stats<<<dim3(NN, BB), 256, 0, stream>>>(adj, f1, f2, mx, dn);
        k_att_pv<<<dim3(NN / 16, BB * HH), 256, 0, stream>>>(adj, f1, f2, mx, dn, h, y);
        k_outproj<<<dim3(NN, BB), 256, 0, stream>>>(y, W_out, a_out, ho, g1, g2);
        k_out_stats<<<dim3(NN, BB), 256, 0, stream>>>(adj, g1, g2, mxo, dno);
        k_out_pv<<<dim3(NN / 16, CC / 64, BB), 256, 0, stream>>>(adj, g1, g2, mxo, dno, ho,
                                                                 xbuf, tbuf);
        k_mask_ln<<<dim3(NN, BB), 256, 0, stream>>>(tbuf, mask, ln_w, ln_b, xbuf);
    }
    k_relu_out<<<8192, 256, 0, stream>>>(xbuf, out);
}

// Round 2
// 1166.950 us; speedup vs baseline: 1.6885x; 1.6885x over previous
//
#include <hip/hip_runtime.h>
#include <hip/hip_bf16.h>
#include <math.h>

#define BB 8
#define NN 1024
#define FF 256
#define HH 8
#define OO 64
#define CC 256
#define NEGV -9e15f

typedef __attribute__((ext_vector_type(8))) short short8;
typedef __attribute__((ext_vector_type(4))) float f32x4;

// ---------- helpers ----------
__device__ __forceinline__ float lrelu(float v, float a) { return v > 0.f ? v : a * v; }

// ---------- x copy ----------
__global__ void k_copy(const float* __restrict__ src, float* __restrict__ dst) {
    int i = blockIdx.x * 256 + threadIdx.x;
    dst[i] = src[i];
}

// ---------- h = per-head projection: h[b,hd,n,o] = sum_f x[b,n,f] * Wa[hd,f,o]
__global__ void k_proj(const float* __restrict__ x, const float* __restrict__ Wa,
                       float* __restrict__ h) {
    int n = blockIdx.x, b = blockIdx.y, t = threadIdx.x;
    __shared__ float xs[FF];
    xs[t] = x[(size_t)(b * NN + n) * FF + t];
    __syncthreads();
    for (int c = t; c < HH * OO; c += 256) {
        int hd = c >> 6, o = c & 63;
        const float* W = Wa + (size_t)hd * FF * OO + o;
        float acc = 0.f;
#pragma unroll 8
        for (int f = 0; f < FF; ++f) acc += xs[f] * W[(size_t)f * OO];
        h[(((size_t)b * HH + hd) * NN + n) * OO + o] = acc;
    }
}

// ---------- f1/f2 dots ----------
__global__ void k_fdots(const float* __restrict__ h, const float* __restrict__ aatt,
                        float* __restrict__ f1, float* __restrict__ f2) {
    int idx = blockIdx.x * 256 + threadIdx.x;  // (b*H+hd)*N + n
    int hd = (idx >> 10) & 7;
    const float* hr = h + (size_t)idx * OO;
    const float* a = aatt + hd * 2 * OO;
    float s1 = 0.f, s2 = 0.f;
#pragma unroll 8
    for (int o = 0; o < OO; ++o) {
        float v = hr[o];
        s1 += v * a[o];
        s2 += v * a[OO + o];
    }
    f1[idx] = s1;
    f2[idx] = s2;
}

// ---------- transpose+convert h[bh][n][o] -> hT[bh][o][n] bf16 ----------
__global__ void k_h2bft(const float* __restrict__ h, __hip_bfloat16* __restrict__ hT) {
    int n0 = blockIdx.x * 64;
    int bh = blockIdx.y;
    int t = threadIdx.x;
    __shared__ float tile[64][65];
    const float* src = h + (size_t)bh * NN * OO;
    for (int e = t; e < 4096; e += 256) {
        int i = e >> 6, o = e & 63;
        tile[i][o] = src[(size_t)(n0 + i) * OO + o];
    }
    __syncthreads();
    __hip_bfloat16* dst = hT + (size_t)bh * OO * NN;
    for (int e = t; e < 4096; e += 256) {
        int o = e >> 6, i = e & 63;
        dst[(size_t)o * NN + n0 + i] = __float2bfloat16(tile[i][o]);
    }
}

// ---------- transpose+convert ho[b][n][c] -> hoT[b][c][n] bf16 ----------
__global__ void k_ho2bft(const float* __restrict__ ho, __hip_bfloat16* __restrict__ hoT) {
    int n0 = blockIdx.x * 64;
    int c0 = blockIdx.y * 64;
    int b = blockIdx.z;
    int t = threadIdx.x;
    __shared__ float tile[64][65];
    for (int e = t; e < 4096; e += 256) {
        int i = e >> 6, o = e & 63;
        tile[i][o] = ho[((size_t)(b * NN + n0 + i)) * CC + c0 + o];
    }
    __syncthreads();
    for (int e = t; e < 4096; e += 256) {
        int o = e >> 6, i = e & 63;
        hoT[((size_t)b * CC + c0 + o) * NN + n0 + i] = __float2bfloat16(tile[i][o]);
    }
}

// ---------- att softmax stats per (b,n) for all 8 heads ----------
__global__ void k_att_stats(const int* __restrict__ adj, const float* __restrict__ f1,
                            const float* __restrict__ f2, float* __restrict__ mx,
                            float* __restrict__ dn) {
    int n = blockIdx.x, b = blockIdx.y, t = threadIdx.x;
    int lane = t & 63, w = t >> 6;
    const int* arow = adj + ((size_t)b * NN + n) * NN;
    float fl[HH], m8[HH], s8[HH];
#pragma unroll
    for (int hd = 0; hd < HH; ++hd) {
        fl[hd] = f1[((size_t)b * HH + hd) * NN + n];
        m8[hd] = -3.4e38f;
        s8[hd] = 0.f;
    }
    for (int m = t; m < NN; m += 256) {
        int a = arow[m];
#pragma unroll
        for (int hd = 0; hd < HH; ++hd) {
            float v;
            if (a > 0) v = lrelu(fl[hd] + f2[((size_t)b * HH + hd) * NN + m], 0.2f);
            else v = NEGV;
            m8[hd] = fmaxf(m8[hd], v);
        }
    }
    __shared__ float red[4][HH];
#pragma unroll
    for (int hd = 0; hd < HH; ++hd)
        for (int off = 32; off; off >>= 1) m8[hd] = fmaxf(m8[hd], __shfl_xor(m8[hd], off));
    if (lane == 0)
        for (int hd = 0; hd < HH; ++hd) red[w][hd] = m8[hd];
    __syncthreads();
    float rm[HH];
#pragma unroll
    for (int hd = 0; hd < HH; ++hd)
        rm[hd] = fmaxf(fmaxf(red[0][hd], red[1][hd]), fmaxf(red[2][hd], red[3][hd]));
    __syncthreads();
    for (int m = t; m < NN; m += 256) {
        int a = arow[m];
#pragma unroll
        for (int hd = 0; hd < HH; ++hd) {
            float v;
            if (a > 0) v = lrelu(fl[hd] + f2[((size_t)b * HH + hd) * NN + m], 0.2f);
            else v = NEGV;
            s8[hd] += __expf(v - rm[hd]);
        }
    }
#pragma unroll
    for (int hd = 0; hd < HH; ++hd)
        for (int off = 32; off; off >>= 1) s8[hd] += __shfl_xor(s8[hd], off);
    if (lane == 0)
        for (int hd = 0; hd < HH; ++hd) red[w][hd] = s8[hd];
    __syncthreads();
    if (t < HH) {
        float sm = red[0][t] + red[1][t] + red[2][t] + red[3][t];
        mx[((size_t)b * HH + t) * NN + n] = rm[t];
        dn[((size_t)b * HH + t) * NN + n] = sm;
    }
}

// ---------- MFMA: y = lrelu(elu(A @ h), 0.01), heads concatenated ----------
__global__ void k_att_pv_mfma(const int* __restrict__ adj, const float* __restrict__ f1,
                              const float* __restrict__ f2, const float* __restrict__ mx,
                              const float* __restrict__ dn,
                              const __hip_bfloat16* __restrict__ hT,
                              float* __restrict__ y) {
    int n0 = blockIdx.x * 16;
    int bh = blockIdx.y;
    int b = bh >> 3, hd = bh & 7;
    int t = threadIdx.x, lane = t & 63, w = t >> 6;
    __shared__ __align__(16) __hip_bfloat16 As[16][72];
    __shared__ float f1s[16], mxs[16], ids[16];
    if (t < 16) {
        f1s[t] = f1[(size_t)bh * NN + n0 + t];
        mxs[t] = mx[(size_t)bh * NN + n0 + t];
        ids[t] = 1.0f / dn[(size_t)bh * NN + n0 + t];
    }
    __syncthreads();
    f32x4 acc = {0.f, 0.f, 0.f, 0.f};
    const float* f2b = f2 + (size_t)bh * NN;
    const __hip_bfloat16* hb = hT + ((size_t)bh * OO + w * 16 + (lane & 15)) * NN;
    const int* adjb = adj + (size_t)b * NN * NN;
    int ar = lane & 15;
    int ak = (lane >> 4) * 8;
    for (int k0 = 0; k0 < NN; k0 += 64) {
        for (int e = t; e < 1024; e += 256) {
            int r = e >> 6, i = e & 63;
            int a = adjb[(size_t)(n0 + r) * NN + k0 + i];
            float v = (a > 0) ? lrelu(f1s[r] + f2b[k0 + i], 0.2f) : NEGV;
            As[r][i] = __float2bfloat16(__expf(v - mxs[r]) * ids[r]);
        }
        __syncthreads();
        short8 a0 = *(const short8*)&As[ar][ak];
        short8 b0 = *(const short8*)&hb[k0 + ak];
        acc = __builtin_amdgcn_mfma_f32_16x16x32_bf16(a0, b0, acc, 0, 0, 0);
        short8 a1 = *(const short8*)&As[ar][32 + ak];
        short8 b1 = *(const short8*)&hb[k0 + 32 + ak];
        acc = __builtin_amdgcn_mfma_f32_16x16x32_bf16(a1, b1, acc, 0, 0, 0);
        __syncthreads();
    }
    int col = w * 16 + (lane & 15);
    int rbase = (lane >> 4) * 4;
#pragma unroll
    for (int r = 0; r < 4; ++r) {
        int n = n0 + rbase + r;
        float v = acc[r];
        float e = v > 0.f ? v : expm1f(v);
        float yv = e > 0.f ? e : 0.01f * e;
        y[((size_t)b * NN + n) * (HH * OO) + hd * OO + col] = yv;
    }
}

// ---------- ho = y @ W_out, plus g1/g2 dots fused ----------
__global__ void k_outproj(const float* __restrict__ y, const float* __restrict__ Wo,
                          const float* __restrict__ ao, float* __restrict__ ho,
                          float* __restrict__ g1, float* __restrict__ g2) {
    int n = blockIdx.x, b = blockIdx.y, t = threadIdx.x;
    __shared__ float ys[512];
    ys[t] = y[((size_t)b * NN + n) * 512 + t];
    ys[t + 256] = y[((size_t)b * NN + n) * 512 + t + 256];
    __syncthreads();
    float acc = 0.f;
#pragma unroll 8
    for (int f = 0; f < 512; ++f) acc += ys[f] * Wo[(size_t)f * CC + t];
    ho[((size_t)b * NN + n) * CC + t] = acc;
    float p1 = acc * ao[t], p2 = acc * ao[CC + t];
    for (int off = 32; off; off >>= 1) {
        p1 += __shfl_xor(p1, off);
        p2 += __shfl_xor(p2, off);
    }
    __shared__ float r1[4], r2[4];
    int lane = t & 63, w = t >> 6;
    if (lane == 0) { r1[w] = p1; r2[w] = p2; }
    __syncthreads();
    if (t == 0) {
        g1[b * NN + n] = r1[0] + r1[1] + r1[2] + r1[3];
        g2[b * NN + n] = r2[0] + r2[1] + r2[2] + r2[3];
    }
}

// ---------- out-layer softmax stats ----------
__global__ void k_out_stats(const int* __restrict__ adj, const float* __restrict__ g1,
                            const float* __restrict__ g2, float* __restrict__ mxo,
                            float* __restrict__ dno) {
    int n = blockIdx.x, b = blockIdx.y, t = threadIdx.x;
    int lane = t & 63, w = t >> 6;
    const int* arow = adj + ((size_t)b * NN + n) * NN;
    float gl = g1[b * NN + n];
    float mm = -3.4e38f, ss = 0.f;
    for (int m = t; m < NN; m += 256) {
        int a = arow[m];
        float v = (a > 0) ? lrelu(gl + g2[b * NN + m], 0.2f) : NEGV;
        mm = fmaxf(mm, v);
    }
    for (int off = 32; off; off >>= 1) mm = fmaxf(mm, __shfl_xor(mm, off));
    __shared__ float red[4];
    if (lane == 0) red[w] = mm;
    __syncthreads();
    float rm = fmaxf(fmaxf(red[0], red[1]), fmaxf(red[2], red[3]));
    __syncthreads();
    for (int m = t; m < NN; m += 256) {
        int a = arow[m];
        float v = (a > 0) ? lrelu(gl + g2[b * NN + m], 0.2f) : NEGV;
        ss += __expf(v - rm);
    }
    for (int off = 32; off; off >>= 1) ss += __shfl_xor(ss, off);
    if (lane == 0) red[w] = ss;
    __syncthreads();
    if (t == 0) {
        mxo[b * NN + n] = rm;
        dno[b * NN + n] = red[0] + red[1] + red[2] + red[3];
    }
}

// ---------- MFMA: t = x + elu(Ao @ ho) ----------
__global__ void k_out_pv_mfma(const int* __restrict__ adj, const float* __restrict__ g1,
                              const float* __restrict__ g2, const float* __restrict__ mxo,
                              const float* __restrict__ dno,
                              const __hip_bfloat16* __restrict__ hoT,
                              const float* __restrict__ xin, float* __restrict__ tout) {
    int n0 = blockIdx.x * 16;
    int half = blockIdx.y;  // 0/1: cols half*128 .. +128
    int b = blockIdx.z;
    int t = threadIdx.x, lane = t & 63, w = t >> 6;
    __shared__ __align__(16) __hip_bfloat16 As[16][72];
    __shared__ float g1s[16], mxs[16], ids[16];
    if (t < 16) {
        g1s[t] = g1[(size_t)b * NN + n0 + t];
        mxs[t] = mxo[(size_t)b * NN + n0 + t];
        ids[t] = 1.0f / dno[(size_t)b * NN + n0 + t];
    }
    __syncthreads();
    f32x4 acc0 = {0.f, 0.f, 0.f, 0.f}, acc1 = {0.f, 0.f, 0.f, 0.f};
    const float* g2b = g2 + (size_t)b * NN;
    int colbase = half * 128 + w * 32;
    const __hip_bfloat16* h0 = hoT + ((size_t)b * CC + colbase + (lane & 15)) * NN;
    const __hip_bfloat16* h1 = h0 + (size_t)16 * NN;
    const int* adjb = adj + (size_t)b * NN * NN;
    int ar = lane & 15;
    int ak = (lane >> 4) * 8;
    for (int k0 = 0; k0 < NN; k0 += 64) {
        for (int e = t; e < 1024; e += 256) {
            int r = e >> 6, i = e & 63;
            int a = adjb[(size_t)(n0 + r) * NN + k0 + i];
            float v = (a > 0) ? lrelu(g1s[r] + g2b[k0 + i], 0.2f) : NEGV;
            As[r][i] = __float2bfloat16(__expf(v - mxs[r]) * ids[r]);
        }
        __syncthreads();
#pragma unroll
        for (int kk = 0; kk < 64; kk += 32) {
            short8 a = *(const short8*)&As[ar][kk + ak];
            short8 bv0 = *(const short8*)&h0[k0 + kk + ak];
            short8 bv1 = *(const short8*)&h1[k0 + kk + ak];
            acc0 = __builtin_amdgcn_mfma_f32_16x16x32_bf16(a, bv0, acc0, 0, 0, 0);
            acc1 = __builtin_amdgcn_mfma_f32_16x16x32_bf16(a, bv1, acc1, 0, 0, 0);
        }
        __syncthreads();
    }
    int rbase = (lane >> 4) * 4;
#pragma unroll
    for (int r = 0; r < 4; ++r) {
        int n = n0 + rbase + r;
        size_t rowo = ((size_t)b * NN + n) * CC;
        int c0 = colbase + (lane & 15);
        float v0 = acc0[r];
        float e0 = v0 > 0.f ? v0 : expm1f(v0);
        tout[rowo + c0] = xin[rowo + c0] + e0;
        float v1 = acc1[r];
        float e1 = v1 > 0.f ? v1 : expm1f(v1);
        tout[rowo + c0 + 16] = xin[rowo + c0 + 16] + e1;
    }
}

// ---------- mask + layernorm ----------
__global__ void k_mask_ln(const float* __restrict__ tin, const int* __restrict__ mask,
                          const float* __restrict__ lw, const float* __restrict__ lb,
                          float* __restrict__ xout) {
    int n = blockIdx.x, b = blockIdx.y, t = threadIdx.x;
    int lane = t & 63, w = t >> 6;
    float v = (mask[b * NN + n] == 0) ? 0.f : tin[((size_t)b * NN + n) * CC + t];
    __shared__ float r1[4], r2[4];
    float s = v;
    for (int off = 32; off; off >>= 1) s += __shfl_xor(s, off);
    if (lane == 0) r1[w] = s;
    __syncthreads();
    float mu = (r1[0] + r1[1] + r1[2] + r1[3]) * (1.0f / CC);
    float d = v - mu;
    float q = d * d;
    for (int off = 32; off; off >>= 1) q += __shfl_xor(q, off);
    if (lane == 0) r2[w] = q;
    __syncthreads();
    float var = (r2[0] + r2[1] + r2[2] + r2[3]) * (1.0f / CC);
    xout[((size_t)b * NN + n) * CC + t] = d * rsqrtf(var + 1e-5f) * lw[t] + lb[t];
}

// ---------- final relu outputs ----------
__global__ void k_relu_out(const float* __restrict__ xb, float* __restrict__ out) {
    int idx = blockIdx.x * 256 + threadIdx.x;
    float v = xb[idx];
    v = v > 0.f ? v : 0.f;
    out[idx] = v;
    int c = idx & 255;
    int bn = idx >> 8;
    int n = bn & 1023;
    int b = bn >> 10;
    if (n == 0) out[(size_t)BB * NN * CC + b * CC + c] = v;
}

extern "C" void kernel_launch(void* const* d_in, const int* in_sizes, int n_in,
                              void* d_out, int out_size, void* d_ws, size_t ws_size,
                              hipStream_t stream) {
    const float* x = (const float*)d_in[0];
    const int* adj = (const int*)d_in[1];
    const int* mask = (const int*)d_in[2];
    const float* W_att = (const float*)d_in[3];
    const float* a_att = (const float*)d_in[4];
    const float* W_out = (const float*)d_in[5];
    const float* a_out = (const float*)d_in[6];
    const float* ln_w = (const float*)d_in[7];
    const float* ln_b = (const float*)d_in[8];
    float* out = (float*)d_out;

    float* ws = (float*)d_ws;
    float* xbuf = ws;                         // 2,097,152
    float* h    = xbuf + 2097152;             // 4,194,304
    float* f1   = h + 4194304;                // 65,536
    float* f2   = f1 + 65536;                 // 65,536
    float* mx   = f2 + 65536;                 // 65,536
    float* dn   = mx + 65536;                 // 65,536
    float* y    = dn + 65536;                 // 4,194,304 (tbuf aliases this)
    float* tbuf = y;
    float* ho   = y + 4194304;                // 2,097,152
    float* g1   = ho + 2097152;               // 8,192
    float* g2   = g1 + 8192;                  // 8,192
    float* mxo  = g2 + 8192;                  // 8,192
    float* dno  = mxo + 8192;                 // 8,192

    // bf16 transposed copies alias dead f32 regions (lifetimes verified):
    //  hbfT (8 MB) lives in ho's region: used before k_outproj writes ho.
    //  hoT (4 MB) lives in h's region: h is dead after k_h2bft.
    __hip_bfloat16* hbfT = (__hip_bfloat16*)ho;
    __hip_bfloat16* hoT  = (__hip_bfloat16*)h;

    k_copy<<<8192, 256, 0, stream>>>(x, xbuf);

    for (int layer = 0; layer < 2; ++layer) {
        k_proj<<<dim3(NN, BB), 256, 0, stream>>>(xbuf, W_att, h);
        k_fdots<<<256, 256, 0, stream>>>(h, a_att, f1, f2);
        k_h2bft<<<dim3(16, BB * HH), 256, 0, stream>>>(h, hbfT);
        k_att_stats<<<dim3(NN, BB), 256, 0, stream>>>(adj, f1, f2, mx, dn);
        k_att_pv_mfma<<<dim3(NN / 16, BB * HH), 256, 0, stream>>>(adj, f1, f2, mx, dn,
                                                                  hbfT, y);
        k_outproj<<<dim3(NN, BB), 256, 0, stream>>>(y, W_out, a_out, ho, g1, g2);
        k_ho2bft<<<dim3(16, 4, BB), 256, 0, stream>>>(ho, hoT);
        k_out_stats<<<dim3(NN, BB), 256, 0, stream>>>(adj, g1, g2, mxo, dno);
        k_out_pv_mfma<<<dim3(NN / 16, 2, BB), 256, 0, stream>>>(adj, g1, g2, mxo, dno,
                                                                hoT, xbuf, tbuf);
        k_mask_ln<<<dim3(NN, BB), 256, 0, stream>>>(tbuf, mask, ln_w, ln_b, xbuf);
    }
    k_relu_out<<<8192, 256, 0, stream>>>(xbuf, out);
}

// Round 4
// 685.077 us; speedup vs baseline: 2.8762x; 1.7034x over previous
//
#include <hip/hip_runtime.h>
#include <hip/hip_bf16.h>
#include <math.h>

#define BB 8
#define NN 1024
#define FF 256
#define HH 8
#define OO 64
#define CC 256
#define NEGV -9e15f

typedef __attribute__((ext_vector_type(8))) short short8;
typedef __attribute__((ext_vector_type(4))) float f32x4;

__device__ __forceinline__ float lrelu(float v, float a) { return v > 0.f ? v : a * v; }

__device__ __forceinline__ short bf16s(float f) {
    __hip_bfloat16 h = __float2bfloat16(f);
    return *reinterpret_cast<short*>(&h);
}

// ---------- x copy ----------
__global__ void k_copy(const float* __restrict__ src, float* __restrict__ dst) {
    int i = blockIdx.x * 256 + threadIdx.x;
    dst[i] = src[i];
}

// ---------- one-time weight transpose+convert ----------
// WaT[hd][o][f] = bf16(W_att[hd][f][o]);  WoT[c][k] = bf16(W_out[k][c])
__global__ void k_wprep(const float* __restrict__ Wa, const float* __restrict__ Wo,
                        __hip_bfloat16* __restrict__ WaT, __hip_bfloat16* __restrict__ WoT) {
    int i = blockIdx.x * 256 + threadIdx.x;  // 0..262143
    if (i < 131072) {
        int hd = i >> 14, o = (i >> 8) & 63, f = i & 255;
        WaT[i] = __float2bfloat16(Wa[hd * 16384 + f * 64 + o]);
    } else {
        int j = i - 131072;
        int c = j >> 9, k = j & 511;
        WoT[j] = __float2bfloat16(Wo[k * 256 + c]);
    }
}

// ---------- MFMA proj: h = x @ W_att (per head), fused f1/f2 + bf16 hT write ----
// grid (128 row-tiles, 8 heads), 256 thr. Wave w: rows tile*64 + w*16 .. +15, all 64 cols.
__global__ void k_proj_mfma(const float* __restrict__ x,
                            const __hip_bfloat16* __restrict__ WaT,
                            const float* __restrict__ aatt,
                            __hip_bfloat16* __restrict__ hT,
                            float* __restrict__ f1, float* __restrict__ f2) {
    int tile = blockIdx.x, hd = blockIdx.y;
    int t = threadIdx.x, lane = t & 63, w = t >> 6;
    int r0 = tile * 64;          // global row base (b*NN+n)
    int b = r0 >> 10;
    int n0 = r0 & 1023;
    int bh = b * HH + hd;
    int al = lane & 15, ah = lane >> 4;
    const float* xrow = x + (size_t)(r0 + w * 16 + al) * FF;
    const __hip_bfloat16* Wb = WaT + (size_t)hd * OO * FF;
    f32x4 z4 = {0.f, 0.f, 0.f, 0.f};
    f32x4 acc[4] = {z4, z4, z4, z4};
    for (int k0 = 0; k0 < FF; k0 += 32) {
        int k = k0 + ah * 8;
        short8 af;
#pragma unroll
        for (int q = 0; q < 8; ++q) af[q] = bf16s(xrow[k + q]);
#pragma unroll
        for (int cf = 0; cf < 4; ++cf) {
            int col = cf * 16 + al;
            short8 bf = *(const short8*)&Wb[(size_t)col * FF + k];
            acc[cf] = __builtin_amdgcn_mfma_f32_16x16x32_bf16(af, bf, acc[cf], 0, 0, 0);
        }
    }
    // write hT[bh][o][n] bf16
    int nb = n0 + w * 16 + ah * 4;  // row base for this lane's D rows
#pragma unroll
    for (int cf = 0; cf < 4; ++cf) {
        int col = cf * 16 + al;
        __hip_bfloat16* dst = hT + ((size_t)bh * OO + col) * NN + nb;
#pragma unroll
        for (int r = 0; r < 4; ++r) dst[r] = __float2bfloat16(acc[cf][r]);
    }
    // fused f1/f2: reduce acc * a_att over the 64 cols
    float p1[4] = {0.f, 0.f, 0.f, 0.f}, p2[4] = {0.f, 0.f, 0.f, 0.f};
#pragma unroll
    for (int cf = 0; cf < 4; ++cf) {
        int col = cf * 16 + al;
        float a1 = aatt[hd * 2 * OO + col];
        float a2 = aatt[hd * 2 * OO + OO + col];
#pragma unroll
        for (int r = 0; r < 4; ++r) {
            p1[r] += acc[cf][r] * a1;
            p2[r] += acc[cf][r] * a2;
        }
    }
#pragma unroll
    for (int off = 1; off < 16; off <<= 1) {
#pragma unroll
        for (int r = 0; r < 4; ++r) {
            p1[r] += __shfl_xor(p1[r], off);
            p2[r] += __shfl_xor(p2[r], off);
        }
    }
    if (al == 0) {
#pragma unroll
        for (int r = 0; r < 4; ++r) {
            f1[(size_t)bh * NN + nb + r] = p1[r];
            f2[(size_t)bh * NN + nb + r] = p2[r];
        }
    }
}

// ---------- att softmax stats per (b,n) for all 8 heads ----------
__global__ void k_att_stats(const int* __restrict__ adj, const float* __restrict__ f1,
                            const float* __restrict__ f2, float* __restrict__ mx,
                            float* __restrict__ dn) {
    int n = blockIdx.x, b = blockIdx.y, t = threadIdx.x;
    int lane = t & 63, w = t >> 6;
    const int* arow = adj + ((size_t)b * NN + n) * NN;
    float fl[HH], m8[HH], s8[HH];
#pragma unroll
    for (int hd = 0; hd < HH; ++hd) {
        fl[hd] = f1[((size_t)b * HH + hd) * NN + n];
        m8[hd] = -3.4e38f;
        s8[hd] = 0.f;
    }
    for (int m = t; m < NN; m += 256) {
        int a = arow[m];
#pragma unroll
        for (int hd = 0; hd < HH; ++hd) {
            float v;
            if (a > 0) v = lrelu(fl[hd] + f2[((size_t)b * HH + hd) * NN + m], 0.2f);
            else v = NEGV;
            m8[hd] = fmaxf(m8[hd], v);
        }
    }
    __shared__ float red[4][HH];
#pragma unroll
    for (int hd = 0; hd < HH; ++hd)
        for (int off = 32; off; off >>= 1) m8[hd] = fmaxf(m8[hd], __shfl_xor(m8[hd], off));
    if (lane == 0)
        for (int hd = 0; hd < HH; ++hd) red[w][hd] = m8[hd];
    __syncthreads();
    float rm[HH];
#pragma unroll
    for (int hd = 0; hd < HH; ++hd)
        rm[hd] = fmaxf(fmaxf(red[0][hd], red[1][hd]), fmaxf(red[2][hd], red[3][hd]));
    __syncthreads();
    for (int m = t; m < NN; m += 256) {
        int a = arow[m];
#pragma unroll
        for (int hd = 0; hd < HH; ++hd) {
            float v;
            if (a > 0) v = lrelu(fl[hd] + f2[((size_t)b * HH + hd) * NN + m], 0.2f);
            else v = NEGV;
            s8[hd] += __expf(v - rm[hd]);
        }
    }
#pragma unroll
    for (int hd = 0; hd < HH; ++hd)
        for (int off = 32; off; off >>= 1) s8[hd] += __shfl_xor(s8[hd], off);
    if (lane == 0)
        for (int hd = 0; hd < HH; ++hd) red[w][hd] = s8[hd];
    __syncthreads();
    if (t < HH) {
        float sm = red[0][t] + red[1][t] + red[2][t] + red[3][t];
        mx[((size_t)b * HH + t) * NN + n] = rm[t];
        dn[((size_t)b * HH + t) * NN + n] = sm;
    }
}

// ---------- MFMA: ybf = bf16(lrelu(elu(A @ h), 0.01)), heads concatenated ----------
__global__ void k_att_pv_mfma(const int* __restrict__ adj, const float* __restrict__ f1,
                              const float* __restrict__ f2, const float* __restrict__ mx,
                              const float* __restrict__ dn,
                              const __hip_bfloat16* __restrict__ hT,
                              __hip_bfloat16* __restrict__ ybf) {
    int n0 = blockIdx.x * 16;
    int bh = blockIdx.y;
    int b = bh >> 3, hd = bh & 7;
    int t = threadIdx.x, lane = t & 63, w = t >> 6;
    __shared__ __align__(16) __hip_bfloat16 As[16][72];
    __shared__ float f1s[16], mxs[16], ids[16];
    if (t < 16) {
        f1s[t] = f1[(size_t)bh * NN + n0 + t];
        mxs[t] = mx[(size_t)bh * NN + n0 + t];
        ids[t] = 1.0f / dn[(size_t)bh * NN + n0 + t];
    }
    __syncthreads();
    f32x4 acc = {0.f, 0.f, 0.f, 0.f};
    const float* f2b = f2 + (size_t)bh * NN;
    const __hip_bfloat16* hb = hT + ((size_t)bh * OO + w * 16 + (lane & 15)) * NN;
    const int* adjb = adj + (size_t)b * NN * NN;
    int ar = lane & 15;
    int ak = (lane >> 4) * 8;
    for (int k0 = 0; k0 < NN; k0 += 64) {
        for (int e = t; e < 1024; e += 256) {
            int r = e >> 6, i = e & 63;
            int a = adjb[(size_t)(n0 + r) * NN + k0 + i];
            float v = (a > 0) ? lrelu(f1s[r] + f2b[k0 + i], 0.2f) : NEGV;
            As[r][i] = __float2bfloat16(__expf(v - mxs[r]) * ids[r]);
        }
        __syncthreads();
        short8 a0 = *(const short8*)&As[ar][ak];
        short8 b0 = *(const short8*)&hb[k0 + ak];
        acc = __builtin_amdgcn_mfma_f32_16x16x32_bf16(a0, b0, acc, 0, 0, 0);
        short8 a1 = *(const short8*)&As[ar][32 + ak];
        short8 b1 = *(const short8*)&hb[k0 + 32 + ak];
        acc = __builtin_amdgcn_mfma_f32_16x16x32_bf16(a1, b1, acc, 0, 0, 0);
        __syncthreads();
    }
    int col = w * 16 + (lane & 15);
    int rbase = (lane >> 4) * 4;
#pragma unroll
    for (int r = 0; r < 4; ++r) {
        int n = n0 + rbase + r;
        float v = acc[r];
        float e = v > 0.f ? v : expm1f(v);
        float yv = e > 0.f ? e : 0.01f * e;
        ybf[((size_t)b * NN + n) * (HH * OO) + hd * OO + col] = __float2bfloat16(yv);
    }
}

// ---------- MFMA outproj: ho = y @ W_out, fused g1/g2 + bf16 hoT write ----------
// grid 256 blocks (32-row tiles); wave w: all 32 rows, cols w*64..+63
__global__ void k_outproj_mfma(const __hip_bfloat16* __restrict__ ybf,
                               const __hip_bfloat16* __restrict__ WoT,
                               const float* __restrict__ ao,
                               __hip_bfloat16* __restrict__ hoT,
                               float* __restrict__ g1, float* __restrict__ g2) {
    int tile = blockIdx.x;
    int t = threadIdx.x, lane = t & 63, w = t >> 6;
    int r0 = tile * 32;
    int b = r0 >> 10, n0 = r0 & 1023;
    __shared__ __align__(16) __hip_bfloat16 As[32][520];
    __shared__ float pg1[4][32], pg2[4][32];
    for (int e = t; e < 2048; e += 256) {
        int row = e >> 6, k8 = (e & 63) * 8;
        *(short8*)&As[row][k8] = *(const short8*)&ybf[(size_t)(r0 + row) * 512 + k8];
    }
    __syncthreads();
    int al = lane & 15, ah = lane >> 4;
    f32x4 z4 = {0.f, 0.f, 0.f, 0.f};
    f32x4 acc0[4] = {z4, z4, z4, z4};
    f32x4 acc1[4] = {z4, z4, z4, z4};
    for (int k0 = 0; k0 < 512; k0 += 32) {
        int k = k0 + ah * 8;
        short8 a0 = *(const short8*)&As[al][k];
        short8 a1 = *(const short8*)&As[16 + al][k];
#pragma unroll
        for (int cf = 0; cf < 4; ++cf) {
            int col = w * 64 + cf * 16 + al;
            short8 bf = *(const short8*)&WoT[(size_t)col * 512 + k];
            acc0[cf] = __builtin_amdgcn_mfma_f32_16x16x32_bf16(a0, bf, acc0[cf], 0, 0, 0);
            acc1[cf] = __builtin_amdgcn_mfma_f32_16x16x32_bf16(a1, bf, acc1[cf], 0, 0, 0);
        }
    }
    // hoT[b][c][n] bf16 writes + g partials
    float q1[8] = {0.f, 0.f, 0.f, 0.f, 0.f, 0.f, 0.f, 0.f};
    float q2[8] = {0.f, 0.f, 0.f, 0.f, 0.f, 0.f, 0.f, 0.f};
#pragma unroll
    for (int cf = 0; cf < 4; ++cf) {
        int col = w * 64 + cf * 16 + al;
        float a1v = ao[col], a2v = ao[CC + col];
        __hip_bfloat16* dst = hoT + ((size_t)b * CC + col) * NN + n0 + ah * 4;
#pragma unroll
        for (int r = 0; r < 4; ++r) {
            dst[r] = __float2bfloat16(acc0[cf][r]);
            dst[16 + r] = __float2bfloat16(acc1[cf][r]);
            q1[r] += acc0[cf][r] * a1v;
            q2[r] += acc0[cf][r] * a2v;
            q1[4 + r] += acc1[cf][r] * a1v;
            q2[4 + r] += acc1[cf][r] * a2v;
        }
    }
#pragma unroll
    for (int off = 1; off < 16; off <<= 1) {
#pragma unroll
        for (int j = 0; j < 8; ++j) {
            q1[j] += __shfl_xor(q1[j], off);
            q2[j] += __shfl_xor(q2[j], off);
        }
    }
    if (al == 0) {
#pragma unroll
        for (int j = 0; j < 8; ++j) {
            int row = (j >> 2) * 16 + ah * 4 + (j & 3);
            pg1[w][row] = q1[j];
            pg2[w][row] = q2[j];
        }
    }
    __syncthreads();
    if (t < 32) {
        g1[r0 + t] = pg1[0][t] + pg1[1][t] + pg1[2][t] + pg1[3][t];
        g2[r0 + t] = pg2[0][t] + pg2[1][t] + pg2[2][t] + pg2[3][t];
    }
}

// ---------- out-layer softmax stats ----------
__global__ void k_out_stats(const int* __restrict__ adj, const float* __restrict__ g1,
                            const float* __restrict__ g2, float* __restrict__ mxo,
                            float* __restrict__ dno) {
    int n = blockIdx.x, b = blockIdx.y, t = threadIdx.x;
    int lane = t & 63, w = t >> 6;
    const int* arow = adj + ((size_t)b * NN + n) * NN;
    float gl = g1[b * NN + n];
    float mm = -3.4e38f, ss = 0.f;
    for (int m = t; m < NN; m += 256) {
        int a = arow[m];
        float v = (a > 0) ? lrelu(gl + g2[b * NN + m], 0.2f) : NEGV;
        mm = fmaxf(mm, v);
    }
    for (int off = 32; off; off >>= 1) mm = fmaxf(mm, __shfl_xor(mm, off));
    __shared__ float red[4];
    if (lane == 0) red[w] = mm;
    __syncthreads();
    float rm = fmaxf(fmaxf(red[0], red[1]), fmaxf(red[2], red[3]));
    __syncthreads();
    for (int m = t; m < NN; m += 256) {
        int a = arow[m];
        float v = (a > 0) ? lrelu(gl + g2[b * NN + m], 0.2f) : NEGV;
        ss += __expf(v - rm);
    }
    for (int off = 32; off; off >>= 1) ss += __shfl_xor(ss, off);
    if (lane == 0) red[w] = ss;
    __syncthreads();
    if (t == 0) {
        mxo[b * NN + n] = rm;
        dno[b * NN + n] = red[0] + red[1] + red[2] + red[3];
    }
}

// ---------- MFMA: t = x + elu(Ao @ ho) ----------
__global__ void k_out_pv_mfma(const int* __restrict__ adj, const float* __restrict__ g1,
                              const float* __restrict__ g2, const float* __restrict__ mxo,
                              const float* __restrict__ dno,
                              const __hip_bfloat16* __restrict__ hoT,
                              const float* __restrict__ xin, float* __restrict__ tout) {
    int n0 = blockIdx.x * 16;
    int half = blockIdx.y;
    int b = blockIdx.z;
    int t = threadIdx.x, lane = t & 63, w = t >> 6;
    __shared__ __align__(16) __hip_bfloat16 As[16][72];
    __shared__ float g1s[16], mxs[16], ids[16];
    if (t < 16) {
        g1s[t] = g1[(size_t)b * NN + n0 + t];
        mxs[t] = mxo[(size_t)b * NN + n0 + t];
        ids[t] = 1.0f / dno[(size_t)b * NN + n0 + t];
    }
    __syncthreads();
    f32x4 acc0 = {0.f, 0.f, 0.f, 0.f}, acc1 = {0.f, 0.f, 0.f, 0.f};
    const float* g2b = g2 + (size_t)b * NN;
    int colbase = half * 128 + w * 32;
    const __hip_bfloat16* h0 = hoT + ((size_t)b * CC + colbase + (lane & 15)) * NN;
    const __hip_bfloat16* h1 = h0 + (size_t)16 * NN;
    const int* adjb = adj + (size_t)b * NN * NN;
    int ar = lane & 15;
    int ak = (lane >> 4) * 8;
    for (int k0 = 0; k0 < NN; k0 += 64) {
        for (int e = t; e < 1024; e += 256) {
            int r = e >> 6, i = e & 63;
            int a = adjb[(size_t)(n0 + r) * NN + k0 + i];
            float v = (a > 0) ? lrelu(g1s[r] + g2b[k0 + i], 0.2f) : NEGV;
            As[r][i] = __float2bfloat16(__expf(v - mxs[r]) * ids[r]);
        }
        __syncthreads();
#pragma unroll
        for (int kk = 0; kk < 64; kk += 32) {
            short8 a = *(const short8*)&As[ar][kk + ak];
            short8 bv0 = *(const short8*)&h0[k0 + kk + ak];
            short8 bv1 = *(const short8*)&h1[k0 + kk + ak];
            acc0 = __builtin_amdgcn_mfma_f32_16x16x32_bf16(a, bv0, acc0, 0, 0, 0);
            acc1 = __builtin_amdgcn_mfma_f32_16x16x32_bf16(a, bv1, acc1, 0, 0, 0);
        }
        __syncthreads();
    }
    int rbase = (lane >> 4) * 4;
#pragma unroll
    for (int r = 0; r < 4; ++r) {
        int n = n0 + rbase + r;
        size_t rowo = ((size_t)b * NN + n) * CC;
        int c0 = colbase + (lane & 15);
        float v0 = acc0[r];
        float e0 = v0 > 0.f ? v0 : expm1f(v0);
        tout[rowo + c0] = xin[rowo + c0] + e0;
        float v1 = acc1[r];
        float e1 = v1 > 0.f ? v1 : expm1f(v1);
        tout[rowo + c0 + 16] = xin[rowo + c0 + 16] + e1;
    }
}

// ---------- mask + layernorm ----------
__global__ void k_mask_ln(const float* __restrict__ tin, const int* __restrict__ mask,
                          const float* __restrict__ lw, const float* __restrict__ lb,
                          float* __restrict__ xout) {
    int n = blockIdx.x, b = blockIdx.y, t = threadIdx.x;
    int lane = t & 63, w = t >> 6;
    float v = (mask[b * NN + n] == 0) ? 0.f : tin[((size_t)b * NN + n) * CC + t];
    __shared__ float r1[4], r2[4];
    float s = v;
    for (int off = 32; off; off >>= 1) s += __shfl_xor(s, off);
    if (lane == 0) r1[w] = s;
    __syncthreads();
    float mu = (r1[0] + r1[1] + r1[2] + r1[3]) * (1.0f / CC);
    float d = v - mu;
    float q = d * d;
    for (int off = 32; off; off >>= 1) q += __shfl_xor(q, off);
    if (lane == 0) r2[w] = q;
    __syncthreads();
    float var = (r2[0] + r2[1] + r2[2] + r2[3]) * (1.0f / CC);
    xout[((size_t)b * NN + n) * CC + t] = d * rsqrtf(var + 1e-5f) * lw[t] + lb[t];
}

// ---------- final relu outputs ----------
__global__ void k_relu_out(const float* __restrict__ xb, float* __restrict__ out) {
    int idx = blockIdx.x * 256 + threadIdx.x;
    float v = xb[idx];
    v = v > 0.f ? v : 0.f;
    out[idx] = v;
    int c = idx & 255;
    int bn = idx >> 8;
    int n = bn & 1023;
    int b = bn >> 10;
    if (n == 0) out[(size_t)BB * NN * CC + b * CC + c] = v;
}

extern "C" void kernel_launch(void* const* d_in, const int* in_sizes, int n_in,
                              void* d_out, int out_size, void* d_ws, size_t ws_size,
                              hipStream_t stream) {
    const float* x = (const float*)d_in[0];
    const int* adj = (const int*)d_in[1];
    const int* mask = (const int*)d_in[2];
    const float* W_att = (const float*)d_in[3];
    const float* a_att = (const float*)d_in[4];
    const float* W_out = (const float*)d_in[5];
    const float* a_out = (const float*)d_in[6];
    const float* ln_w = (const float*)d_in[7];
    const float* ln_b = (const float*)d_in[8];
    float* out = (float*)d_out;

    float* ws = (float*)d_ws;
    float* xbuf = ws;                          // 2,097,152 f32
    float* tbuf = xbuf + 2097152;              // 2,097,152 f32
    float* f1   = tbuf + 2097152;              // 65,536
    float* f2   = f1 + 65536;
    float* mx   = f2 + 65536;
    float* dn   = mx + 65536;
    float* g1   = dn + 65536;                  // 8,192
    float* g2   = g1 + 8192;
    float* mxo  = g2 + 8192;
    float* dno  = mxo + 8192;
    float* p    = dno + 8192;
    __hip_bfloat16* hT  = (__hip_bfloat16*)p;            // 4,194,304 bf16 (2,097,152 slots)
    __hip_bfloat16* ybf = (__hip_bfloat16*)(p + 2097152);// 4,194,304 bf16
    __hip_bfloat16* hoT = (__hip_bfloat16*)(p + 4194304);// 2,097,152 bf16 (1,048,576 slots)
    __hip_bfloat16* WaT = (__hip_bfloat16*)(p + 5242880);// 131,072 bf16 (65,536 slots)
    __hip_bfloat16* WoT = (__hip_bfloat16*)(p + 5308416);// 131,072 bf16

    k_copy<<<8192, 256, 0, stream>>>(x, xbuf);
    k_wprep<<<1024, 256, 0, stream>>>(W_att, W_out, WaT, WoT);

    for (int layer = 0; layer < 2; ++layer) {
        k_proj_mfma<<<dim3(128, 8), 256, 0, stream>>>(xbuf, WaT, a_att, hT, f1, f2);
        k_att_stats<<<dim3(NN, BB), 256, 0, stream>>>(adj, f1, f2, mx, dn);
        k_att_pv_mfma<<<dim3(NN / 16, BB * HH), 256, 0, stream>>>(adj, f1, f2, mx, dn,
                                                                  hT, ybf);
        k_outproj_mfma<<<256, 256, 0, stream>>>(ybf, WoT, a_out, hoT, g1, g2);
        k_out_stats<<<dim3(NN, BB), 256, 0, stream>>>(adj, g1, g2, mxo, dno);
        k_out_pv_mfma<<<dim3(NN / 16, 2, BB), 256, 0, stream>>>(adj, g1, g2, mxo, dno,
                                                                hoT, xbuf, tbuf);
        k_mask_ln<<<dim3(NN, BB), 256, 0, stream>>>(tbuf, mask, ln_w, ln_b, xbuf);
    }
    k_relu_out<<<8192, 256, 0, stream>>>(xbuf, out);
}

// Round 5
// 355.393 us; speedup vs baseline: 5.5443x; 1.9277x over previous
//
#include <hip/hip_runtime.h>
#include <hip/hip_bf16.h>
#include <math.h>

#define BB 8
#define NN 1024
#define FF 256
#define HH 8
#define OO 64
#define CC 256

typedef __attribute__((ext_vector_type(8))) short short8;
typedef __attribute__((ext_vector_type(4))) short s16x4;
typedef __attribute__((ext_vector_type(4))) float f32x4;
typedef unsigned long long u64;

__device__ __forceinline__ float lrelu(float v, float a) { return v > 0.f ? v : a * v; }

__device__ __forceinline__ short bf16s(float f) {
    __hip_bfloat16 h = __float2bfloat16(f);
    return *reinterpret_cast<short*>(&h);
}

// ---------- x copy ----------
__global__ void k_copy(const float* __restrict__ src, float* __restrict__ dst) {
    int i = blockIdx.x * 256 + threadIdx.x;
    dst[i] = src[i];
}

// ---------- adj -> bitmask (1 MB) ----------
__global__ void k_adjprep(const int* __restrict__ adj, u64* __restrict__ adjbit) {
    int i = blockIdx.x * 256 + threadIdx.x;
    u64 m = __ballot(adj[i] > 0);
    if ((threadIdx.x & 63) == 0) adjbit[i >> 6] = m;
}

// ---------- one-time weight transpose+convert ----------
__global__ void k_wprep(const float* __restrict__ Wa, const float* __restrict__ Wo,
                        __hip_bfloat16* __restrict__ WaT, __hip_bfloat16* __restrict__ WoT) {
    int i = blockIdx.x * 256 + threadIdx.x;  // 0..262143
    if (i < 131072) {
        int hd = i >> 14, o = (i >> 8) & 63, f = i & 255;
        WaT[i] = __float2bfloat16(Wa[hd * 16384 + f * 64 + o]);
    } else {
        int j = i - 131072;
        int c = j >> 9, k = j & 511;
        WoT[j] = __float2bfloat16(Wo[k * 256 + c]);
    }
}

// ---------- MFMA proj: h = x @ W_att (per head), fused f1/f2 + bf16 hT write ----
__global__ void k_proj_mfma(const float* __restrict__ x,
                            const __hip_bfloat16* __restrict__ WaT,
                            const float* __restrict__ aatt,
                            __hip_bfloat16* __restrict__ hT,
                            float* __restrict__ f1, float* __restrict__ f2) {
    int tile = blockIdx.x, hd = blockIdx.y;
    int t = threadIdx.x, lane = t & 63, w = t >> 6;
    int r0 = tile * 64;
    int b = r0 >> 10;
    int n0 = r0 & 1023;
    int bh = b * HH + hd;
    int al = lane & 15, ah = lane >> 4;
    const float* xrow = x + (size_t)(r0 + w * 16 + al) * FF;
    const __hip_bfloat16* Wb = WaT + (size_t)hd * OO * FF;
    f32x4 z4 = {0.f, 0.f, 0.f, 0.f};
    f32x4 acc[4] = {z4, z4, z4, z4};
    for (int k0 = 0; k0 < FF; k0 += 32) {
        int k = k0 + ah * 8;
        short8 af;
#pragma unroll
        for (int q = 0; q < 8; ++q) af[q] = bf16s(xrow[k + q]);
#pragma unroll
        for (int cf = 0; cf < 4; ++cf) {
            int col = cf * 16 + al;
            short8 bf = *(const short8*)&Wb[(size_t)col * FF + k];
            acc[cf] = __builtin_amdgcn_mfma_f32_16x16x32_bf16(af, bf, acc[cf], 0, 0, 0);
        }
    }
    int nb = n0 + w * 16 + ah * 4;
#pragma unroll
    for (int cf = 0; cf < 4; ++cf) {
        int col = cf * 16 + al;
        __hip_bfloat16* dst = hT + ((size_t)bh * OO + col) * NN + nb;
#pragma unroll
        for (int r = 0; r < 4; ++r) dst[r] = __float2bfloat16(acc[cf][r]);
    }
    float p1[4] = {0.f, 0.f, 0.f, 0.f}, p2[4] = {0.f, 0.f, 0.f, 0.f};
#pragma unroll
    for (int cf = 0; cf < 4; ++cf) {
        int col = cf * 16 + al;
        float a1 = aatt[hd * 2 * OO + col];
        float a2 = aatt[hd * 2 * OO + OO + col];
#pragma unroll
        for (int r = 0; r < 4; ++r) {
            p1[r] += acc[cf][r] * a1;
            p2[r] += acc[cf][r] * a2;
        }
    }
#pragma unroll
    for (int off = 1; off < 16; off <<= 1) {
#pragma unroll
        for (int r = 0; r < 4; ++r) {
            p1[r] += __shfl_xor(p1[r], off);
            p2[r] += __shfl_xor(p2[r], off);
        }
    }
    if (al == 0) {
#pragma unroll
        for (int r = 0; r < 4; ++r) {
            f1[(size_t)bh * NN + nb + r] = p1[r];
            f2[(size_t)bh * NN + nb + r] = p2[r];
        }
    }
}

// ---------- FUSED att: factorized softmax + PV MFMA + deferred normalization ----
// A_ij = bit * (Q_j > thr_i ? P_i*Q_j : R_i*S_j);  out = (A@h)/rowsum(A)
__global__ void k_att_fused(const u64* __restrict__ adjbit, const float* __restrict__ f1,
                            const float* __restrict__ f2,
                            const __hip_bfloat16* __restrict__ hT,
                            __hip_bfloat16* __restrict__ ybf) {
    int n0 = blockIdx.x * 16;
    int bh = blockIdx.y;
    int b = bh >> 3, hd = bh & 7;
    int t = threadIdx.x, lane = t & 63, w = t >> 6;
    __shared__ float Qs[1024], Ss[1024];
    __shared__ u64 bits[272];               // [16][17] padded (bank-conflict-free)
    __shared__ __align__(16) __hip_bfloat16 As[16][72];
    __shared__ float psum[4][16];
    const float* f2b = f2 + (size_t)bh * NN;
    for (int j = t; j < 1024; j += 256) {
        float v = f2b[j];
        Qs[j] = __expf(v);
        Ss[j] = __expf(0.2f * v);
    }
    bits[(t >> 4) * 17 + (t & 15)] =
        adjbit[((size_t)b * NN + n0 + (t >> 4)) * 16 + (t & 15)];
    // per-thread row constants: this thread builds row r, cols i0..i0+3 of each tile
    int r = t & 15;
    int i0 = (t >> 4) * 4;
    float fl = f1[(size_t)bh * NN + n0 + r];
    float thr = __expf(-fl);
    float P = __expf(fl);
    float R = __expf(0.2f * fl);
    __syncthreads();
    int ar = lane & 15, ah = lane >> 4;
    int ak = ah * 8;
    const __hip_bfloat16* hb = hT + ((size_t)bh * OO + w * 16 + ar) * NN;
    f32x4 acc = {0.f, 0.f, 0.f, 0.f};
    float ps = 0.f;
    for (int k0 = 0; k0 < NN; k0 += 64) {
        u64 m = bits[r * 17 + (k0 >> 6)];
        f32x4 q4 = *(const f32x4*)&Qs[k0 + i0];
        f32x4 s4 = *(const f32x4*)&Ss[k0 + i0];
        s16x4 op;
#pragma unroll
        for (int e = 0; e < 4; ++e) {
            float q = q4[e], s = s4[e];
            float val = ((m >> (i0 + e)) & 1) ? (q > thr ? P * q : R * s) : 0.f;
            ps += val;
            op[e] = bf16s(val);
        }
        *(s16x4*)&As[r][i0] = op;
        __syncthreads();
        short8 a0 = *(const short8*)&As[ar][ak];
        short8 b0 = *(const short8*)&hb[k0 + ak];
        acc = __builtin_amdgcn_mfma_f32_16x16x32_bf16(a0, b0, acc, 0, 0, 0);
        short8 a1 = *(const short8*)&As[ar][32 + ak];
        short8 b1 = *(const short8*)&hb[k0 + 32 + ak];
        acc = __builtin_amdgcn_mfma_f32_16x16x32_bf16(a1, b1, acc, 0, 0, 0);
        __syncthreads();
    }
    ps += __shfl_xor(ps, 16);
    ps += __shfl_xor(ps, 32);
    if (lane < 16) psum[w][lane] = ps;
    __syncthreads();
    int rbase = ah * 4;
    int col = w * 16 + ar;
#pragma unroll
    for (int rr = 0; rr < 4; ++rr) {
        int row = rbase + rr;
        float dn = psum[0][row] + psum[1][row] + psum[2][row] + psum[3][row];
        float v = acc[rr] * (1.0f / dn);
        float e = v > 0.f ? v : expm1f(v);
        float yv = e > 0.f ? e : 0.01f * e;
        ybf[((size_t)b * NN + n0 + row) * 512 + hd * OO + col] = __float2bfloat16(yv);
    }
}

// ---------- MFMA outproj: ho = y @ W_out, fused g1/g2 + bf16 hoT write ----------
__global__ void k_outproj_mfma(const __hip_bfloat16* __restrict__ ybf,
                               const __hip_bfloat16* __restrict__ WoT,
                               const float* __restrict__ ao,
                               __hip_bfloat16* __restrict__ hoT,
                               float* __restrict__ g1, float* __restrict__ g2) {
    int tile = blockIdx.x;
    int t = threadIdx.x, lane = t & 63, w = t >> 6;
    int r0 = tile * 32;
    int b = r0 >> 10, n0 = r0 & 1023;
    __shared__ __align__(16) __hip_bfloat16 As[32][520];
    __shared__ float pg1[4][32], pg2[4][32];
    for (int e = t; e < 2048; e += 256) {
        int row = e >> 6, k8 = (e & 63) * 8;
        *(short8*)&As[row][k8] = *(const short8*)&ybf[(size_t)(r0 + row) * 512 + k8];
    }
    __syncthreads();
    int al = lane & 15, ah = lane >> 4;
    f32x4 z4 = {0.f, 0.f, 0.f, 0.f};
    f32x4 acc0[4] = {z4, z4, z4, z4};
    f32x4 acc1[4] = {z4, z4, z4, z4};
    for (int k0 = 0; k0 < 512; k0 += 32) {
        int k = k0 + ah * 8;
        short8 a0 = *(const short8*)&As[al][k];
        short8 a1 = *(const short8*)&As[16 + al][k];
#pragma unroll
        for (int cf = 0; cf < 4; ++cf) {
            int col = w * 64 + cf * 16 + al;
            short8 bf = *(const short8*)&WoT[(size_t)col * 512 + k];
            acc0[cf] = __builtin_amdgcn_mfma_f32_16x16x32_bf16(a0, bf, acc0[cf], 0, 0, 0);
            acc1[cf] = __builtin_amdgcn_mfma_f32_16x16x32_bf16(a1, bf, acc1[cf], 0, 0, 0);
        }
    }
    float q1[8] = {0.f, 0.f, 0.f, 0.f, 0.f, 0.f, 0.f, 0.f};
    float q2[8] = {0.f, 0.f, 0.f, 0.f, 0.f, 0.f, 0.f, 0.f};
#pragma unroll
    for (int cf = 0; cf < 4; ++cf) {
        int col = w * 64 + cf * 16 + al;
        float a1v = ao[col], a2v = ao[CC + col];
        __hip_bfloat16* dst = hoT + ((size_t)b * CC + col) * NN + n0 + ah * 4;
#pragma unroll
        for (int r = 0; r < 4; ++r) {
            dst[r] = __float2bfloat16(acc0[cf][r]);
            dst[16 + r] = __float2bfloat16(acc1[cf][r]);
            q1[r] += acc0[cf][r] * a1v;
            q2[r] += acc0[cf][r] * a2v;
            q1[4 + r] += acc1[cf][r] * a1v;
            q2[4 + r] += acc1[cf][r] * a2v;
        }
    }
#pragma unroll
    for (int off = 1; off < 16; off <<= 1) {
#pragma unroll
        for (int j = 0; j < 8; ++j) {
            q1[j] += __shfl_xor(q1[j], off);
            q2[j] += __shfl_xor(q2[j], off);
        }
    }
    if (al == 0) {
#pragma unroll
        for (int j = 0; j < 8; ++j) {
            int row = (j >> 2) * 16 + ah * 4 + (j & 3);
            pg1[w][row] = q1[j];
            pg2[w][row] = q2[j];
        }
    }
    __syncthreads();
    if (t < 32) {
        g1[r0 + t] = pg1[0][t] + pg1[1][t] + pg1[2][t] + pg1[3][t];
        g2[r0 + t] = pg2[0][t] + pg2[1][t] + pg2[2][t] + pg2[3][t];
    }
}

// ---------- FUSED out layer: factorized softmax + PV + residual ----------
__global__ void k_out_fused(const u64* __restrict__ adjbit, const float* __restrict__ g1,
                            const float* __restrict__ g2,
                            const __hip_bfloat16* __restrict__ hoT,
                            const float* __restrict__ xin, float* __restrict__ tout) {
    int n0 = blockIdx.x * 16;
    int b = blockIdx.y;
    int t = threadIdx.x, lane = t & 63, w = t >> 6;
    __shared__ float Qs[1024], Ss[1024];
    __shared__ u64 bits[272];
    __shared__ __align__(16) __hip_bfloat16 As[16][72];
    __shared__ float psum[4][16];
    const float* g2b = g2 + (size_t)b * NN;
    for (int j = t; j < 1024; j += 256) {
        float v = g2b[j];
        Qs[j] = __expf(v);
        Ss[j] = __expf(0.2f * v);
    }
    bits[(t >> 4) * 17 + (t & 15)] =
        adjbit[((size_t)b * NN + n0 + (t >> 4)) * 16 + (t & 15)];
    int r = t & 15;
    int i0 = (t >> 4) * 4;
    float gl = g1[(size_t)b * NN + n0 + r];
    float thr = __expf(-gl);
    float P = __expf(gl);
    float R = __expf(0.2f * gl);
    __syncthreads();
    int ar = lane & 15, ah = lane >> 4;
    int ak = ah * 8;
    const __hip_bfloat16* hbase = hoT + ((size_t)b * CC + w * 64 + ar) * NN;
    f32x4 z4 = {0.f, 0.f, 0.f, 0.f};
    f32x4 acc[4] = {z4, z4, z4, z4};
    float ps = 0.f;
    for (int k0 = 0; k0 < NN; k0 += 64) {
        u64 m = bits[r * 17 + (k0 >> 6)];
        f32x4 q4 = *(const f32x4*)&Qs[k0 + i0];
        f32x4 s4 = *(const f32x4*)&Ss[k0 + i0];
        s16x4 op;
#pragma unroll
        for (int e = 0; e < 4; ++e) {
            float q = q4[e], s = s4[e];
            float val = ((m >> (i0 + e)) & 1) ? (q > thr ? P * q : R * s) : 0.f;
            ps += val;
            op[e] = bf16s(val);
        }
        *(s16x4*)&As[r][i0] = op;
        __syncthreads();
        short8 a0 = *(const short8*)&As[ar][ak];
        short8 a1 = *(const short8*)&As[ar][32 + ak];
#pragma unroll
        for (int cf = 0; cf < 4; ++cf) {
            const __hip_bfloat16* hb = hbase + (size_t)cf * 16 * NN;
            short8 bv0 = *(const short8*)&hb[k0 + ak];
            short8 bv1 = *(const short8*)&hb[k0 + 32 + ak];
            acc[cf] = __builtin_amdgcn_mfma_f32_16x16x32_bf16(a0, bv0, acc[cf], 0, 0, 0);
            acc[cf] = __builtin_amdgcn_mfma_f32_16x16x32_bf16(a1, bv1, acc[cf], 0, 0, 0);
        }
        __syncthreads();
    }
    ps += __shfl_xor(ps, 16);
    ps += __shfl_xor(ps, 32);
    if (lane < 16) psum[w][lane] = ps;
    __syncthreads();
    int rbase = ah * 4;
#pragma unroll
    for (int rr = 0; rr < 4; ++rr) {
        int row = rbase + rr;
        float ids = 1.0f / (psum[0][row] + psum[1][row] + psum[2][row] + psum[3][row]);
        size_t rowo = ((size_t)b * NN + n0 + row) * CC;
#pragma unroll
        for (int cf = 0; cf < 4; ++cf) {
            int col = w * 64 + cf * 16 + ar;
            float v = acc[cf][rr] * ids;
            float e = v > 0.f ? v : expm1f(v);
            tout[rowo + col] = xin[rowo + col] + e;
        }
    }
}

// ---------- mask + layernorm ----------
__global__ void k_mask_ln(const float* __restrict__ tin, const int* __restrict__ mask,
                          const float* __restrict__ lw, const float* __restrict__ lb,
                          float* __restrict__ xout) {
    int n = blockIdx.x, b = blockIdx.y, t = threadIdx.x;
    int lane = t & 63, w = t >> 6;
    float v = (mask[b * NN + n] == 0) ? 0.f : tin[((size_t)b * NN + n) * CC + t];
    __shared__ float r1[4], r2[4];
    float s = v;
    for (int off = 32; off; off >>= 1) s += __shfl_xor(s, off);
    if (lane == 0) r1[w] = s;
    __syncthreads();
    float mu = (r1[0] + r1[1] + r1[2] + r1[3]) * (1.0f / CC);
    float d = v - mu;
    float q = d * d;
    for (int off = 32; off; off >>= 1) q += __shfl_xor(q, off);
    if (lane == 0) r2[w] = q;
    __syncthreads();
    float var = (r2[0] + r2[1] + r2[2] + r2[3]) * (1.0f / CC);
    xout[((size_t)b * NN + n) * CC + t] = d * rsqrtf(var + 1e-5f) * lw[t] + lb[t];
}

// ---------- final relu outputs ----------
__global__ void k_relu_out(const float* __restrict__ xb, float* __restrict__ out) {
    int idx = blockIdx.x * 256 + threadIdx.x;
    float v = xb[idx];
    v = v > 0.f ? v : 0.f;
    out[idx] = v;
    int c = idx & 255;
    int bn = idx >> 8;
    int n = bn & 1023;
    int b = bn >> 10;
    if (n == 0) out[(size_t)BB * NN * CC + b * CC + c] = v;
}

extern "C" void kernel_launch(void* const* d_in, const int* in_sizes, int n_in,
                              void* d_out, int out_size, void* d_ws, size_t ws_size,
                              hipStream_t stream) {
    const float* x = (const float*)d_in[0];
    const int* adj = (const int*)d_in[1];
    const int* mask = (const int*)d_in[2];
    const float* W_att = (const float*)d_in[3];
    const float* a_att = (const float*)d_in[4];
    const float* W_out = (const float*)d_in[5];
    const float* a_out = (const float*)d_in[6];
    const float* ln_w = (const float*)d_in[7];
    const float* ln_b = (const float*)d_in[8];
    float* out = (float*)d_out;

    float* ws = (float*)d_ws;
    float* xbuf = ws;                          // 2,097,152 f32
    float* tbuf = xbuf + 2097152;              // 2,097,152 f32
    float* f1   = tbuf + 2097152;              // 65,536
    float* f2   = f1 + 65536;                  // 65,536
    float* g1   = f2 + 65536;                  // 8,192
    float* g2   = g1 + 8192;                   // 8,192
    float* p    = g2 + 8192;
    __hip_bfloat16* hT  = (__hip_bfloat16*)p;             // 4,194,304 bf16
    __hip_bfloat16* ybf = (__hip_bfloat16*)(p + 2097152); // 4,194,304 bf16
    __hip_bfloat16* hoT = (__hip_bfloat16*)(p + 4194304); // 2,097,152 bf16
    __hip_bfloat16* WaT = (__hip_bfloat16*)(p + 5242880); // 131,072 bf16
    __hip_bfloat16* WoT = (__hip_bfloat16*)(p + 5308416); // 131,072 bf16
    u64* adjbit = (u64*)(p + 5373952);                    // 131,072 u64 (1 MB)

    k_copy<<<8192, 256, 0, stream>>>(x, xbuf);
    k_wprep<<<1024, 256, 0, stream>>>(W_att, W_out, WaT, WoT);
    k_adjprep<<<32768, 256, 0, stream>>>(adj, adjbit);

    for (int layer = 0; layer < 2; ++layer) {
        k_proj_mfma<<<dim3(128, 8), 256, 0, stream>>>(xbuf, WaT, a_att, hT, f1, f2);
        k_att_fused<<<dim3(NN / 16, BB * HH), 256, 0, stream>>>(adjbit, f1, f2, hT, ybf);
        k_outproj_mfma<<<256, 256, 0, stream>>>(ybf, WoT, a_out, hoT, g1, g2);
        k_out_fused<<<dim3(NN / 16, BB), 256, 0, stream>>>(adjbit, g1, g2, hoT, xbuf, tbuf);
        k_mask_ln<<<dim3(NN, BB), 256, 0, stream>>>(tbuf, mask, ln_w, ln_b, xbuf);
    }
    k_relu_out<<<8192, 256, 0, stream>>>(xbuf, out);
}

// Round 6
// 330.525 us; speedup vs baseline: 5.9614x; 1.0752x over previous
//
#include <hip/hip_runtime.h>
#include <hip/hip_bf16.h>
#include <math.h>

#define BB 8
#define NN 1024
#define FF 256
#define HH 8
#define OO 64
#define CC 256

typedef __attribute__((ext_vector_type(8))) short short8;
typedef __attribute__((ext_vector_type(4))) float f32x4;
typedef unsigned long long u64;

__device__ __forceinline__ short bf16s(float f) {
    __hip_bfloat16 h = __float2bfloat16(f);
    return *reinterpret_cast<short*>(&h);
}

// ---------- adj -> bitmask (1 MB) ----------
__global__ void k_adjprep(const int* __restrict__ adj, u64* __restrict__ adjbit) {
    int i = blockIdx.x * 256 + threadIdx.x;
    u64 m = __ballot(adj[i] > 0);
    if ((threadIdx.x & 63) == 0) adjbit[i >> 6] = m;
}

// ---------- one-time weight transpose+convert ----------
__global__ void k_wprep(const float* __restrict__ Wa, const float* __restrict__ Wo,
                        __hip_bfloat16* __restrict__ WaT, __hip_bfloat16* __restrict__ WoT) {
    int i = blockIdx.x * 256 + threadIdx.x;  // 0..262143
    if (i < 131072) {
        int hd = i >> 14, o = (i >> 8) & 63, f = i & 255;
        WaT[i] = __float2bfloat16(Wa[hd * 16384 + f * 64 + o]);
    } else {
        int j = i - 131072;
        int c = j >> 9, k = j & 511;
        WoT[j] = __float2bfloat16(Wo[k * 256 + c]);
    }
}

// ---------- MFMA proj: h = x @ W_att (per head), fused f1/f2 + bf16 hT write ----
__global__ void k_proj_mfma(const float* __restrict__ x,
                            const __hip_bfloat16* __restrict__ WaT,
                            const float* __restrict__ aatt,
                            __hip_bfloat16* __restrict__ hT,
                            float* __restrict__ f1, float* __restrict__ f2) {
    int tile = blockIdx.x, hd = blockIdx.y;
    int t = threadIdx.x, lane = t & 63, w = t >> 6;
    int r0 = tile * 64;
    int b = r0 >> 10;
    int n0 = r0 & 1023;
    int bh = b * HH + hd;
    int al = lane & 15, ah = lane >> 4;
    const float* xrow = x + (size_t)(r0 + w * 16 + al) * FF;
    const __hip_bfloat16* Wb = WaT + (size_t)hd * OO * FF;
    f32x4 z4 = {0.f, 0.f, 0.f, 0.f};
    f32x4 acc[4] = {z4, z4, z4, z4};
    for (int k0 = 0; k0 < FF; k0 += 32) {
        int k = k0 + ah * 8;
        short8 af;
#pragma unroll
        for (int q = 0; q < 8; ++q) af[q] = bf16s(xrow[k + q]);
#pragma unroll
        for (int cf = 0; cf < 4; ++cf) {
            int col = cf * 16 + al;
            short8 bf = *(const short8*)&Wb[(size_t)col * FF + k];
            acc[cf] = __builtin_amdgcn_mfma_f32_16x16x32_bf16(af, bf, acc[cf], 0, 0, 0);
        }
    }
    int nb = n0 + w * 16 + ah * 4;
#pragma unroll
    for (int cf = 0; cf < 4; ++cf) {
        int col = cf * 16 + al;
        __hip_bfloat16* dst = hT + ((size_t)bh * OO + col) * NN + nb;
#pragma unroll
        for (int r = 0; r < 4; ++r) dst[r] = __float2bfloat16(acc[cf][r]);
    }
    float p1[4] = {0.f, 0.f, 0.f, 0.f}, p2[4] = {0.f, 0.f, 0.f, 0.f};
#pragma unroll
    for (int cf = 0; cf < 4; ++cf) {
        int col = cf * 16 + al;
        float a1 = aatt[hd * 2 * OO + col];
        float a2 = aatt[hd * 2 * OO + OO + col];
#pragma unroll
        for (int r = 0; r < 4; ++r) {
            p1[r] += acc[cf][r] * a1;
            p2[r] += acc[cf][r] * a2;
        }
    }
#pragma unroll
    for (int off = 1; off < 16; off <<= 1) {
#pragma unroll
        for (int r = 0; r < 4; ++r) {
            p1[r] += __shfl_xor(p1[r], off);
            p2[r] += __shfl_xor(p2[r], off);
        }
    }
    if (al == 0) {
#pragma unroll
        for (int r = 0; r < 4; ++r) {
            f1[(size_t)bh * NN + nb + r] = p1[r];
            f2[(size_t)bh * NN + nb + r] = p2[r];
        }
    }
}

// ---------- FUSED att v2: 64-row blocks, wave-private A, barrier-free K-loop ----
// A_ij = bit * (Q_j > thr_i ? P_i*Q_j : R_i*S_j);  out = (A@h)/rowsum(A)
__global__ void k_att_fused(const u64* __restrict__ adjbit, const float* __restrict__ f1,
                            const float* __restrict__ f2,
                            const __hip_bfloat16* __restrict__ hT,
                            __hip_bfloat16* __restrict__ ybf) {
    int n0 = blockIdx.x * 64;
    int bh = blockIdx.y;
    int b = bh >> 3, hd = bh & 7;
    int t = threadIdx.x, lane = t & 63, w = t >> 6;
    __shared__ float Qs[1024], Ss[1024];
    __shared__ u64 bits[64 * 17];             // [64][17] padded
    __shared__ __align__(16) __hip_bfloat16 As[4][16][72];  // wave-private 16x64 tiles
    const float* f2b = f2 + (size_t)bh * NN;
    for (int j = t; j < 1024; j += 256) {
        float v = f2b[j];
        Qs[j] = __expf(v);
        Ss[j] = __expf(0.2f * v);
    }
    for (int e = t; e < 1024; e += 256) {
        int rr = e >> 4, c = e & 15;
        bits[rr * 17 + c] = adjbit[((size_t)b * NN + n0 + rr) * 16 + c];
    }
    int g = lane >> 4, r = lane & 15;   // builder: wave-row r, cols g*16..+15
    int row = w * 16 + r;               // row within 64-row block
    float fl = f1[(size_t)bh * NN + n0 + row];
    float thr = __expf(-fl);
    float P = __expf(fl);
    float R = __expf(0.2f * fl);
    __syncthreads();
    const __hip_bfloat16* hb = hT + ((size_t)bh * OO + r) * NN;  // + cf*16*NN below
    f32x4 z4 = {0.f, 0.f, 0.f, 0.f};
    f32x4 acc[4] = {z4, z4, z4, z4};
    float ps = 0.f;
    for (int k0 = 0; k0 < NN; k0 += 64) {
        u64 m = bits[row * 17 + (k0 >> 6)];
        short8 vv[2];
#pragma unroll
        for (int h = 0; h < 2; ++h) {
            short8 vx;
#pragma unroll
            for (int e4 = 0; e4 < 2; ++e4) {
                int cbase = g * 16 + h * 8 + e4 * 4;
                f32x4 q4 = *(const f32x4*)&Qs[k0 + cbase];
                f32x4 s4 = *(const f32x4*)&Ss[k0 + cbase];
#pragma unroll
                for (int e = 0; e < 4; ++e) {
                    float val = ((m >> (cbase + e)) & 1)
                                    ? (q4[e] > thr ? P * q4[e] : R * s4[e]) : 0.f;
                    ps += val;
                    vx[e4 * 4 + e] = bf16s(val);
                }
            }
            vv[h] = vx;
        }
        *(short8*)&As[w][r][g * 16] = vv[0];
        *(short8*)&As[w][r][g * 16 + 8] = vv[1];
        // same-wave consume (DS in-order per wave; no block barrier needed)
        short8 a0 = *(const short8*)&As[w][r][g * 8];
        short8 a1 = *(const short8*)&As[w][r][32 + g * 8];
#pragma unroll
        for (int cf = 0; cf < 4; ++cf) {
            const __hip_bfloat16* hc = hb + (size_t)cf * 16 * NN;
            short8 b0 = *(const short8*)&hc[k0 + g * 8];
            short8 b1 = *(const short8*)&hc[k0 + 32 + g * 8];
            acc[cf] = __builtin_amdgcn_mfma_f32_16x16x32_bf16(a0, b0, acc[cf], 0, 0, 0);
            acc[cf] = __builtin_amdgcn_mfma_f32_16x16x32_bf16(a1, b1, acc[cf], 0, 0, 0);
        }
    }
    // rowsum: reduce over col-groups (lanes r, r+16, r+32, r+48)
    ps += __shfl_xor(ps, 16);
    ps += __shfl_xor(ps, 32);
#pragma unroll
    for (int rr = 0; rr < 4; ++rr) {
        int rloc = g * 4 + rr;                 // D-row within wave tile
        float dn = __shfl(ps, rloc);           // lane rloc holds rowsum of row rloc
        float ids = 1.0f / dn;
        int nrow = n0 + w * 16 + rloc;
#pragma unroll
        for (int cf = 0; cf < 4; ++cf) {
            float v = acc[cf][rr] * ids;
            float e = v > 0.f ? v : expm1f(v);
            float yv = e > 0.f ? e : 0.01f * e;
            ybf[((size_t)b * NN + nrow) * 512 + hd * OO + cf * 16 + r] =
                __float2bfloat16(yv);
        }
    }
}

// ---------- MFMA outproj: ho = y @ W_out, fused g1/g2 + bf16 hoT write ----------
__global__ void k_outproj_mfma(const __hip_bfloat16* __restrict__ ybf,
                               const __hip_bfloat16* __restrict__ WoT,
                               const float* __restrict__ ao,
                               __hip_bfloat16* __restrict__ hoT,
                               float* __restrict__ g1, float* __restrict__ g2) {
    int tile = blockIdx.x;
    int t = threadIdx.x, lane = t & 63, w = t >> 6;
    int r0 = tile * 32;
    int b = r0 >> 10, n0 = r0 & 1023;
    __shared__ __align__(16) __hip_bfloat16 As[32][520];
    __shared__ float pg1[4][32], pg2[4][32];
    for (int e = t; e < 2048; e += 256) {
        int row = e >> 6, k8 = (e & 63) * 8;
        *(short8*)&As[row][k8] = *(const short8*)&ybf[(size_t)(r0 + row) * 512 + k8];
    }
    __syncthreads();
    int al = lane & 15, ah = lane >> 4;
    f32x4 z4 = {0.f, 0.f, 0.f, 0.f};
    f32x4 acc0[4] = {z4, z4, z4, z4};
    f32x4 acc1[4] = {z4, z4, z4, z4};
    for (int k0 = 0; k0 < 512; k0 += 32) {
        int k = k0 + ah * 8;
        short8 a0 = *(const short8*)&As[al][k];
        short8 a1 = *(const short8*)&As[16 + al][k];
#pragma unroll
        for (int cf = 0; cf < 4; ++cf) {
            int col = w * 64 + cf * 16 + al;
            short8 bf = *(const short8*)&WoT[(size_t)col * 512 + k];
            acc0[cf] = __builtin_amdgcn_mfma_f32_16x16x32_bf16(a0, bf, acc0[cf], 0, 0, 0);
            acc1[cf] = __builtin_amdgcn_mfma_f32_16x16x32_bf16(a1, bf, acc1[cf], 0, 0, 0);
        }
    }
    float q1[8] = {0.f, 0.f, 0.f, 0.f, 0.f, 0.f, 0.f, 0.f};
    float q2[8] = {0.f, 0.f, 0.f, 0.f, 0.f, 0.f, 0.f, 0.f};
#pragma unroll
    for (int cf = 0; cf < 4; ++cf) {
        int col = w * 64 + cf * 16 + al;
        float a1v = ao[col], a2v = ao[CC + col];
        __hip_bfloat16* dst = hoT + ((size_t)b * CC + col) * NN + n0 + ah * 4;
#pragma unroll
        for (int r = 0; r < 4; ++r) {
            dst[r] = __float2bfloat16(acc0[cf][r]);
            dst[16 + r] = __float2bfloat16(acc1[cf][r]);
            q1[r] += acc0[cf][r] * a1v;
            q2[r] += acc0[cf][r] * a2v;
            q1[4 + r] += acc1[cf][r] * a1v;
            q2[4 + r] += acc1[cf][r] * a2v;
        }
    }
#pragma unroll
    for (int off = 1; off < 16; off <<= 1) {
#pragma unroll
        for (int j = 0; j < 8; ++j) {
            q1[j] += __shfl_xor(q1[j], off);
            q2[j] += __shfl_xor(q2[j], off);
        }
    }
    if (al == 0) {
#pragma unroll
        for (int j = 0; j < 8; ++j) {
            int row = (j >> 2) * 16 + ah * 4 + (j & 3);
            pg1[w][row] = q1[j];
            pg2[w][row] = q2[j];
        }
    }
    __syncthreads();
    if (t < 32) {
        g1[r0 + t] = pg1[0][t] + pg1[1][t] + pg1[2][t] + pg1[3][t];
        g2[r0 + t] = pg2[0][t] + pg2[1][t] + pg2[2][t] + pg2[3][t];
    }
}

// ---------- FUSED out v2: K=256 staging (8 barriers total) + PV + residual ----------
__global__ void k_out_fused(const u64* __restrict__ adjbit, const float* __restrict__ g1,
                            const float* __restrict__ g2,
                            const __hip_bfloat16* __restrict__ hoT,
                            const float* __restrict__ xin, float* __restrict__ tout) {
    int n0 = blockIdx.x * 16;
    int b = blockIdx.y;
    int t = threadIdx.x, lane = t & 63, w = t >> 6;
    __shared__ float Qs[1024], Ss[1024];
    __shared__ u64 bits[16 * 17];
    __shared__ __align__(16) __hip_bfloat16 As[16][264];  // 16 x 256 K-window
    __shared__ float psum[4][16];
    const float* g2b = g2 + (size_t)b * NN;
    for (int j = t; j < 1024; j += 256) {
        float v = g2b[j];
        Qs[j] = __expf(v);
        Ss[j] = __expf(0.2f * v);
    }
    {
        int rr = t >> 4, c = t & 15;
        bits[rr * 17 + c] = adjbit[((size_t)b * NN + n0 + rr) * 16 + c];
    }
    int br = t & 15, kg = t >> 4;   // builder: row br, window-cols kg*16..+15
    float gl = g1[(size_t)b * NN + n0 + br];
    float thr = __expf(-gl);
    float P = __expf(gl);
    float R = __expf(0.2f * gl);
    int ar = lane & 15, g = lane >> 4;
    const __hip_bfloat16* hw = hoT + ((size_t)b * CC + w * 64 + ar) * NN;
    f32x4 z4 = {0.f, 0.f, 0.f, 0.f};
    f32x4 acc[4] = {z4, z4, z4, z4};
    float ps = 0.f;
    __syncthreads();
    for (int ks = 0; ks < NN; ks += 256) {
        u64 m = bits[br * 17 + (ks >> 6) + (kg >> 2)];
        int sh = (kg & 3) * 16;
        short8 vv[2];
#pragma unroll
        for (int h = 0; h < 2; ++h) {
            short8 vx;
#pragma unroll
            for (int e4 = 0; e4 < 2; ++e4) {
                int cw = kg * 16 + h * 8 + e4 * 4;   // col within 256-window
                f32x4 q4 = *(const f32x4*)&Qs[ks + cw];
                f32x4 s4 = *(const f32x4*)&Ss[ks + cw];
#pragma unroll
                for (int e = 0; e < 4; ++e) {
                    float val = ((m >> (sh + h * 8 + e4 * 4 + e)) & 1)
                                    ? (q4[e] > thr ? P * q4[e] : R * s4[e]) : 0.f;
                    ps += val;
                    vx[e4 * 4 + e] = bf16s(val);
                }
            }
            vv[h] = vx;
        }
        *(short8*)&As[br][kg * 16] = vv[0];
        *(short8*)&As[br][kg * 16 + 8] = vv[1];
        __syncthreads();
#pragma unroll
        for (int ksub = 0; ksub < 4; ++ksub) {
            short8 a0 = *(const short8*)&As[ar][ksub * 64 + g * 8];
            short8 a1 = *(const short8*)&As[ar][ksub * 64 + 32 + g * 8];
#pragma unroll
            for (int cf = 0; cf < 4; ++cf) {
                const __hip_bfloat16* hc = hw + (size_t)cf * 16 * NN;
                short8 b0 = *(const short8*)&hc[ks + ksub * 64 + g * 8];
                short8 b1 = *(const short8*)&hc[ks + ksub * 64 + 32 + g * 8];
                acc[cf] = __builtin_amdgcn_mfma_f32_16x16x32_bf16(a0, b0, acc[cf], 0, 0, 0);
                acc[cf] = __builtin_amdgcn_mfma_f32_16x16x32_bf16(a1, b1, acc[cf], 0, 0, 0);
            }
        }
        __syncthreads();
    }
    // rowsum: wave-local reduce over kg groups, then cross-wave via LDS
    ps += __shfl_xor(ps, 16);
    ps += __shfl_xor(ps, 32);
    if (lane < 16) psum[w][lane] = ps;
    __syncthreads();
#pragma unroll
    for (int rr = 0; rr < 4; ++rr) {
        int rloc = g * 4 + rr;
        float dn = psum[0][rloc] + psum[1][rloc] + psum[2][rloc] + psum[3][rloc];
        float ids = 1.0f / dn;
        size_t rowo = ((size_t)b * NN + n0 + rloc) * CC;
#pragma unroll
        for (int cf = 0; cf < 4; ++cf) {
            int col = w * 64 + cf * 16 + ar;
            float v = acc[cf][rr] * ids;
            float e = v > 0.f ? v : expm1f(v);
            tout[rowo + col] = xin[rowo + col] + e;
        }
    }
}

// ---------- mask + layernorm (+ optional final relu outputs) ----------
__global__ void k_mask_ln(const float* __restrict__ tin, const int* __restrict__ mask,
                          const float* __restrict__ lw, const float* __restrict__ lb,
                          float* __restrict__ xout, float* __restrict__ outf, int final_) {
    int n = blockIdx.x, b = blockIdx.y, t = threadIdx.x;
    int lane = t & 63, w = t >> 6;
    float v = (mask[b * NN + n] == 0) ? 0.f : tin[((size_t)b * NN + n) * CC + t];
    __shared__ float r1[4], r2[4];
    float s = v;
    for (int off = 32; off; off >>= 1) s += __shfl_xor(s, off);
    if (lane == 0) r1[w] = s;
    __syncthreads();
    float mu = (r1[0] + r1[1] + r1[2] + r1[3]) * (1.0f / CC);
    float d = v - mu;
    float q = d * d;
    for (int off = 32; off; off >>= 1) q += __shfl_xor(q, off);
    if (lane == 0) r2[w] = q;
    __syncthreads();
    float var = (r2[0] + r2[1] + r2[2] + r2[3]) * (1.0f / CC);
    float ln = d * rsqrtf(var + 1e-5f) * lw[t] + lb[t];
    size_t idx = ((size_t)b * NN + n) * CC + t;
    if (final_) {
        float rv = ln > 0.f ? ln : 0.f;
        outf[idx] = rv;
        if (n == 0) outf[(size_t)BB * NN * CC + b * CC + t] = rv;
    } else {
        xout[idx] = ln;
    }
}

extern "C" void kernel_launch(void* const* d_in, const int* in_sizes, int n_in,
                              void* d_out, int out_size, void* d_ws, size_t ws_size,
                              hipStream_t stream) {
    const float* x = (const float*)d_in[0];
    const int* adj = (const int*)d_in[1];
    const int* mask = (const int*)d_in[2];
    const float* W_att = (const float*)d_in[3];
    const float* a_att = (const float*)d_in[4];
    const float* W_out = (const float*)d_in[5];
    const float* a_out = (const float*)d_in[6];
    const float* ln_w = (const float*)d_in[7];
    const float* ln_b = (const float*)d_in[8];
    float* out = (float*)d_out;

    float* ws = (float*)d_ws;
    float* xbuf = ws;                          // 2,097,152 f32
    float* tbuf = xbuf + 2097152;              // 2,097,152 f32
    float* f1   = tbuf + 2097152;              // 65,536
    float* f2   = f1 + 65536;                  // 65,536
    float* g1   = f2 + 65536;                  // 8,192
    float* g2   = g1 + 8192;                   // 8,192
    float* p    = g2 + 8192;
    __hip_bfloat16* hT  = (__hip_bfloat16*)p;             // 4,194,304 bf16
    __hip_bfloat16* ybf = (__hip_bfloat16*)(p + 2097152); // 4,194,304 bf16
    __hip_bfloat16* hoT = (__hip_bfloat16*)(p + 4194304); // 2,097,152 bf16
    __hip_bfloat16* WaT = (__hip_bfloat16*)(p + 5242880); // 131,072 bf16
    __hip_bfloat16* WoT = (__hip_bfloat16*)(p + 5308416); // 131,072 bf16
    u64* adjbit = (u64*)(p + 5373952);                    // 131,072 u64 (1 MB)

    k_wprep<<<1024, 256, 0, stream>>>(W_att, W_out, WaT, WoT);
    k_adjprep<<<32768, 256, 0, stream>>>(adj, adjbit);

    for (int layer = 0; layer < 2; ++layer) {
        const float* xin_l = layer ? xbuf : x;
        k_proj_mfma<<<dim3(128, 8), 256, 0, stream>>>(xin_l, WaT, a_att, hT, f1, f2);
        k_att_fused<<<dim3(NN / 64, BB * HH), 256, 0, stream>>>(adjbit, f1, f2, hT, ybf);
        k_outproj_mfma<<<256, 256, 0, stream>>>(ybf, WoT, a_out, hoT, g1, g2);
        k_out_fused<<<dim3(NN / 16, BB), 256, 0, stream>>>(adjbit, g1, g2, hoT, xin_l,
                                                           tbuf);
        k_mask_ln<<<dim3(NN, BB), 256, 0, stream>>>(tbuf, mask, ln_w, ln_b, xbuf, out,
                                                    layer == 1);
    }
}

// Round 7
// 324.159 us; speedup vs baseline: 6.0785x; 1.0196x over previous
//
#include <hip/hip_runtime.h>
#include <hip/hip_bf16.h>
#include <math.h>

#define BB 8
#define NN 1024
#define FF 256
#define HH 8
#define OO 64
#define CC 256

typedef __attribute__((ext_vector_type(8))) short short8;
typedef __attribute__((ext_vector_type(4))) float f32x4;
typedef unsigned long long u64;

__device__ __forceinline__ short bf16s(float f) {
    __hip_bfloat16 h = __float2bfloat16(f);
    return *reinterpret_cast<short*>(&h);
}

// ---------- adj -> bitmask (1 MB) ----------
__global__ void k_adjprep(const int* __restrict__ adj, u64* __restrict__ adjbit) {
    int i = blockIdx.x * 256 + threadIdx.x;
    u64 m = __ballot(adj[i] > 0);
    if ((threadIdx.x & 63) == 0) adjbit[i >> 6] = m;
}

// ---------- one-time weight transpose+convert ----------
__global__ void k_wprep(const float* __restrict__ Wa, const float* __restrict__ Wo,
                        __hip_bfloat16* __restrict__ WaT, __hip_bfloat16* __restrict__ WoT) {
    int i = blockIdx.x * 256 + threadIdx.x;  // 0..262143
    if (i < 131072) {
        int hd = i >> 14, o = (i >> 8) & 63, f = i & 255;
        WaT[i] = __float2bfloat16(Wa[hd * 16384 + f * 64 + o]);
    } else {
        int j = i - 131072;
        int c = j >> 9, k = j & 511;
        WoT[j] = __float2bfloat16(Wo[k * 256 + c]);
    }
}

// ---------- MFMA proj: h = x @ W_att (per head), fused f1/f2 + bf16 hT write ----
__global__ void k_proj_mfma(const float* __restrict__ x,
                            const __hip_bfloat16* __restrict__ WaT,
                            const float* __restrict__ aatt,
                            __hip_bfloat16* __restrict__ hT,
                            float* __restrict__ f1, float* __restrict__ f2) {
    int tile = blockIdx.x, hd = blockIdx.y;
    int t = threadIdx.x, lane = t & 63, w = t >> 6;
    int r0 = tile * 64;
    int b = r0 >> 10;
    int n0 = r0 & 1023;
    int bh = b * HH + hd;
    int al = lane & 15, ah = lane >> 4;
    const float* xrow = x + (size_t)(r0 + w * 16 + al) * FF;
    const __hip_bfloat16* Wb = WaT + (size_t)hd * OO * FF;
    f32x4 z4 = {0.f, 0.f, 0.f, 0.f};
    f32x4 acc[4] = {z4, z4, z4, z4};
    for (int k0 = 0; k0 < FF; k0 += 32) {
        int k = k0 + ah * 8;
        short8 af;
#pragma unroll
        for (int q = 0; q < 8; ++q) af[q] = bf16s(xrow[k + q]);
#pragma unroll
        for (int cf = 0; cf < 4; ++cf) {
            int col = cf * 16 + al;
            short8 bf = *(const short8*)&Wb[(size_t)col * FF + k];
            acc[cf] = __builtin_amdgcn_mfma_f32_16x16x32_bf16(af, bf, acc[cf], 0, 0, 0);
        }
    }
    int nb = n0 + w * 16 + ah * 4;
#pragma unroll
    for (int cf = 0; cf < 4; ++cf) {
        int col = cf * 16 + al;
        __hip_bfloat16* dst = hT + ((size_t)bh * OO + col) * NN + nb;
#pragma unroll
        for (int r = 0; r < 4; ++r) dst[r] = __float2bfloat16(acc[cf][r]);
    }
    float p1[4] = {0.f, 0.f, 0.f, 0.f}, p2[4] = {0.f, 0.f, 0.f, 0.f};
#pragma unroll
    for (int cf = 0; cf < 4; ++cf) {
        int col = cf * 16 + al;
        float a1 = aatt[hd * 2 * OO + col];
        float a2 = aatt[hd * 2 * OO + OO + col];
#pragma unroll
        for (int r = 0; r < 4; ++r) {
            p1[r] += acc[cf][r] * a1;
            p2[r] += acc[cf][r] * a2;
        }
    }
#pragma unroll
    for (int off = 1; off < 16; off <<= 1) {
#pragma unroll
        for (int r = 0; r < 4; ++r) {
            p1[r] += __shfl_xor(p1[r], off);
            p2[r] += __shfl_xor(p2[r], off);
        }
    }
    if (al == 0) {
#pragma unroll
        for (int r = 0; r < 4; ++r) {
            f1[(size_t)bh * NN + nb + r] = p1[r];
            f2[(size_t)bh * NN + nb + r] = p2[r];
        }
    }
}

// ---------- FUSED att v3: register-direct A fragments, barrier-free K-loop ------
// exp(lrelu(f1+f2)) = max(P*Q, R*S);  A_ij = bit * that;  out = (A@h)/rowsum(A)
__global__ void k_att_fused(const u64* __restrict__ adjbit, const float* __restrict__ f1,
                            const float* __restrict__ f2,
                            const __hip_bfloat16* __restrict__ hT,
                            __hip_bfloat16* __restrict__ ybf) {
    int orig = blockIdx.x;                     // 1024 blocks
    int wgid = (orig & 7) * 128 + (orig >> 3); // XCD-contiguous: 16 tiles/bh on one XCD
    int bh = wgid >> 4;
    int n0 = (wgid & 15) * 64;
    int b = bh >> 3, hd = bh & 7;
    int t = threadIdx.x, lane = t & 63, w = t >> 6;
    __shared__ float Qs[1024], Ss[1024];
    __shared__ u64 bits[64 * 17];
    const float* f2b = f2 + (size_t)bh * NN;
    for (int j = t; j < 1024; j += 256) {
        float v = f2b[j];
        Qs[j] = __expf(v);
        Ss[j] = __expf(0.2f * v);
    }
    for (int e = t; e < 1024; e += 256) {
        int rr = e >> 4, c = e & 15;
        bits[rr * 17 + c] = adjbit[((size_t)b * NN + n0 + rr) * 16 + c];
    }
    int g = lane >> 4, r = lane & 15;
    int row = w * 16 + r;                 // row within the block's 64
    float fl = f1[(size_t)bh * NN + n0 + row];
    float P = __expf(fl), R = __expf(0.2f * fl);
    __syncthreads();
    const __hip_bfloat16* hb = hT + ((size_t)bh * OO + r) * NN;
    f32x4 z4 = {0.f, 0.f, 0.f, 0.f};
    f32x4 acc[4] = {z4, z4, z4, z4};
    float ps = 0.f;
    int c0 = g * 8;
#pragma unroll 2
    for (int k0 = 0; k0 < NN; k0 += 64) {
        u64 m = bits[row * 17 + (k0 >> 6)];
        unsigned bl0 = (unsigned)(m >> c0) & 0xffu;
        unsigned bl1 = (unsigned)(m >> (32 + c0)) & 0xffu;
        // lane builds exactly its own A-fragments: row r, k = c0..c0+7 (+32)
        f32x4 qa0 = *(const f32x4*)&Qs[k0 + c0];
        f32x4 qb0 = *(const f32x4*)&Qs[k0 + c0 + 4];
        f32x4 sa0 = *(const f32x4*)&Ss[k0 + c0];
        f32x4 sb0 = *(const f32x4*)&Ss[k0 + c0 + 4];
        f32x4 qa1 = *(const f32x4*)&Qs[k0 + 32 + c0];
        f32x4 qb1 = *(const f32x4*)&Qs[k0 + 32 + c0 + 4];
        f32x4 sa1 = *(const f32x4*)&Ss[k0 + 32 + c0];
        f32x4 sb1 = *(const f32x4*)&Ss[k0 + 32 + c0 + 4];
        short8 a0, a1;
#pragma unroll
        for (int e = 0; e < 4; ++e) {
            float v0 = ((bl0 >> e) & 1) ? fmaxf(P * qa0[e], R * sa0[e]) : 0.f;
            float v1 = ((bl0 >> (4 + e)) & 1) ? fmaxf(P * qb0[e], R * sb0[e]) : 0.f;
            float v2 = ((bl1 >> e) & 1) ? fmaxf(P * qa1[e], R * sa1[e]) : 0.f;
            float v3 = ((bl1 >> (4 + e)) & 1) ? fmaxf(P * qb1[e], R * sb1[e]) : 0.f;
            ps += (v0 + v1) + (v2 + v3);
            a0[e] = bf16s(v0);
            a0[4 + e] = bf16s(v1);
            a1[e] = bf16s(v2);
            a1[4 + e] = bf16s(v3);
        }
#pragma unroll
        for (int cf = 0; cf < 4; ++cf) {
            const __hip_bfloat16* hc = hb + (size_t)cf * 16 * NN;
            short8 b0 = *(const short8*)&hc[k0 + c0];
            short8 b1 = *(const short8*)&hc[k0 + 32 + c0];
            acc[cf] = __builtin_amdgcn_mfma_f32_16x16x32_bf16(a0, b0, acc[cf], 0, 0, 0);
            acc[cf] = __builtin_amdgcn_mfma_f32_16x16x32_bf16(a1, b1, acc[cf], 0, 0, 0);
        }
    }
    // rowsum over the 4 col-groups (lanes r, r+16, r+32, r+48)
    ps += __shfl_xor(ps, 16);
    ps += __shfl_xor(ps, 32);
#pragma unroll
    for (int rr = 0; rr < 4; ++rr) {
        int rloc = g * 4 + rr;
        float dn = __shfl(ps, rloc);
        float ids = 1.0f / dn;
        int nrow = n0 + w * 16 + rloc;
#pragma unroll
        for (int cf = 0; cf < 4; ++cf) {
            float v = acc[cf][rr] * ids;
            float e = v > 0.f ? v : expm1f(v);
            float yv = e > 0.f ? e : 0.01f * e;
            ybf[((size_t)b * NN + nrow) * 512 + hd * OO + cf * 16 + r] =
                __float2bfloat16(yv);
        }
    }
}

// ---------- MFMA outproj: ho = y @ W_out, fused g1/g2 + bf16 hoT write ----------
__global__ void k_outproj_mfma(const __hip_bfloat16* __restrict__ ybf,
                               const __hip_bfloat16* __restrict__ WoT,
                               const float* __restrict__ ao,
                               __hip_bfloat16* __restrict__ hoT,
                               float* __restrict__ g1, float* __restrict__ g2) {
    int tile = blockIdx.x;
    int t = threadIdx.x, lane = t & 63, w = t >> 6;
    int r0 = tile * 32;
    int b = r0 >> 10, n0 = r0 & 1023;
    __shared__ __align__(16) __hip_bfloat16 As[32][520];
    __shared__ float pg1[4][32], pg2[4][32];
    for (int e = t; e < 2048; e += 256) {
        int row = e >> 6, k8 = (e & 63) * 8;
        *(short8*)&As[row][k8] = *(const short8*)&ybf[(size_t)(r0 + row) * 512 + k8];
    }
    __syncthreads();
    int al = lane & 15, ah = lane >> 4;
    f32x4 z4 = {0.f, 0.f, 0.f, 0.f};
    f32x4 acc0[4] = {z4, z4, z4, z4};
    f32x4 acc1[4] = {z4, z4, z4, z4};
    for (int k0 = 0; k0 < 512; k0 += 32) {
        int k = k0 + ah * 8;
        short8 a0 = *(const short8*)&As[al][k];
        short8 a1 = *(const short8*)&As[16 + al][k];
#pragma unroll
        for (int cf = 0; cf < 4; ++cf) {
            int col = w * 64 + cf * 16 + al;
            short8 bf = *(const short8*)&WoT[(size_t)col * 512 + k];
            acc0[cf] = __builtin_amdgcn_mfma_f32_16x16x32_bf16(a0, bf, acc0[cf], 0, 0, 0);
            acc1[cf] = __builtin_amdgcn_mfma_f32_16x16x32_bf16(a1, bf, acc1[cf], 0, 0, 0);
        }
    }
    float q1[8] = {0.f, 0.f, 0.f, 0.f, 0.f, 0.f, 0.f, 0.f};
    float q2[8] = {0.f, 0.f, 0.f, 0.f, 0.f, 0.f, 0.f, 0.f};
#pragma unroll
    for (int cf = 0; cf < 4; ++cf) {
        int col = w * 64 + cf * 16 + al;
        float a1v = ao[col], a2v = ao[CC + col];
        __hip_bfloat16* dst = hoT + ((size_t)b * CC + col) * NN + n0 + ah * 4;
#pragma unroll
        for (int r = 0; r < 4; ++r) {
            dst[r] = __float2bfloat16(acc0[cf][r]);
            dst[16 + r] = __float2bfloat16(acc1[cf][r]);
            q1[r] += acc0[cf][r] * a1v;
            q2[r] += acc0[cf][r] * a2v;
            q1[4 + r] += acc1[cf][r] * a1v;
            q2[4 + r] += acc1[cf][r] * a2v;
        }
    }
#pragma unroll
    for (int off = 1; off < 16; off <<= 1) {
#pragma unroll
        for (int j = 0; j < 8; ++j) {
            q1[j] += __shfl_xor(q1[j], off);
            q2[j] += __shfl_xor(q2[j], off);
        }
    }
    if (al == 0) {
#pragma unroll
        for (int j = 0; j < 8; ++j) {
            int row = (j >> 2) * 16 + ah * 4 + (j & 3);
            pg1[w][row] = q1[j];
            pg2[w][row] = q2[j];
        }
    }
    __syncthreads();
    if (t < 32) {
        g1[r0 + t] = pg1[0][t] + pg1[1][t] + pg1[2][t] + pg1[3][t];
        g2[r0 + t] = pg2[0][t] + pg2[1][t] + pg2[2][t] + pg2[3][t];
    }
}

// ---------- FUSED out v3: K=256 staging + fmax identity + XCD swizzle ----------
__global__ void k_out_fused(const u64* __restrict__ adjbit, const float* __restrict__ g1,
                            const float* __restrict__ g2,
                            const __hip_bfloat16* __restrict__ hoT,
                            const float* __restrict__ xin, float* __restrict__ tout) {
    int orig = blockIdx.x;                    // 512 blocks
    int wgid = (orig & 7) * 64 + (orig >> 3); // all 64 tiles of one b on one XCD
    int b = wgid >> 6;
    int n0 = (wgid & 63) * 16;
    int t = threadIdx.x, lane = t & 63, w = t >> 6;
    __shared__ float Qs[1024], Ss[1024];
    __shared__ u64 bits[16 * 17];
    __shared__ __align__(16) __hip_bfloat16 As[16][264];  // 16 x 256 K-window
    __shared__ float psum[4][16];
    const float* g2b = g2 + (size_t)b * NN;
    for (int j = t; j < 1024; j += 256) {
        float v = g2b[j];
        Qs[j] = __expf(v);
        Ss[j] = __expf(0.2f * v);
    }
    {
        int rr = t >> 4, c = t & 15;
        bits[rr * 17 + c] = adjbit[((size_t)b * NN + n0 + rr) * 16 + c];
    }
    int br = t & 15, kg = t >> 4;   // builder: row br, window-cols kg*16..+15
    float gl = g1[(size_t)b * NN + n0 + br];
    float P = __expf(gl);
    float R = __expf(0.2f * gl);
    int ar = lane & 15, g = lane >> 4;
    const __hip_bfloat16* hw = hoT + ((size_t)b * CC + w * 64 + ar) * NN;
    f32x4 z4 = {0.f, 0.f, 0.f, 0.f};
    f32x4 acc[4] = {z4, z4, z4, z4};
    float ps = 0.f;
    __syncthreads();
    for (int ks = 0; ks < NN; ks += 256) {
        u64 m = bits[br * 17 + (ks >> 6) + (kg >> 2)];
        int sh = (kg & 3) * 16;
        short8 vv[2];
#pragma unroll
        for (int h = 0; h < 2; ++h) {
            short8 vx;
#pragma unroll
            for (int e4 = 0; e4 < 2; ++e4) {
                int cw = kg * 16 + h * 8 + e4 * 4;
                f32x4 q4 = *(const f32x4*)&Qs[ks + cw];
                f32x4 s4 = *(const f32x4*)&Ss[ks + cw];
#pragma unroll
                for (int e = 0; e < 4; ++e) {
                    float val = ((m >> (sh + h * 8 + e4 * 4 + e)) & 1)
                                    ? fmaxf(P * q4[e], R * s4[e]) : 0.f;
                    ps += val;
                    vx[e4 * 4 + e] = bf16s(val);
                }
            }
            vv[h] = vx;
        }
        *(short8*)&As[br][kg * 16] = vv[0];
        *(short8*)&As[br][kg * 16 + 8] = vv[1];
        __syncthreads();
#pragma unroll
        for (int ksub = 0; ksub < 4; ++ksub) {
            short8 a0 = *(const short8*)&As[ar][ksub * 64 + g * 8];
            short8 a1 = *(const short8*)&As[ar][ksub * 64 + 32 + g * 8];
#pragma unroll
            for (int cf = 0; cf < 4; ++cf) {
                const __hip_bfloat16* hc = hw + (size_t)cf * 16 * NN;
                short8 b0 = *(const short8*)&hc[ks + ksub * 64 + g * 8];
                short8 b1 = *(const short8*)&hc[ks + ksub * 64 + 32 + g * 8];
                acc[cf] = __builtin_amdgcn_mfma_f32_16x16x32_bf16(a0, b0, acc[cf], 0, 0, 0);
                acc[cf] = __builtin_amdgcn_mfma_f32_16x16x32_bf16(a1, b1, acc[cf], 0, 0, 0);
            }
        }
        __syncthreads();
    }
    ps += __shfl_xor(ps, 16);
    ps += __shfl_xor(ps, 32);
    if (lane < 16) psum[w][lane] = ps;
    __syncthreads();
#pragma unroll
    for (int rr = 0; rr < 4; ++rr) {
        int rloc = g * 4 + rr;
        float dn = psum[0][rloc] + psum[1][rloc] + psum[2][rloc] + psum[3][rloc];
        float ids = 1.0f / dn;
        size_t rowo = ((size_t)b * NN + n0 + rloc) * CC;
#pragma unroll
        for (int cf = 0; cf < 4; ++cf) {
            int col = w * 64 + cf * 16 + ar;
            float v = acc[cf][rr] * ids;
            float e = v > 0.f ? v : expm1f(v);
            tout[rowo + col] = xin[rowo + col] + e;
        }
    }
}

// ---------- mask + layernorm (+ optional final relu outputs) ----------
__global__ void k_mask_ln(const float* __restrict__ tin, const int* __restrict__ mask,
                          const float* __restrict__ lw, const float* __restrict__ lb,
                          float* __restrict__ xout, float* __restrict__ outf, int final_) {
    int n = blockIdx.x, b = blockIdx.y, t = threadIdx.x;
    int lane = t & 63, w = t >> 6;
    float v = (mask[b * NN + n] == 0) ? 0.f : tin[((size_t)b * NN + n) * CC + t];
    __shared__ float r1[4], r2[4];
    float s = v;
    for (int off = 32; off; off >>= 1) s += __shfl_xor(s, off);
    if (lane == 0) r1[w] = s;
    __syncthreads();
    float mu = (r1[0] + r1[1] + r1[2] + r1[3]) * (1.0f / CC);
    float d = v - mu;
    float q = d * d;
    for (int off = 32; off; off >>= 1) q += __shfl_xor(q, off);
    if (lane == 0) r2[w] = q;
    __syncthreads();
    float var = (r2[0] + r2[1] + r2[2] + r2[3]) * (1.0f / CC);
    float ln = d * rsqrtf(var + 1e-5f) * lw[t] + lb[t];
    size_t idx = ((size_t)b * NN + n) * CC + t;
    if (final_) {
        float rv = ln > 0.f ? ln : 0.f;
        outf[idx] = rv;
        if (n == 0) outf[(size_t)BB * NN * CC + b * CC + t] = rv;
    } else {
        xout[idx] = ln;
    }
}

extern "C" void kernel_launch(void* const* d_in, const int* in_sizes, int n_in,
                              void* d_out, int out_size, void* d_ws, size_t ws_size,
                              hipStream_t stream) {
    const float* x = (const float*)d_in[0];
    const int* adj = (const int*)d_in[1];
    const int* mask = (const int*)d_in[2];
    const float* W_att = (const float*)d_in[3];
    const float* a_att = (const float*)d_in[4];
    const float* W_out = (const float*)d_in[5];
    const float* a_out = (const float*)d_in[6];
    const float* ln_w = (const float*)d_in[7];
    const float* ln_b = (const float*)d_in[8];
    float* out = (float*)d_out;

    float* ws = (float*)d_ws;
    float* xbuf = ws;                          // 2,097,152 f32
    float* tbuf = xbuf + 2097152;              // 2,097,152 f32
    float* f1   = tbuf + 2097152;              // 65,536
    float* f2   = f1 + 65536;                  // 65,536
    float* g1   = f2 + 65536;                  // 8,192
    float* g2   = g1 + 8192;                   // 8,192
    float* p    = g2 + 8192;
    __hip_bfloat16* hT  = (__hip_bfloat16*)p;             // 4,194,304 bf16
    __hip_bfloat16* ybf = (__hip_bfloat16*)(p + 2097152); // 4,194,304 bf16
    __hip_bfloat16* hoT = (__hip_bfloat16*)(p + 4194304); // 2,097,152 bf16
    __hip_bfloat16* WaT = (__hip_bfloat16*)(p + 5242880); // 131,072 bf16
    __hip_bfloat16* WoT = (__hip_bfloat16*)(p + 5308416); // 131,072 bf16
    u64* adjbit = (u64*)(p + 5373952);                    // 131,072 u64 (1 MB)

    k_wprep<<<1024, 256, 0, stream>>>(W_att, W_out, WaT, WoT);
    k_adjprep<<<32768, 256, 0, stream>>>(adj, adjbit);

    for (int layer = 0; layer < 2; ++layer) {
        const float* xin_l = layer ? xbuf : x;
        k_proj_mfma<<<dim3(128, 8), 256, 0, stream>>>(xin_l, WaT, a_att, hT, f1, f2);
        k_att_fused<<<1024, 256, 0, stream>>>(adjbit, f1, f2, hT, ybf);
        k_outproj_mfma<<<256, 256, 0, stream>>>(ybf, WoT, a_out, hoT, g1, g2);
        k_out_fused<<<512, 256, 0, stream>>>(adjbit, g1, g2, hoT, xin_l, tbuf);
        k_mask_ln<<<dim3(NN, BB), 256, 0, stream>>>(tbuf, mask, ln_w, ln_b, xbuf, out,
                                                    layer == 1);
    }
}

// Round 9
// 239.315 us; speedup vs baseline: 8.2335x; 1.3545x over previous
//
#include <hip/hip_runtime.h>
#include <hip/hip_bf16.h>
#include <math.h>

#define BB 8
#define NN 1024
#define FF 256
#define HH 8
#define OO 64
#define CC 256

typedef __attribute__((ext_vector_type(8))) short short8;
typedef __attribute__((ext_vector_type(4))) short s16x4;
typedef __attribute__((ext_vector_type(4))) float f32x4;
typedef unsigned long long u64;

__device__ __forceinline__ short bf16s(float f) {
    __hip_bfloat16 h = __float2bfloat16(f);
    return *reinterpret_cast<short*>(&h);
}

// ---------- adj -> bitmask (1 MB) ----------
__global__ void k_adjprep(const int* __restrict__ adj, u64* __restrict__ adjbit) {
    int i = blockIdx.x * 256 + threadIdx.x;
    u64 m = __ballot(adj[i] > 0);
    if ((threadIdx.x & 63) == 0) adjbit[i >> 6] = m;
}

// ---------- one-time weight transpose+convert ----------
__global__ void k_wprep(const float* __restrict__ Wa, const float* __restrict__ Wo,
                        __hip_bfloat16* __restrict__ WaT, __hip_bfloat16* __restrict__ WoT) {
    int i = blockIdx.x * 256 + threadIdx.x;  // 0..262143
    if (i < 131072) {
        int hd = i >> 14, o = (i >> 8) & 63, f = i & 255;
        WaT[i] = __float2bfloat16(Wa[hd * 16384 + f * 64 + o]);
    } else {
        int j = i - 131072;
        int c = j >> 9, k = j & 511;
        WoT[j] = __float2bfloat16(Wo[k * 256 + c]);
    }
}

// ---------- MFMA proj: h = x @ W_att, fused f1/f2; h stored FRAGMENT-MAJOR ----
// hF block (bh, kw, cf, half) of 512 bf16: elem (g*16+r)*8+q holds
// h[n = kw*64 + half*32 + g*8 + q][o = cf*16 + r].
__global__ void k_proj_mfma(const float* __restrict__ x,
                            const __hip_bfloat16* __restrict__ WaT,
                            const float* __restrict__ aatt,
                            __hip_bfloat16* __restrict__ hF,
                            float* __restrict__ f1, float* __restrict__ f2) {
    int tile = blockIdx.x, hd = blockIdx.y;
    int t = threadIdx.x, lane = t & 63, w = t >> 6;
    int r0 = tile * 64;
    int b = r0 >> 10;
    int n0 = r0 & 1023;
    int bh = b * HH + hd;
    int al = lane & 15, ah = lane >> 4;
    const float* xrow = x + (size_t)(r0 + w * 16 + al) * FF;
    const __hip_bfloat16* Wb = WaT + (size_t)hd * OO * FF;
    f32x4 z4 = {0.f, 0.f, 0.f, 0.f};
    f32x4 acc[4] = {z4, z4, z4, z4};
    for (int k0 = 0; k0 < FF; k0 += 32) {
        int k = k0 + ah * 8;
        short8 af;
#pragma unroll
        for (int q = 0; q < 8; ++q) af[q] = bf16s(xrow[k + q]);
#pragma unroll
        for (int cf = 0; cf < 4; ++cf) {
            int col = cf * 16 + al;
            short8 bf = *(const short8*)&Wb[(size_t)col * FF + k];
            acc[cf] = __builtin_amdgcn_mfma_f32_16x16x32_bf16(af, bf, acc[cf], 0, 0, 0);
        }
    }
    // fragment-major write: local row nl = w*16 + ah*4 + r  ->  half,g,q
    int kw = tile & 15;
    int half = w >> 1;
    int hg = (w & 1) * 2 + (ah >> 1);
    int q0 = (ah & 1) * 4;
#pragma unroll
    for (int cf = 0; cf < 4; ++cf) {
        size_t base = ((((size_t)bh * 16 + kw) * 4 + cf) * 2 + half) * 512 +
                      (hg * 16 + al) * 8 + q0;
        s16x4 v;
#pragma unroll
        for (int r = 0; r < 4; ++r) v[r] = bf16s(acc[cf][r]);
        *(s16x4*)&hF[base] = v;
    }
    // fused f1/f2
    int nb = n0 + w * 16 + ah * 4;
    float p1[4] = {0.f, 0.f, 0.f, 0.f}, p2[4] = {0.f, 0.f, 0.f, 0.f};
#pragma unroll
    for (int cf = 0; cf < 4; ++cf) {
        int col = cf * 16 + al;
        float a1 = aatt[hd * 2 * OO + col];
        float a2 = aatt[hd * 2 * OO + OO + col];
#pragma unroll
        for (int r = 0; r < 4; ++r) {
            p1[r] += acc[cf][r] * a1;
            p2[r] += acc[cf][r] * a2;
        }
    }
#pragma unroll
    for (int off = 1; off < 16; off <<= 1) {
#pragma unroll
        for (int r = 0; r < 4; ++r) {
            p1[r] += __shfl_xor(p1[r], off);
            p2[r] += __shfl_xor(p2[r], off);
        }
    }
    if (al == 0) {
#pragma unroll
        for (int r = 0; r < 4; ++r) {
            f1[(size_t)bh * NN + nb + r] = p1[r];
            f2[(size_t)bh * NN + nb + r] = p2[r];
        }
    }
}

// ---------- FUSED att v4: register A + fragment-major coalesced B reads ---------
__global__ void k_att_fused(const u64* __restrict__ adjbit, const float* __restrict__ f1,
                            const float* __restrict__ f2,
                            const __hip_bfloat16* __restrict__ hF,
                            __hip_bfloat16* __restrict__ ybf) {
    int orig = blockIdx.x;                     // 1024 blocks
    int wgid = (orig & 7) * 128 + (orig >> 3); // XCD-contiguous: 16 tiles/bh per XCD
    int bh = wgid >> 4;
    int n0 = (wgid & 15) * 64;
    int b = bh >> 3, hd = bh & 7;
    int t = threadIdx.x, lane = t & 63, w = t >> 6;
    __shared__ float Qs[1024], Ss[1024];
    __shared__ u64 bits[64 * 17];
    const float* f2b = f2 + (size_t)bh * NN;
    for (int j = t; j < 1024; j += 256) {
        float v = f2b[j];
        Qs[j] = __expf(v);
        Ss[j] = __expf(0.2f * v);
    }
    for (int e = t; e < 1024; e += 256) {
        int rr = e >> 4, c = e & 15;
        bits[rr * 17 + c] = adjbit[((size_t)b * NN + n0 + rr) * 16 + c];
    }
    int g = lane >> 4, r = lane & 15;
    int row = w * 16 + r;
    float fl = f1[(size_t)bh * NN + n0 + row];
    float P = __expf(fl), R = __expf(0.2f * fl);
    __syncthreads();
    const __hip_bfloat16* hFb = hF + (size_t)bh * 16 * 4 * 2 * 512 + lane * 8;
    f32x4 z4 = {0.f, 0.f, 0.f, 0.f};
    f32x4 acc[4] = {z4, z4, z4, z4};
    float ps = 0.f;
    int c0 = g * 8;
#pragma unroll 2
    for (int k0 = 0; k0 < NN; k0 += 64) {
        int kw = k0 >> 6;
        u64 m = bits[row * 17 + kw];
        unsigned bl0 = (unsigned)(m >> c0) & 0xffu;
        unsigned bl1 = (unsigned)(m >> (32 + c0)) & 0xffu;
        f32x4 qa0 = *(const f32x4*)&Qs[k0 + c0];
        f32x4 qb0 = *(const f32x4*)&Qs[k0 + c0 + 4];
        f32x4 sa0 = *(const f32x4*)&Ss[k0 + c0];
        f32x4 sb0 = *(const f32x4*)&Ss[k0 + c0 + 4];
        f32x4 qa1 = *(const f32x4*)&Qs[k0 + 32 + c0];
        f32x4 qb1 = *(const f32x4*)&Qs[k0 + 32 + c0 + 4];
        f32x4 sa1 = *(const f32x4*)&Ss[k0 + 32 + c0];
        f32x4 sb1 = *(const f32x4*)&Ss[k0 + 32 + c0 + 4];
        short8 a0, a1;
#pragma unroll
        for (int e = 0; e < 4; ++e) {
            float v0 = ((bl0 >> e) & 1) ? fmaxf(P * qa0[e], R * sa0[e]) : 0.f;
            float v1 = ((bl0 >> (4 + e)) & 1) ? fmaxf(P * qb0[e], R * sb0[e]) : 0.f;
            float v2 = ((bl1 >> e) & 1) ? fmaxf(P * qa1[e], R * sa1[e]) : 0.f;
            float v3 = ((bl1 >> (4 + e)) & 1) ? fmaxf(P * qb1[e], R * sb1[e]) : 0.f;
            ps += (v0 + v1) + (v2 + v3);
            a0[e] = bf16s(v0);
            a0[4 + e] = bf16s(v1);
            a1[e] = bf16s(v2);
            a1[4 + e] = bf16s(v3);
        }
#pragma unroll
        for (int cf = 0; cf < 4; ++cf) {
            const __hip_bfloat16* blk = hFb + ((size_t)(kw * 4 + cf) * 2) * 512;
            short8 b0 = *(const short8*)&blk[0];
            short8 b1 = *(const short8*)&blk[512];
            acc[cf] = __builtin_amdgcn_mfma_f32_16x16x32_bf16(a0, b0, acc[cf], 0, 0, 0);
            acc[cf] = __builtin_amdgcn_mfma_f32_16x16x32_bf16(a1, b1, acc[cf], 0, 0, 0);
        }
    }
    ps += __shfl_xor(ps, 16);
    ps += __shfl_xor(ps, 32);
#pragma unroll
    for (int rr = 0; rr < 4; ++rr) {
        int rloc = g * 4 + rr;
        float dn = __shfl(ps, rloc);
        float ids = 1.0f / dn;
        int nrow = n0 + w * 16 + rloc;
#pragma unroll
        for (int cf = 0; cf < 4; ++cf) {
            float v = acc[cf][rr] * ids;
            float e = v > 0.f ? v : expm1f(v);
            float yv = e > 0.f ? e : 0.01f * e;
            ybf[((size_t)b * NN + nrow) * 512 + hd * OO + cf * 16 + r] =
                __float2bfloat16(yv);
        }
    }
}

// ---------- MFMA outproj: ho = y @ W_out, fused g1/g2; ho stored FRAGMENT-MAJOR -
// hoF block (b, kw, cfB, half) of 512 bf16: elem (g*16+r)*8+q holds
// ho[n = kw*64 + half*32 + g*8 + q][c = cfB*16 + r].
__global__ void k_outproj_mfma(const __hip_bfloat16* __restrict__ ybf,
                               const __hip_bfloat16* __restrict__ WoT,
                               const float* __restrict__ ao,
                               __hip_bfloat16* __restrict__ hoF,
                               float* __restrict__ g1, float* __restrict__ g2) {
    int tile = blockIdx.x;
    int t = threadIdx.x, lane = t & 63, w = t >> 6;
    int r0 = tile * 32;
    int b = r0 >> 10;
    __shared__ __align__(16) __hip_bfloat16 As[32][520];
    __shared__ float pg1[4][32], pg2[4][32];
    for (int e = t; e < 2048; e += 256) {
        int row = e >> 6, k8 = (e & 63) * 8;
        *(short8*)&As[row][k8] = *(const short8*)&ybf[(size_t)(r0 + row) * 512 + k8];
    }
    __syncthreads();
    int al = lane & 15, ah = lane >> 4;
    f32x4 z4 = {0.f, 0.f, 0.f, 0.f};
    f32x4 acc0[4] = {z4, z4, z4, z4};
    f32x4 acc1[4] = {z4, z4, z4, z4};
    for (int k0 = 0; k0 < 512; k0 += 32) {
        int k = k0 + ah * 8;
        short8 a0 = *(const short8*)&As[al][k];
        short8 a1 = *(const short8*)&As[16 + al][k];
#pragma unroll
        for (int cf = 0; cf < 4; ++cf) {
            int col = w * 64 + cf * 16 + al;
            short8 bf = *(const short8*)&WoT[(size_t)col * 512 + k];
            acc0[cf] = __builtin_amdgcn_mfma_f32_16x16x32_bf16(a0, bf, acc0[cf], 0, 0, 0);
            acc1[cf] = __builtin_amdgcn_mfma_f32_16x16x32_bf16(a1, bf, acc1[cf], 0, 0, 0);
        }
    }
    // fragment-major hoF writes + g partials
    // BUGFIX (r8): kw must be local to batch b: n0 = (tile&31)*32 -> kw=(tile&31)>>1
    int kw = (tile >> 1) & 15;
    int half = tile & 1;
    int hg0 = ah >> 1;
    int q0 = (ah & 1) * 4;
    float q1[8] = {0.f, 0.f, 0.f, 0.f, 0.f, 0.f, 0.f, 0.f};
    float q2[8] = {0.f, 0.f, 0.f, 0.f, 0.f, 0.f, 0.f, 0.f};
#pragma unroll
    for (int cf = 0; cf < 4; ++cf) {
        int col = w * 64 + cf * 16 + al;
        int cfB = w * 4 + cf;
        float a1v = ao[col], a2v = ao[CC + col];
        size_t base = ((((size_t)b * 16 + kw) * 16 + cfB) * 2 + half) * 512;
        s16x4 v0, v1;
#pragma unroll
        for (int r = 0; r < 4; ++r) {
            v0[r] = bf16s(acc0[cf][r]);
            v1[r] = bf16s(acc1[cf][r]);
            q1[r] += acc0[cf][r] * a1v;
            q2[r] += acc0[cf][r] * a2v;
            q1[4 + r] += acc1[cf][r] * a1v;
            q2[4 + r] += acc1[cf][r] * a2v;
        }
        *(s16x4*)&hoF[base + (hg0 * 16 + al) * 8 + q0] = v0;
        *(s16x4*)&hoF[base + ((hg0 + 2) * 16 + al) * 8 + q0] = v1;
    }
#pragma unroll
    for (int off = 1; off < 16; off <<= 1) {
#pragma unroll
        for (int j = 0; j < 8; ++j) {
            q1[j] += __shfl_xor(q1[j], off);
            q2[j] += __shfl_xor(q2[j], off);
        }
    }
    if (al == 0) {
#pragma unroll
        for (int j = 0; j < 8; ++j) {
            int row = (j >> 2) * 16 + ah * 4 + (j & 3);
            pg1[w][row] = q1[j];
            pg2[w][row] = q2[j];
        }
    }
    __syncthreads();
    if (t < 32) {
        g1[r0 + t] = pg1[0][t] + pg1[1][t] + pg1[2][t] + pg1[3][t];
        g2[r0 + t] = pg2[0][t] + pg2[1][t] + pg2[2][t] + pg2[3][t];
    }
}

// ---------- FUSED out v4: K=256 staging + fragment-major coalesced B reads ------
__global__ void k_out_fused(const u64* __restrict__ adjbit, const float* __restrict__ g1,
                            const float* __restrict__ g2,
                            const __hip_bfloat16* __restrict__ hoF,
                            const float* __restrict__ xin, float* __restrict__ tout) {
    int orig = blockIdx.x;                    // 512 blocks
    int wgid = (orig & 7) * 64 + (orig >> 3);
    int b = wgid >> 6;
    int n0 = (wgid & 63) * 16;
    int t = threadIdx.x, lane = t & 63, w = t >> 6;
    __shared__ float Qs[1024], Ss[1024];
    __shared__ u64 bits[16 * 17];
    __shared__ __align__(16) __hip_bfloat16 As[16][264];
    __shared__ float psum[4][16];
    const float* g2b = g2 + (size_t)b * NN;
    for (int j = t; j < 1024; j += 256) {
        float v = g2b[j];
        Qs[j] = __expf(v);
        Ss[j] = __expf(0.2f * v);
    }
    {
        int rr = t >> 4, c = t & 15;
        bits[rr * 17 + c] = adjbit[((size_t)b * NN + n0 + rr) * 16 + c];
    }
    int br = t & 15, kg = t >> 4;
    float gl = g1[(size_t)b * NN + n0 + br];
    float P = __expf(gl);
    float R = __expf(0.2f * gl);
    int ar = lane & 15, g = lane >> 4;
    const __hip_bfloat16* hoFb = hoF + (size_t)b * 16 * 16 * 2 * 512 + lane * 8;
    f32x4 z4 = {0.f, 0.f, 0.f, 0.f};
    f32x4 acc[4] = {z4, z4, z4, z4};
    float ps = 0.f;
    __syncthreads();
    for (int ks = 0; ks < NN; ks += 256) {
        u64 m = bits[br * 17 + (ks >> 6) + (kg >> 2)];
        int sh = (kg & 3) * 16;
        short8 vv[2];
#pragma unroll
        for (int h = 0; h < 2; ++h) {
            short8 vx;
#pragma unroll
            for (int e4 = 0; e4 < 2; ++e4) {
                int cw = kg * 16 + h * 8 + e4 * 4;
                f32x4 q4 = *(const f32x4*)&Qs[ks + cw];
                f32x4 s4 = *(const f32x4*)&Ss[ks + cw];
#pragma unroll
                for (int e = 0; e < 4; ++e) {
                    float val = ((m >> (sh + h * 8 + e4 * 4 + e)) & 1)
                                    ? fmaxf(P * q4[e], R * s4[e]) : 0.f;
                    ps += val;
                    vx[e4 * 4 + e] = bf16s(val);
                }
            }
            vv[h] = vx;
        }
        *(short8*)&As[br][kg * 16] = vv[0];
        *(short8*)&As[br][kg * 16 + 8] = vv[1];
        __syncthreads();
#pragma unroll
        for (int ksub = 0; ksub < 4; ++ksub) {
            int kw = (ks >> 6) + ksub;
            short8 a0 = *(const short8*)&As[ar][ksub * 64 + g * 8];
            short8 a1 = *(const short8*)&As[ar][ksub * 64 + 32 + g * 8];
#pragma unroll
            for (int cf = 0; cf < 4; ++cf) {
                int cfB = w * 4 + cf;
                const __hip_bfloat16* blk = hoFb + ((size_t)(kw * 16 + cfB) * 2) * 512;
                short8 b0 = *(const short8*)&blk[0];
                short8 b1 = *(const short8*)&blk[512];
                acc[cf] = __builtin_amdgcn_mfma_f32_16x16x32_bf16(a0, b0, acc[cf], 0, 0, 0);
                acc[cf] = __builtin_amdgcn_mfma_f32_16x16x32_bf16(a1, b1, acc[cf], 0, 0, 0);
            }
        }
        __syncthreads();
    }
    ps += __shfl_xor(ps, 16);
    ps += __shfl_xor(ps, 32);
    if (lane < 16) psum[w][lane] = ps;
    __syncthreads();
#pragma unroll
    for (int rr = 0; rr < 4; ++rr) {
        int rloc = g * 4 + rr;
        float dn = psum[0][rloc] + psum[1][rloc] + psum[2][rloc] + psum[3][rloc];
        float ids = 1.0f / dn;
        size_t rowo = ((size_t)b * NN + n0 + rloc) * CC;
#pragma unroll
        for (int cf = 0; cf < 4; ++cf) {
            int col = w * 64 + cf * 16 + ar;
            float v = acc[cf][rr] * ids;
            float e = v > 0.f ? v : expm1f(v);
            tout[rowo + col] = xin[rowo + col] + e;
        }
    }
}

// ---------- mask + layernorm (+ optional final relu outputs) ----------
__global__ void k_mask_ln(const float* __restrict__ tin, const int* __restrict__ mask,
                          const float* __restrict__ lw, const float* __restrict__ lb,
                          float* __restrict__ xout, float* __restrict__ outf, int final_) {
    int n = blockIdx.x, b = blockIdx.y, t = threadIdx.x;
    int lane = t & 63, w = t >> 6;
    float v = (mask[b * NN + n] == 0) ? 0.f : tin[((size_t)b * NN + n) * CC + t];
    __shared__ float r1[4], r2[4];
    float s = v;
    for (int off = 32; off; off >>= 1) s += __shfl_xor(s, off);
    if (lane == 0) r1[w] = s;
    __syncthreads();
    float mu = (r1[0] + r1[1] + r1[2] + r1[3]) * (1.0f / CC);
    float d = v - mu;
    float q = d * d;
    for (int off = 32; off; off >>= 1) q += __shfl_xor(q, off);
    if (lane == 0) r2[w] = q;
    __syncthreads();
    float var = (r2[0] + r2[1] + r2[2] + r2[3]) * (1.0f / CC);
    float ln = d * rsqrtf(var + 1e-5f) * lw[t] + lb[t];
    size_t idx = ((size_t)b * NN + n) * CC + t;
    if (final_) {
        float rv = ln > 0.f ? ln : 0.f;
        outf[idx] = rv;
        if (n == 0) outf[(size_t)BB * NN * CC + b * CC + t] = rv;
    } else {
        xout[idx] = ln;
    }
}

extern "C" void kernel_launch(void* const* d_in, const int* in_sizes, int n_in,
                              void* d_out, int out_size, void* d_ws, size_t ws_size,
                              hipStream_t stream) {
    const float* x = (const float*)d_in[0];
    const int* adj = (const int*)d_in[1];
    const int* mask = (const int*)d_in[2];
    const float* W_att = (const float*)d_in[3];
    const float* a_att = (const float*)d_in[4];
    const float* W_out = (const float*)d_in[5];
    const float* a_out = (const float*)d_in[6];
    const float* ln_w = (const float*)d_in[7];
    const float* ln_b = (const float*)d_in[8];
    float* out = (float*)d_out;

    float* ws = (float*)d_ws;
    float* xbuf = ws;                          // 2,097,152 f32
    float* tbuf = xbuf + 2097152;              // 2,097,152 f32
    float* f1   = tbuf + 2097152;              // 65,536
    float* f2   = f1 + 65536;                  // 65,536
    float* g1   = f2 + 65536;                  // 8,192
    float* g2   = g1 + 8192;                   // 8,192
    float* p    = g2 + 8192;
    __hip_bfloat16* hF  = (__hip_bfloat16*)p;             // 4,194,304 bf16 (8 MB)
    __hip_bfloat16* ybf = (__hip_bfloat16*)(p + 2097152); // 4,194,304 bf16
    __hip_bfloat16* hoF = (__hip_bfloat16*)(p + 4194304); // 2,097,152 bf16 (4 MB)
    __hip_bfloat16* WaT = (__hip_bfloat16*)(p + 5242880); // 131,072 bf16
    __hip_bfloat16* WoT = (__hip_bfloat16*)(p + 5308416); // 131,072 bf16
    u64* adjbit = (u64*)(p + 5373952);                    // 131,072 u64 (1 MB)

    k_wprep<<<1024, 256, 0, stream>>>(W_att, W_out, WaT, WoT);
    k_adjprep<<<32768, 256, 0, stream>>>(adj, adjbit);

    for (int layer = 0; layer < 2; ++layer) {
        const float* xin_l = layer ? xbuf : x;
        k_proj_mfma<<<dim3(128, 8), 256, 0, stream>>>(xin_l, WaT, a_att, hF, f1, f2);
        k_att_fused<<<1024, 256, 0, stream>>>(adjbit, f1, f2, hF, ybf);
        k_outproj_mfma<<<256, 256, 0, stream>>>(ybf, WoT, a_out, hoF, g1, g2);
        k_out_fused<<<512, 256, 0, stream>>>(adjbit, g1, g2, hoF, xin_l, tbuf);
        k_mask_ln<<<dim3(NN, BB), 256, 0, stream>>>(tbuf, mask, ln_w, ln_b, xbuf, out,
                                                    layer == 1);
    }
}

// Round 10
// 226.359 us; speedup vs baseline: 8.7048x; 1.0572x over previous
//
#include <hip/hip_runtime.h>
#include <hip/hip_bf16.h>
#include <math.h>

#define BB 8
#define NN 1024
#define FF 256
#define HH 8
#define OO 64
#define CC 256

typedef __attribute__((ext_vector_type(8))) short short8;
typedef __attribute__((ext_vector_type(4))) short s16x4;
typedef __attribute__((ext_vector_type(4))) float f32x4;
typedef unsigned long long u64;

__device__ __forceinline__ short bf16s(float f) {
    __hip_bfloat16 h = __float2bfloat16(f);
    return *reinterpret_cast<short*>(&h);
}

// ---------- x -> bf16 ----------
__global__ void k_xprep(const float* __restrict__ x, __hip_bfloat16* __restrict__ xbf) {
    int i = blockIdx.x * 256 + threadIdx.x;
    xbf[i] = __float2bfloat16(x[i]);
}

// ---------- adj -> bitmask (1 MB) ----------
__global__ void k_adjprep(const int* __restrict__ adj, u64* __restrict__ adjbit) {
    int i = blockIdx.x * 256 + threadIdx.x;
    u64 m = __ballot(adj[i] > 0);
    if ((threadIdx.x & 63) == 0) adjbit[i >> 6] = m;
}

// ---------- one-time weight transpose+convert ----------
__global__ void k_wprep(const float* __restrict__ Wa, const float* __restrict__ Wo,
                        __hip_bfloat16* __restrict__ WaT, __hip_bfloat16* __restrict__ WoT) {
    int i = blockIdx.x * 256 + threadIdx.x;  // 0..262143
    if (i < 131072) {
        int hd = i >> 14, o = (i >> 8) & 63, f = i & 255;
        WaT[i] = __float2bfloat16(Wa[hd * 16384 + f * 64 + o]);
    } else {
        int j = i - 131072;
        int c = j >> 9, k = j & 511;
        WoT[j] = __float2bfloat16(Wo[k * 256 + c]);
    }
}

// ---------- MFMA proj: h = xbf @ W_att, fused f1/f2; h stored FRAGMENT-MAJOR ----
// hF block (bh, kw, cf, half) of 512 bf16: elem (g*16+r)*8+q holds
// h[n = kw*64 + half*32 + g*8 + q][o = cf*16 + r].
__global__ void k_proj_mfma(const __hip_bfloat16* __restrict__ xbf,
                            const __hip_bfloat16* __restrict__ WaT,
                            const float* __restrict__ aatt,
                            __hip_bfloat16* __restrict__ hF,
                            float* __restrict__ f1, float* __restrict__ f2) {
    int tile = blockIdx.x, hd = blockIdx.y;
    int t = threadIdx.x, lane = t & 63, w = t >> 6;
    int r0 = tile * 64;
    int b = r0 >> 10;
    int n0 = r0 & 1023;
    int bh = b * HH + hd;
    int al = lane & 15, ah = lane >> 4;
    const __hip_bfloat16* xrow = xbf + (size_t)(r0 + w * 16 + al) * FF;
    const __hip_bfloat16* Wb = WaT + (size_t)hd * OO * FF;
    f32x4 z4 = {0.f, 0.f, 0.f, 0.f};
    f32x4 acc[4] = {z4, z4, z4, z4};
    for (int k0 = 0; k0 < FF; k0 += 32) {
        int k = k0 + ah * 8;
        short8 af = *(const short8*)&xrow[k];
#pragma unroll
        for (int cf = 0; cf < 4; ++cf) {
            int col = cf * 16 + al;
            short8 bf = *(const short8*)&Wb[(size_t)col * FF + k];
            acc[cf] = __builtin_amdgcn_mfma_f32_16x16x32_bf16(af, bf, acc[cf], 0, 0, 0);
        }
    }
    // fragment-major write: local row nl = w*16 + ah*4 + r  ->  half,g,q
    int kw = tile & 15;
    int half = w >> 1;
    int hg = (w & 1) * 2 + (ah >> 1);
    int q0 = (ah & 1) * 4;
#pragma unroll
    for (int cf = 0; cf < 4; ++cf) {
        size_t base = ((((size_t)bh * 16 + kw) * 4 + cf) * 2 + half) * 512 +
                      (hg * 16 + al) * 8 + q0;
        s16x4 v;
#pragma unroll
        for (int r = 0; r < 4; ++r) v[r] = bf16s(acc[cf][r]);
        *(s16x4*)&hF[base] = v;
    }
    // fused f1/f2
    int nb = n0 + w * 16 + ah * 4;
    float p1[4] = {0.f, 0.f, 0.f, 0.f}, p2[4] = {0.f, 0.f, 0.f, 0.f};
#pragma unroll
    for (int cf = 0; cf < 4; ++cf) {
        int col = cf * 16 + al;
        float a1 = aatt[hd * 2 * OO + col];
        float a2 = aatt[hd * 2 * OO + OO + col];
#pragma unroll
        for (int r = 0; r < 4; ++r) {
            p1[r] += acc[cf][r] * a1;
            p2[r] += acc[cf][r] * a2;
        }
    }
#pragma unroll
    for (int off = 1; off < 16; off <<= 1) {
#pragma unroll
        for (int r = 0; r < 4; ++r) {
            p1[r] += __shfl_xor(p1[r], off);
            p2[r] += __shfl_xor(p2[r], off);
        }
    }
    if (al == 0) {
#pragma unroll
        for (int r = 0; r < 4; ++r) {
            f1[(size_t)bh * NN + nb + r] = p1[r];
            f2[(size_t)bh * NN + nb + r] = p2[r];
        }
    }
}

// ---------- FUSED att v4: register A + fragment-major coalesced B reads ---------
__global__ void k_att_fused(const u64* __restrict__ adjbit, const float* __restrict__ f1,
                            const float* __restrict__ f2,
                            const __hip_bfloat16* __restrict__ hF,
                            __hip_bfloat16* __restrict__ ybf) {
    int orig = blockIdx.x;                     // 1024 blocks
    int wgid = (orig & 7) * 128 + (orig >> 3); // XCD-contiguous: 16 tiles/bh per XCD
    int bh = wgid >> 4;
    int n0 = (wgid & 15) * 64;
    int b = bh >> 3, hd = bh & 7;
    int t = threadIdx.x, lane = t & 63, w = t >> 6;
    __shared__ float Qs[1024], Ss[1024];
    __shared__ u64 bits[64 * 17];
    const float* f2b = f2 + (size_t)bh * NN;
    for (int j = t; j < 1024; j += 256) {
        float v = f2b[j];
        Qs[j] = __expf(v);
        Ss[j] = __expf(0.2f * v);
    }
    for (int e = t; e < 1024; e += 256) {
        int rr = e >> 4, c = e & 15;
        bits[rr * 17 + c] = adjbit[((size_t)b * NN + n0 + rr) * 16 + c];
    }
    int g = lane >> 4, r = lane & 15;
    int row = w * 16 + r;
    float fl = f1[(size_t)bh * NN + n0 + row];
    float P = __expf(fl), R = __expf(0.2f * fl);
    __syncthreads();
    const __hip_bfloat16* hFb = hF + (size_t)bh * 16 * 4 * 2 * 512 + lane * 8;
    f32x4 z4 = {0.f, 0.f, 0.f, 0.f};
    f32x4 acc[4] = {z4, z4, z4, z4};
    float ps = 0.f;
    int c0 = g * 8;
#pragma unroll 2
    for (int k0 = 0; k0 < NN; k0 += 64) {
        int kw = k0 >> 6;
        u64 m = bits[row * 17 + kw];
        unsigned bl0 = (unsigned)(m >> c0) & 0xffu;
        unsigned bl1 = (unsigned)(m >> (32 + c0)) & 0xffu;
        f32x4 qa0 = *(const f32x4*)&Qs[k0 + c0];
        f32x4 qb0 = *(const f32x4*)&Qs[k0 + c0 + 4];
        f32x4 sa0 = *(const f32x4*)&Ss[k0 + c0];
        f32x4 sb0 = *(const f32x4*)&Ss[k0 + c0 + 4];
        f32x4 qa1 = *(const f32x4*)&Qs[k0 + 32 + c0];
        f32x4 qb1 = *(const f32x4*)&Qs[k0 + 32 + c0 + 4];
        f32x4 sa1 = *(const f32x4*)&Ss[k0 + 32 + c0];
        f32x4 sb1 = *(const f32x4*)&Ss[k0 + 32 + c0 + 4];
        short8 a0, a1;
#pragma unroll
        for (int e = 0; e < 4; ++e) {
            float v0 = ((bl0 >> e) & 1) ? fmaxf(P * qa0[e], R * sa0[e]) : 0.f;
            float v1 = ((bl0 >> (4 + e)) & 1) ? fmaxf(P * qb0[e], R * sb0[e]) : 0.f;
            float v2 = ((bl1 >> e) & 1) ? fmaxf(P * qa1[e], R * sa1[e]) : 0.f;
            float v3 = ((bl1 >> (4 + e)) & 1) ? fmaxf(P * qb1[e], R * sb1[e]) : 0.f;
            ps += (v0 + v1) + (v2 + v3);
            a0[e] = bf16s(v0);
            a0[4 + e] = bf16s(v1);
            a1[e] = bf16s(v2);
            a1[4 + e] = bf16s(v3);
        }
#pragma unroll
        for (int cf = 0; cf < 4; ++cf) {
            const __hip_bfloat16* blk = hFb + ((size_t)(kw * 4 + cf) * 2) * 512;
            short8 b0 = *(const short8*)&blk[0];
            short8 b1 = *(const short8*)&blk[512];
            acc[cf] = __builtin_amdgcn_mfma_f32_16x16x32_bf16(a0, b0, acc[cf], 0, 0, 0);
            acc[cf] = __builtin_amdgcn_mfma_f32_16x16x32_bf16(a1, b1, acc[cf], 0, 0, 0);
        }
    }
    ps += __shfl_xor(ps, 16);
    ps += __shfl_xor(ps, 32);
#pragma unroll
    for (int rr = 0; rr < 4; ++rr) {
        int rloc = g * 4 + rr;
        float dn = __shfl(ps, rloc);
        float ids = 1.0f / dn;
        int nrow = n0 + w * 16 + rloc;
#pragma unroll
        for (int cf = 0; cf < 4; ++cf) {
            float v = acc[cf][rr] * ids;
            float e = v > 0.f ? v : expm1f(v);
            float yv = e > 0.f ? e : 0.01f * e;
            ybf[((size_t)b * NN + nrow) * 512 + hd * OO + cf * 16 + r] =
                __float2bfloat16(yv);
        }
    }
}

// ---------- MFMA outproj: ho = y @ W_out, fused g1/g2; ho stored FRAGMENT-MAJOR -
// hoF block (b, kw, cfB, half) of 512 bf16: elem (g*16+r)*8+q holds
// ho[n = kw*64 + half*32 + g*8 + q][c = cfB*16 + r].
__global__ void k_outproj_mfma(const __hip_bfloat16* __restrict__ ybf,
                               const __hip_bfloat16* __restrict__ WoT,
                               const float* __restrict__ ao,
                               __hip_bfloat16* __restrict__ hoF,
                               float* __restrict__ g1, float* __restrict__ g2) {
    int tile = blockIdx.x;
    int t = threadIdx.x, lane = t & 63, w = t >> 6;
    int r0 = tile * 32;
    int b = r0 >> 10;
    __shared__ __align__(16) __hip_bfloat16 As[32][520];
    __shared__ float pg1[4][32], pg2[4][32];
    for (int e = t; e < 2048; e += 256) {
        int row = e >> 6, k8 = (e & 63) * 8;
        *(short8*)&As[row][k8] = *(const short8*)&ybf[(size_t)(r0 + row) * 512 + k8];
    }
    __syncthreads();
    int al = lane & 15, ah = lane >> 4;
    f32x4 z4 = {0.f, 0.f, 0.f, 0.f};
    f32x4 acc0[4] = {z4, z4, z4, z4};
    f32x4 acc1[4] = {z4, z4, z4, z4};
    for (int k0 = 0; k0 < 512; k0 += 32) {
        int k = k0 + ah * 8;
        short8 a0 = *(const short8*)&As[al][k];
        short8 a1 = *(const short8*)&As[16 + al][k];
#pragma unroll
        for (int cf = 0; cf < 4; ++cf) {
            int col = w * 64 + cf * 16 + al;
            short8 bf = *(const short8*)&WoT[(size_t)col * 512 + k];
            acc0[cf] = __builtin_amdgcn_mfma_f32_16x16x32_bf16(a0, bf, acc0[cf], 0, 0, 0);
            acc1[cf] = __builtin_amdgcn_mfma_f32_16x16x32_bf16(a1, bf, acc1[cf], 0, 0, 0);
        }
    }
    // fragment-major hoF writes + g partials; kw local to batch b
    int kw = (tile >> 1) & 15;
    int half = tile & 1;
    int hg0 = ah >> 1;
    int q0 = (ah & 1) * 4;
    float q1[8] = {0.f, 0.f, 0.f, 0.f, 0.f, 0.f, 0.f, 0.f};
    float q2[8] = {0.f, 0.f, 0.f, 0.f, 0.f, 0.f, 0.f, 0.f};
#pragma unroll
    for (int cf = 0; cf < 4; ++cf) {
        int col = w * 64 + cf * 16 + al;
        int cfB = w * 4 + cf;
        float a1v = ao[col], a2v = ao[CC + col];
        size_t base = ((((size_t)b * 16 + kw) * 16 + cfB) * 2 + half) * 512;
        s16x4 v0, v1;
#pragma unroll
        for (int r = 0; r < 4; ++r) {
            v0[r] = bf16s(acc0[cf][r]);
            v1[r] = bf16s(acc1[cf][r]);
            q1[r] += acc0[cf][r] * a1v;
            q2[r] += acc0[cf][r] * a2v;
            q1[4 + r] += acc1[cf][r] * a1v;
            q2[4 + r] += acc1[cf][r] * a2v;
        }
        *(s16x4*)&hoF[base + (hg0 * 16 + al) * 8 + q0] = v0;
        *(s16x4*)&hoF[base + ((hg0 + 2) * 16 + al) * 8 + q0] = v1;
    }
#pragma unroll
    for (int off = 1; off < 16; off <<= 1) {
#pragma unroll
        for (int j = 0; j < 8; ++j) {
            q1[j] += __shfl_xor(q1[j], off);
            q2[j] += __shfl_xor(q2[j], off);
        }
    }
    if (al == 0) {
#pragma unroll
        for (int j = 0; j < 8; ++j) {
            int row = (j >> 2) * 16 + ah * 4 + (j & 3);
            pg1[w][row] = q1[j];
            pg2[w][row] = q2[j];
        }
    }
    __syncthreads();
    if (t < 32) {
        g1[r0 + t] = pg1[0][t] + pg1[1][t] + pg1[2][t] + pg1[3][t];
        g2[r0 + t] = pg2[0][t] + pg2[1][t] + pg2[2][t] + pg2[3][t];
    }
}

// ---------- FUSED out v5: PV + residual + mask + LayerNorm (+final relu) --------
__global__ void k_out_fused(const u64* __restrict__ adjbit, const float* __restrict__ g1,
                            const float* __restrict__ g2,
                            const __hip_bfloat16* __restrict__ hoF,
                            const float* __restrict__ xin, const int* __restrict__ mask,
                            const float* __restrict__ lw, const float* __restrict__ lb,
                            float* __restrict__ xout, __hip_bfloat16* __restrict__ xbfout,
                            float* __restrict__ outf, int final_) {
    int orig = blockIdx.x;                    // 512 blocks
    int wgid = (orig & 7) * 64 + (orig >> 3);
    int b = wgid >> 6;
    int n0 = (wgid & 63) * 16;
    int t = threadIdx.x, lane = t & 63, w = t >> 6;
    __shared__ float Qs[1024], Ss[1024];
    __shared__ u64 bits[16 * 17];
    __shared__ __align__(16) __hip_bfloat16 As[16][264];
    __shared__ float psum[4][16];
    __shared__ float lns[4][16], lnq[4][16];
    const float* g2b = g2 + (size_t)b * NN;
    for (int j = t; j < 1024; j += 256) {
        float v = g2b[j];
        Qs[j] = __expf(v);
        Ss[j] = __expf(0.2f * v);
    }
    {
        int rr = t >> 4, c = t & 15;
        bits[rr * 17 + c] = adjbit[((size_t)b * NN + n0 + rr) * 16 + c];
    }
    int br = t & 15, kg = t >> 4;
    float gl = g1[(size_t)b * NN + n0 + br];
    float P = __expf(gl);
    float R = __expf(0.2f * gl);
    int ar = lane & 15, g = lane >> 4;
    const __hip_bfloat16* hoFb = hoF + (size_t)b * 16 * 16 * 2 * 512 + lane * 8;
    f32x4 z4 = {0.f, 0.f, 0.f, 0.f};
    f32x4 acc[4] = {z4, z4, z4, z4};
    float ps = 0.f;
    __syncthreads();
    for (int ks = 0; ks < NN; ks += 256) {
        u64 m = bits[br * 17 + (ks >> 6) + (kg >> 2)];
        int sh = (kg & 3) * 16;
        short8 vv[2];
#pragma unroll
        for (int h = 0; h < 2; ++h) {
            short8 vx;
#pragma unroll
            for (int e4 = 0; e4 < 2; ++e4) {
                int cw = kg * 16 + h * 8 + e4 * 4;
                f32x4 q4 = *(const f32x4*)&Qs[ks + cw];
                f32x4 s4 = *(const f32x4*)&Ss[ks + cw];
#pragma unroll
                for (int e = 0; e < 4; ++e) {
                    float val = ((m >> (sh + h * 8 + e4 * 4 + e)) & 1)
                                    ? fmaxf(P * q4[e], R * s4[e]) : 0.f;
                    ps += val;
                    vx[e4 * 4 + e] = bf16s(val);
                }
            }
            vv[h] = vx;
        }
        *(short8*)&As[br][kg * 16] = vv[0];
        *(short8*)&As[br][kg * 16 + 8] = vv[1];
        __syncthreads();
#pragma unroll
        for (int ksub = 0; ksub < 4; ++ksub) {
            int kw = (ks >> 6) + ksub;
            short8 a0 = *(const short8*)&As[ar][ksub * 64 + g * 8];
            short8 a1 = *(const short8*)&As[ar][ksub * 64 + 32 + g * 8];
#pragma unroll
            for (int cf = 0; cf < 4; ++cf) {
                int cfB = w * 4 + cf;
                const __hip_bfloat16* blk = hoFb + ((size_t)(kw * 16 + cfB) * 2) * 512;
                short8 b0 = *(const short8*)&blk[0];
                short8 b1 = *(const short8*)&blk[512];
                acc[cf] = __builtin_amdgcn_mfma_f32_16x16x32_bf16(a0, b0, acc[cf], 0, 0, 0);
                acc[cf] = __builtin_amdgcn_mfma_f32_16x16x32_bf16(a1, b1, acc[cf], 0, 0, 0);
            }
        }
        __syncthreads();
    }
    ps += __shfl_xor(ps, 16);
    ps += __shfl_xor(ps, 32);
    if (lane < 16) psum[w][lane] = ps;
    __syncthreads();
    // residual + mask, collect LN stats
    float tv[4][4];
#pragma unroll
    for (int rr = 0; rr < 4; ++rr) {
        int rloc = g * 4 + rr;
        float dn = psum[0][rloc] + psum[1][rloc] + psum[2][rloc] + psum[3][rloc];
        float ids = 1.0f / dn;
        int nrow = n0 + rloc;
        int mk = mask[b * NN + nrow];
        size_t rowo = ((size_t)b * NN + nrow) * CC;
        float s1 = 0.f, s2 = 0.f;
#pragma unroll
        for (int cf = 0; cf < 4; ++cf) {
            int col = w * 64 + cf * 16 + ar;
            float v = acc[cf][rr] * ids;
            float e = v > 0.f ? v : expm1f(v);
            float tvv = (mk == 0) ? 0.f : (xin[rowo + col] + e);
            tv[rr][cf] = tvv;
            s1 += tvv;
            s2 += tvv * tvv;
        }
#pragma unroll
        for (int off = 1; off < 16; off <<= 1) {
            s1 += __shfl_xor(s1, off);
            s2 += __shfl_xor(s2, off);
        }
        if (ar == 0) {
            lns[w][rloc] = s1;
            lnq[w][rloc] = s2;
        }
    }
    __syncthreads();
    // layernorm + write
#pragma unroll
    for (int rr = 0; rr < 4; ++rr) {
        int rloc = g * 4 + rr;
        int nrow = n0 + rloc;
        size_t rowo = ((size_t)b * NN + nrow) * CC;
        float su = lns[0][rloc] + lns[1][rloc] + lns[2][rloc] + lns[3][rloc];
        float sq = lnq[0][rloc] + lnq[1][rloc] + lnq[2][rloc] + lnq[3][rloc];
        float mu = su * (1.0f / CC);
        float var = sq * (1.0f / CC) - mu * mu;
        float rstd = rsqrtf(var + 1e-5f);
#pragma unroll
        for (int cf = 0; cf < 4; ++cf) {
            int col = w * 64 + cf * 16 + ar;
            float ln = (tv[rr][cf] - mu) * rstd * lw[col] + lb[col];
            if (final_) {
                float rv = ln > 0.f ? ln : 0.f;
                outf[rowo + col] = rv;
                if (nrow == 0) outf[(size_t)BB * NN * CC + b * CC + col] = rv;
            } else {
                xout[rowo + col] = ln;
                xbfout[rowo + col] = __float2bfloat16(ln);
            }
        }
    }
}

extern "C" void kernel_launch(void* const* d_in, const int* in_sizes, int n_in,
                              void* d_out, int out_size, void* d_ws, size_t ws_size,
                              hipStream_t stream) {
    const float* x = (const float*)d_in[0];
    const int* adj = (const int*)d_in[1];
    const int* mask = (const int*)d_in[2];
    const float* W_att = (const float*)d_in[3];
    const float* a_att = (const float*)d_in[4];
    const float* W_out = (const float*)d_in[5];
    const float* a_out = (const float*)d_in[6];
    const float* ln_w = (const float*)d_in[7];
    const float* ln_b = (const float*)d_in[8];
    float* out = (float*)d_out;

    float* ws = (float*)d_ws;
    float* xbuf = ws;                          // 2,097,152 f32
    float* xbfr = xbuf + 2097152;              // 2,097,152 f32 slot (xbf uses 4 MB)
    float* f1   = xbfr + 2097152;              // 65,536
    float* f2   = f1 + 65536;                  // 65,536
    float* g1   = f2 + 65536;                  // 8,192
    float* g2   = g1 + 8192;                   // 8,192
    float* p    = g2 + 8192;
    __hip_bfloat16* xbf = (__hip_bfloat16*)xbfr;          // 2,097,152 bf16
    __hip_bfloat16* hF  = (__hip_bfloat16*)p;             // 4,194,304 bf16 (8 MB)
    __hip_bfloat16* ybf = (__hip_bfloat16*)(p + 2097152); // 4,194,304 bf16
    __hip_bfloat16* hoF = (__hip_bfloat16*)(p + 4194304); // 2,097,152 bf16 (4 MB)
    __hip_bfloat16* WaT = (__hip_bfloat16*)(p + 5242880); // 131,072 bf16
    __hip_bfloat16* WoT = (__hip_bfloat16*)(p + 5308416); // 131,072 bf16
    u64* adjbit = (u64*)(p + 5373952);                    // 131,072 u64 (1 MB)

    k_wprep<<<1024, 256, 0, stream>>>(W_att, W_out, WaT, WoT);
    k_adjprep<<<32768, 256, 0, stream>>>(adj, adjbit);
    k_xprep<<<8192, 256, 0, stream>>>(x, xbf);

    for (int layer = 0; layer < 2; ++layer) {
        const float* xin_l = layer ? xbuf : x;
        k_proj_mfma<<<dim3(128, 8), 256, 0, stream>>>(xbf, WaT, a_att, hF, f1, f2);
        k_att_fused<<<1024, 256, 0, stream>>>(adjbit, f1, f2, hF, ybf);
        k_outproj_mfma<<<256, 256, 0, stream>>>(ybf, WoT, a_out, hoF, g1, g2);
        k_out_fused<<<512, 256, 0, stream>>>(adjbit, g1, g2, hoF, xin_l, mask,
                                             ln_w, ln_b, xbuf, xbf, out, layer == 1);
    }
}

// Round 11
// 224.492 us; speedup vs baseline: 8.7772x; 1.0083x over previous
//
#include <hip/hip_runtime.h>
#include <hip/hip_bf16.h>
#include <math.h>

#define BB 8
#define NN 1024
#define FF 256
#define HH 8
#define OO 64
#define CC 256

typedef __attribute__((ext_vector_type(8))) short short8;
typedef __attribute__((ext_vector_type(4))) short s16x4;
typedef __attribute__((ext_vector_type(4))) float f32x4;
typedef unsigned long long u64;

__device__ __forceinline__ short bf16s(float f) {
    __hip_bfloat16 h = __float2bfloat16(f);
    return *reinterpret_cast<short*>(&h);
}

// ---------- combined one-time prep: adj bitmask | x->bf16 | weight transposes ----
__global__ void k_prep(const int* __restrict__ adj, const float* __restrict__ x,
                       const float* __restrict__ Wa, const float* __restrict__ Wo,
                       u64* __restrict__ adjbit, __hip_bfloat16* __restrict__ xbf,
                       __hip_bfloat16* __restrict__ WaT, __hip_bfloat16* __restrict__ WoT) {
    int bid = blockIdx.x, t = threadIdx.x;
    if (bid < 32768) {                       // adj -> bitmask
        int i = bid * 256 + t;
        u64 m = __ballot(adj[i] > 0);
        if ((t & 63) == 0) adjbit[i >> 6] = m;
    } else if (bid < 32768 + 8192) {         // x -> bf16
        int i = (bid - 32768) * 256 + t;
        xbf[i] = __float2bfloat16(x[i]);
    } else {                                 // weight transposes
        int i = (bid - 32768 - 8192) * 256 + t;
        if (i < 131072) {
            int hd = i >> 14, o = (i >> 8) & 63, f = i & 255;
            WaT[i] = __float2bfloat16(Wa[hd * 16384 + f * 64 + o]);
        } else {
            int j = i - 131072;
            int c = j >> 9, k = j & 511;
            WoT[j] = __float2bfloat16(Wo[k * 256 + c]);
        }
    }
}

// ---------- MFMA proj: h = xbf @ W_att, fused f1/f2; h stored FRAGMENT-MAJOR ----
// hF block (bh, kw, cf, half) of 512 bf16: elem (g*16+r)*8+q holds
// h[n = kw*64 + half*32 + g*8 + q][o = cf*16 + r].
__global__ void k_proj_mfma(const __hip_bfloat16* __restrict__ xbf,
                            const __hip_bfloat16* __restrict__ WaT,
                            const float* __restrict__ aatt,
                            __hip_bfloat16* __restrict__ hF,
                            float* __restrict__ f1, float* __restrict__ f2) {
    int tile = blockIdx.x, hd = blockIdx.y;
    int t = threadIdx.x, lane = t & 63, w = t >> 6;
    int r0 = tile * 64;
    int b = r0 >> 10;
    int n0 = r0 & 1023;
    int bh = b * HH + hd;
    int al = lane & 15, ah = lane >> 4;
    const __hip_bfloat16* xrow = xbf + (size_t)(r0 + w * 16 + al) * FF;
    const __hip_bfloat16* Wb = WaT + (size_t)hd * OO * FF;
    f32x4 z4 = {0.f, 0.f, 0.f, 0.f};
    f32x4 acc[4] = {z4, z4, z4, z4};
    for (int k0 = 0; k0 < FF; k0 += 32) {
        int k = k0 + ah * 8;
        short8 af = *(const short8*)&xrow[k];
#pragma unroll
        for (int cf = 0; cf < 4; ++cf) {
            int col = cf * 16 + al;
            short8 bf = *(const short8*)&Wb[(size_t)col * FF + k];
            acc[cf] = __builtin_amdgcn_mfma_f32_16x16x32_bf16(af, bf, acc[cf], 0, 0, 0);
        }
    }
    int kw = tile & 15;
    int half = w >> 1;
    int hg = (w & 1) * 2 + (ah >> 1);
    int q0 = (ah & 1) * 4;
#pragma unroll
    for (int cf = 0; cf < 4; ++cf) {
        size_t base = ((((size_t)bh * 16 + kw) * 4 + cf) * 2 + half) * 512 +
                      (hg * 16 + al) * 8 + q0;
        s16x4 v;
#pragma unroll
        for (int r = 0; r < 4; ++r) v[r] = bf16s(acc[cf][r]);
        *(s16x4*)&hF[base] = v;
    }
    int nb = n0 + w * 16 + ah * 4;
    float p1[4] = {0.f, 0.f, 0.f, 0.f}, p2[4] = {0.f, 0.f, 0.f, 0.f};
#pragma unroll
    for (int cf = 0; cf < 4; ++cf) {
        int col = cf * 16 + al;
        float a1 = aatt[hd * 2 * OO + col];
        float a2 = aatt[hd * 2 * OO + OO + col];
#pragma unroll
        for (int r = 0; r < 4; ++r) {
            p1[r] += acc[cf][r] * a1;
            p2[r] += acc[cf][r] * a2;
        }
    }
#pragma unroll
    for (int off = 1; off < 16; off <<= 1) {
#pragma unroll
        for (int r = 0; r < 4; ++r) {
            p1[r] += __shfl_xor(p1[r], off);
            p2[r] += __shfl_xor(p2[r], off);
        }
    }
    if (al == 0) {
#pragma unroll
        for (int r = 0; r < 4; ++r) {
            f1[(size_t)bh * NN + nb + r] = p1[r];
            f2[(size_t)bh * NN + nb + r] = p2[r];
        }
    }
}

// ---------- FUSED att v4: register A + fragment-major coalesced B reads ---------
__global__ void k_att_fused(const u64* __restrict__ adjbit, const float* __restrict__ f1,
                            const float* __restrict__ f2,
                            const __hip_bfloat16* __restrict__ hF,
                            __hip_bfloat16* __restrict__ ybf) {
    int orig = blockIdx.x;                     // 1024 blocks
    int wgid = (orig & 7) * 128 + (orig >> 3); // XCD-contiguous: 16 tiles/bh per XCD
    int bh = wgid >> 4;
    int n0 = (wgid & 15) * 64;
    int b = bh >> 3, hd = bh & 7;
    int t = threadIdx.x, lane = t & 63, w = t >> 6;
    __shared__ float Qs[1024], Ss[1024];
    __shared__ u64 bits[64 * 17];
    const float* f2b = f2 + (size_t)bh * NN;
    for (int j = t; j < 1024; j += 256) {
        float v = f2b[j];
        Qs[j] = __expf(v);
        Ss[j] = __expf(0.2f * v);
    }
    for (int e = t; e < 1024; e += 256) {
        int rr = e >> 4, c = e & 15;
        bits[rr * 17 + c] = adjbit[((size_t)b * NN + n0 + rr) * 16 + c];
    }
    int g = lane >> 4, r = lane & 15;
    int row = w * 16 + r;
    float fl = f1[(size_t)bh * NN + n0 + row];
    float P = __expf(fl), R = __expf(0.2f * fl);
    __syncthreads();
    const __hip_bfloat16* hFb = hF + (size_t)bh * 16 * 4 * 2 * 512 + lane * 8;
    f32x4 z4 = {0.f, 0.f, 0.f, 0.f};
    f32x4 acc[4] = {z4, z4, z4, z4};
    float ps = 0.f;
    int c0 = g * 8;
#pragma unroll 2
    for (int k0 = 0; k0 < NN; k0 += 64) {
        int kw = k0 >> 6;
        u64 m = bits[row * 17 + kw];
        unsigned bl0 = (unsigned)(m >> c0) & 0xffu;
        unsigned bl1 = (unsigned)(m >> (32 + c0)) & 0xffu;
        f32x4 qa0 = *(const f32x4*)&Qs[k0 + c0];
        f32x4 qb0 = *(const f32x4*)&Qs[k0 + c0 + 4];
        f32x4 sa0 = *(const f32x4*)&Ss[k0 + c0];
        f32x4 sb0 = *(const f32x4*)&Ss[k0 + c0 + 4];
        f32x4 qa1 = *(const f32x4*)&Qs[k0 + 32 + c0];
        f32x4 qb1 = *(const f32x4*)&Qs[k0 + 32 + c0 + 4];
        f32x4 sa1 = *(const f32x4*)&Ss[k0 + 32 + c0];
        f32x4 sb1 = *(const f32x4*)&Ss[k0 + 32 + c0 + 4];
        short8 a0, a1;
#pragma unroll
        for (int e = 0; e < 4; ++e) {
            float v0 = ((bl0 >> e) & 1) ? fmaxf(P * qa0[e], R * sa0[e]) : 0.f;
            float v1 = ((bl0 >> (4 + e)) & 1) ? fmaxf(P * qb0[e], R * sb0[e]) : 0.f;
            float v2 = ((bl1 >> e) & 1) ? fmaxf(P * qa1[e], R * sa1[e]) : 0.f;
            float v3 = ((bl1 >> (4 + e)) & 1) ? fmaxf(P * qb1[e], R * sb1[e]) : 0.f;
            ps += (v0 + v1) + (v2 + v3);
            a0[e] = bf16s(v0);
            a0[4 + e] = bf16s(v1);
            a1[e] = bf16s(v2);
            a1[4 + e] = bf16s(v3);
        }
#pragma unroll
        for (int cf = 0; cf < 4; ++cf) {
            const __hip_bfloat16* blk = hFb + ((size_t)(kw * 4 + cf) * 2) * 512;
            short8 b0 = *(const short8*)&blk[0];
            short8 b1 = *(const short8*)&blk[512];
            acc[cf] = __builtin_amdgcn_mfma_f32_16x16x32_bf16(a0, b0, acc[cf], 0, 0, 0);
            acc[cf] = __builtin_amdgcn_mfma_f32_16x16x32_bf16(a1, b1, acc[cf], 0, 0, 0);
        }
    }
    ps += __shfl_xor(ps, 16);
    ps += __shfl_xor(ps, 32);
#pragma unroll
    for (int rr = 0; rr < 4; ++rr) {
        int rloc = g * 4 + rr;
        float dn = __shfl(ps, rloc);
        float ids = 1.0f / dn;
        int nrow = n0 + w * 16 + rloc;
#pragma unroll
        for (int cf = 0; cf < 4; ++cf) {
            float v = acc[cf][rr] * ids;
            float e = v > 0.f ? v : expm1f(v);
            float yv = e > 0.f ? e : 0.01f * e;
            ybf[((size_t)b * NN + nrow) * 512 + hd * OO + cf * 16 + r] =
                __float2bfloat16(yv);
        }
    }
}

// ---------- MFMA outproj: ho = y @ W_out, fused g1/g2; ho stored FRAGMENT-MAJOR -
__global__ void k_outproj_mfma(const __hip_bfloat16* __restrict__ ybf,
                               const __hip_bfloat16* __restrict__ WoT,
                               const float* __restrict__ ao,
                               __hip_bfloat16* __restrict__ hoF,
                               float* __restrict__ g1, float* __restrict__ g2) {
    int tile = blockIdx.x;
    int t = threadIdx.x, lane = t & 63, w = t >> 6;
    int r0 = tile * 32;
    int b = r0 >> 10;
    __shared__ __align__(16) __hip_bfloat16 As[32][520];
    __shared__ float pg1[4][32], pg2[4][32];
    for (int e = t; e < 2048; e += 256) {
        int row = e >> 6, k8 = (e & 63) * 8;
        *(short8*)&As[row][k8] = *(const short8*)&ybf[(size_t)(r0 + row) * 512 + k8];
    }
    __syncthreads();
    int al = lane & 15, ah = lane >> 4;
    f32x4 z4 = {0.f, 0.f, 0.f, 0.f};
    f32x4 acc0[4] = {z4, z4, z4, z4};
    f32x4 acc1[4] = {z4, z4, z4, z4};
    for (int k0 = 0; k0 < 512; k0 += 32) {
        int k = k0 + ah * 8;
        short8 a0 = *(const short8*)&As[al][k];
        short8 a1 = *(const short8*)&As[16 + al][k];
#pragma unroll
        for (int cf = 0; cf < 4; ++cf) {
            int col = w * 64 + cf * 16 + al;
            short8 bf = *(const short8*)&WoT[(size_t)col * 512 + k];
            acc0[cf] = __builtin_amdgcn_mfma_f32_16x16x32_bf16(a0, bf, acc0[cf], 0, 0, 0);
            acc1[cf] = __builtin_amdgcn_mfma_f32_16x16x32_bf16(a1, bf, acc1[cf], 0, 0, 0);
        }
    }
    int kw = (tile >> 1) & 15;
    int half = tile & 1;
    int hg0 = ah >> 1;
    int q0 = (ah & 1) * 4;
    float q1[8] = {0.f, 0.f, 0.f, 0.f, 0.f, 0.f, 0.f, 0.f};
    float q2[8] = {0.f, 0.f, 0.f, 0.f, 0.f, 0.f, 0.f, 0.f};
#pragma unroll
    for (int cf = 0; cf < 4; ++cf) {
        int col = w * 64 + cf * 16 + al;
        int cfB = w * 4 + cf;
        float a1v = ao[col], a2v = ao[CC + col];
        size_t base = ((((size_t)b * 16 + kw) * 16 + cfB) * 2 + half) * 512;
        s16x4 v0, v1;
#pragma unroll
        for (int r = 0; r < 4; ++r) {
            v0[r] = bf16s(acc0[cf][r]);
            v1[r] = bf16s(acc1[cf][r]);
            q1[r] += acc0[cf][r] * a1v;
            q2[r] += acc0[cf][r] * a2v;
            q1[4 + r] += acc1[cf][r] * a1v;
            q2[4 + r] += acc1[cf][r] * a2v;
        }
        *(s16x4*)&hoF[base + (hg0 * 16 + al) * 8 + q0] = v0;
        *(s16x4*)&hoF[base + ((hg0 + 2) * 16 + al) * 8 + q0] = v1;
    }
#pragma unroll
    for (int off = 1; off < 16; off <<= 1) {
#pragma unroll
        for (int j = 0; j < 8; ++j) {
            q1[j] += __shfl_xor(q1[j], off);
            q2[j] += __shfl_xor(q2[j], off);
        }
    }
    if (al == 0) {
#pragma unroll
        for (int j = 0; j < 8; ++j) {
            int row = (j >> 2) * 16 + ah * 4 + (j & 3);
            pg1[w][row] = q1[j];
            pg2[w][row] = q2[j];
        }
    }
    __syncthreads();
    if (t < 32) {
        g1[r0 + t] = pg1[0][t] + pg1[1][t] + pg1[2][t] + pg1[3][t];
        g2[r0 + t] = pg2[0][t] + pg2[1][t] + pg2[2][t] + pg2[3][t];
    }
}

// ---------- FUSED out v6: register-direct A (no K-loop barriers) + LN epilogue --
__global__ void k_out_fused(const u64* __restrict__ adjbit, const float* __restrict__ g1,
                            const float* __restrict__ g2,
                            const __hip_bfloat16* __restrict__ hoF,
                            const float* __restrict__ xin, const int* __restrict__ mask,
                            const float* __restrict__ lw, const float* __restrict__ lb,
                            float* __restrict__ xout, __hip_bfloat16* __restrict__ xbfout,
                            float* __restrict__ outf, int final_) {
    int orig = blockIdx.x;                    // 512 blocks
    int wgid = (orig & 7) * 64 + (orig >> 3);
    int b = wgid >> 6;
    int n0 = (wgid & 63) * 16;
    int t = threadIdx.x, lane = t & 63, w = t >> 6;
    __shared__ float Qs[1024], Ss[1024];
    __shared__ u64 bits[16 * 17];
    __shared__ float lns[4][16], lnq[4][16];
    const float* g2b = g2 + (size_t)b * NN;
    for (int j = t; j < 1024; j += 256) {
        float v = g2b[j];
        Qs[j] = __expf(v);
        Ss[j] = __expf(0.2f * v);
    }
    if (t < 256) {
        int rr = t >> 4, c = t & 15;
        bits[rr * 17 + c] = adjbit[((size_t)b * NN + n0 + rr) * 16 + c];
    }
    int g = lane >> 4, r = lane & 15;
    float gl = g1[(size_t)b * NN + n0 + r];
    float P = __expf(gl);
    float R = __expf(0.2f * gl);
    __syncthreads();
    // wave w: cols w*64..+63 (cfB = w*4+cf); every wave builds the same A rows.
    const __hip_bfloat16* hoFb = hoF + (size_t)b * 16 * 16 * 2 * 512 + lane * 8;
    f32x4 z4 = {0.f, 0.f, 0.f, 0.f};
    f32x4 acc[4] = {z4, z4, z4, z4};
    float ps = 0.f;
    int c0 = g * 8;
#pragma unroll 2
    for (int k0 = 0; k0 < NN; k0 += 64) {
        int kw = k0 >> 6;
        u64 m = bits[r * 17 + kw];
        unsigned bl0 = (unsigned)(m >> c0) & 0xffu;
        unsigned bl1 = (unsigned)(m >> (32 + c0)) & 0xffu;
        f32x4 qa0 = *(const f32x4*)&Qs[k0 + c0];
        f32x4 qb0 = *(const f32x4*)&Qs[k0 + c0 + 4];
        f32x4 sa0 = *(const f32x4*)&Ss[k0 + c0];
        f32x4 sb0 = *(const f32x4*)&Ss[k0 + c0 + 4];
        f32x4 qa1 = *(const f32x4*)&Qs[k0 + 32 + c0];
        f32x4 qb1 = *(const f32x4*)&Qs[k0 + 32 + c0 + 4];
        f32x4 sa1 = *(const f32x4*)&Ss[k0 + 32 + c0];
        f32x4 sb1 = *(const f32x4*)&Ss[k0 + 32 + c0 + 4];
        short8 a0, a1;
#pragma unroll
        for (int e = 0; e < 4; ++e) {
            float v0 = ((bl0 >> e) & 1) ? fmaxf(P * qa0[e], R * sa0[e]) : 0.f;
            float v1 = ((bl0 >> (4 + e)) & 1) ? fmaxf(P * qb0[e], R * sb0[e]) : 0.f;
            float v2 = ((bl1 >> e) & 1) ? fmaxf(P * qa1[e], R * sa1[e]) : 0.f;
            float v3 = ((bl1 >> (4 + e)) & 1) ? fmaxf(P * qb1[e], R * sb1[e]) : 0.f;
            ps += (v0 + v1) + (v2 + v3);
            a0[e] = bf16s(v0);
            a0[4 + e] = bf16s(v1);
            a1[e] = bf16s(v2);
            a1[4 + e] = bf16s(v3);
        }
#pragma unroll
        for (int cf = 0; cf < 4; ++cf) {
            int cfB = w * 4 + cf;
            const __hip_bfloat16* blk = hoFb + ((size_t)(kw * 16 + cfB) * 2) * 512;
            short8 b0 = *(const short8*)&blk[0];
            short8 b1 = *(const short8*)&blk[512];
            acc[cf] = __builtin_amdgcn_mfma_f32_16x16x32_bf16(a0, b0, acc[cf], 0, 0, 0);
            acc[cf] = __builtin_amdgcn_mfma_f32_16x16x32_bf16(a1, b1, acc[cf], 0, 0, 0);
        }
    }
    // rowsum: lane i holds rowsum of row i&15 after 16/32 butterfly
    ps += __shfl_xor(ps, 16);
    ps += __shfl_xor(ps, 32);
    // residual + mask, collect LN stats (row spans 4 waves -> LDS reduce)
    float tv[4][4];
#pragma unroll
    for (int rr = 0; rr < 4; ++rr) {
        int rloc = g * 4 + rr;
        float dn = __shfl(ps, rloc);
        float ids = 1.0f / dn;
        int nrow = n0 + rloc;
        int mk = mask[b * NN + nrow];
        size_t rowo = ((size_t)b * NN + nrow) * CC;
        float s1 = 0.f, s2 = 0.f;
#pragma unroll
        for (int cf = 0; cf < 4; ++cf) {
            int col = w * 64 + cf * 16 + r;
            float v = acc[cf][rr] * ids;
            float e = v > 0.f ? v : expm1f(v);
            float tvv = (mk == 0) ? 0.f : (xin[rowo + col] + e);
            tv[rr][cf] = tvv;
            s1 += tvv;
            s2 += tvv * tvv;
        }
#pragma unroll
        for (int off = 1; off < 16; off <<= 1) {
            s1 += __shfl_xor(s1, off);
            s2 += __shfl_xor(s2, off);
        }
        if (r == 0) {
            lns[w][rloc] = s1;
            lnq[w][rloc] = s2;
        }
    }
    __syncthreads();
#pragma unroll
    for (int rr = 0; rr < 4; ++rr) {
        int rloc = g * 4 + rr;
        int nrow = n0 + rloc;
        size_t rowo = ((size_t)b * NN + nrow) * CC;
        float su = lns[0][rloc] + lns[1][rloc] + lns[2][rloc] + lns[3][rloc];
        float sq = lnq[0][rloc] + lnq[1][rloc] + lnq[2][rloc] + lnq[3][rloc];
        float mu = su * (1.0f / CC);
        float var = sq * (1.0f / CC) - mu * mu;
        float rstd = rsqrtf(var + 1e-5f);
#pragma unroll
        for (int cf = 0; cf < 4; ++cf) {
            int col = w * 64 + cf * 16 + r;
            float ln = (tv[rr][cf] - mu) * rstd * lw[col] + lb[col];
            if (final_) {
                float rv = ln > 0.f ? ln : 0.f;
                outf[rowo + col] = rv;
                if (nrow == 0) outf[(size_t)BB * NN * CC + b * CC + col] = rv;
            } else {
                xout[rowo + col] = ln;
                xbfout[rowo + col] = __float2bfloat16(ln);
            }
        }
    }
}

extern "C" void kernel_launch(void* const* d_in, const int* in_sizes, int n_in,
                              void* d_out, int out_size, void* d_ws, size_t ws_size,
                              hipStream_t stream) {
    const float* x = (const float*)d_in[0];
    const int* adj = (const int*)d_in[1];
    const int* mask = (const int*)d_in[2];
    const float* W_att = (const float*)d_in[3];
    const float* a_att = (const float*)d_in[4];
    const float* W_out = (const float*)d_in[5];
    const float* a_out = (const float*)d_in[6];
    const float* ln_w = (const float*)d_in[7];
    const float* ln_b = (const float*)d_in[8];
    float* out = (float*)d_out;

    float* ws = (float*)d_ws;
    float* xbuf = ws;                          // 2,097,152 f32
    float* xbfr = xbuf + 2097152;              // 2,097,152 f32 slot (xbf)
    float* f1   = xbfr + 2097152;              // 65,536
    float* f2   = f1 + 65536;                  // 65,536
    float* g1   = f2 + 65536;                  // 8,192
    float* g2   = g1 + 8192;                   // 8,192
    float* p    = g2 + 8192;
    __hip_bfloat16* xbf = (__hip_bfloat16*)xbfr;          // 2,097,152 bf16
    __hip_bfloat16* hF  = (__hip_bfloat16*)p;             // 4,194,304 bf16 (8 MB)
    __hip_bfloat16* ybf = (__hip_bfloat16*)(p + 2097152); // 4,194,304 bf16
    __hip_bfloat16* hoF = (__hip_bfloat16*)(p + 4194304); // 2,097,152 bf16 (4 MB)
    __hip_bfloat16* WaT = (__hip_bfloat16*)(p + 5242880); // 131,072 bf16
    __hip_bfloat16* WoT = (__hip_bfloat16*)(p + 5308416); // 131,072 bf16
    u64* adjbit = (u64*)(p + 5373952);                    // 131,072 u64 (1 MB)

    k_prep<<<32768 + 8192 + 1024, 256, 0, stream>>>(adj, x, W_att, W_out,
                                                    adjbit, xbf, WaT, WoT);

    for (int layer = 0; layer < 2; ++layer) {
        const float* xin_l = layer ? xbuf : x;
        k_proj_mfma<<<dim3(128, 8), 256, 0, stream>>>(xbf, WaT, a_att, hF, f1, f2);
        k_att_fused<<<1024, 256, 0, stream>>>(adjbit, f1, f2, hF, ybf);
        k_outproj_mfma<<<256, 256, 0, stream>>>(ybf, WoT, a_out, hoF, g1, g2);
        k_out_fused<<<512, 256, 0, stream>>>(adjbit, g1, g2, hoF, xin_l, mask,
                                             ln_w, ln_b, xbuf, xbf, out, layer == 1);
    }
}

// Round 12
// 208.418 us; speedup vs baseline: 9.4541x; 1.0771x over previous
//
#include <hip/hip_runtime.h>
#include <hip/hip_bf16.h>
#include <math.h>

#define BB 8
#define NN 1024
#define FF 256
#define HH 8
#define OO 64
#define CC 256

typedef __attribute__((ext_vector_type(8))) short short8;
typedef __attribute__((ext_vector_type(4))) short s16x4;
typedef __attribute__((ext_vector_type(4))) float f32x4;
typedef unsigned long long u64;

__device__ __forceinline__ short bf16s(float f) {
    __hip_bfloat16 h = __float2bfloat16(f);
    return *reinterpret_cast<short*>(&h);
}

// ---------- combined one-time prep: adj bitmask | x->bf16 | weight transposes ----
__global__ void k_prep(const int* __restrict__ adj, const float* __restrict__ x,
                       const float* __restrict__ Wa, const float* __restrict__ Wo,
                       u64* __restrict__ adjbit, __hip_bfloat16* __restrict__ xbf,
                       __hip_bfloat16* __restrict__ WaT, __hip_bfloat16* __restrict__ WoT) {
    int bid = blockIdx.x, t = threadIdx.x;
    if (bid < 32768) {                       // adj -> bitmask
        int i = bid * 256 + t;
        u64 m = __ballot(adj[i] > 0);
        if ((t & 63) == 0) adjbit[i >> 6] = m;
    } else if (bid < 32768 + 8192) {         // x -> bf16
        int i = (bid - 32768) * 256 + t;
        xbf[i] = __float2bfloat16(x[i]);
    } else {                                 // weight transposes
        int i = (bid - 32768 - 8192) * 256 + t;
        if (i < 131072) {
            int hd = i >> 14, o = (i >> 8) & 63, f = i & 255;
            WaT[i] = __float2bfloat16(Wa[hd * 16384 + f * 64 + o]);
        } else {
            int j = i - 131072;
            int c = j >> 9, k = j & 511;
            WoT[j] = __float2bfloat16(Wo[k * 256 + c]);
        }
    }
}

// ---------- MFMA proj: h = xbf @ W_att, fused f1/f2; h stored FRAGMENT-MAJOR ----
// hF block (bh, kw, cf, half) of 512 bf16: elem (g*16+r)*8+q holds
// h[n = kw*64 + half*32 + g*8 + q][o = cf*16 + r].
__global__ void k_proj_mfma(const __hip_bfloat16* __restrict__ xbf,
                            const __hip_bfloat16* __restrict__ WaT,
                            const float* __restrict__ aatt,
                            __hip_bfloat16* __restrict__ hF,
                            float* __restrict__ f1, float* __restrict__ f2) {
    int tile = blockIdx.x, hd = blockIdx.y;
    int t = threadIdx.x, lane = t & 63, w = t >> 6;
    int r0 = tile * 64;
    int b = r0 >> 10;
    int n0 = r0 & 1023;
    int bh = b * HH + hd;
    int al = lane & 15, ah = lane >> 4;
    const __hip_bfloat16* xrow = xbf + (size_t)(r0 + w * 16 + al) * FF;
    const __hip_bfloat16* Wb = WaT + (size_t)hd * OO * FF;
    f32x4 z4 = {0.f, 0.f, 0.f, 0.f};
    f32x4 acc[4] = {z4, z4, z4, z4};
    for (int k0 = 0; k0 < FF; k0 += 32) {
        int k = k0 + ah * 8;
        short8 af = *(const short8*)&xrow[k];
#pragma unroll
        for (int cf = 0; cf < 4; ++cf) {
            int col = cf * 16 + al;
            short8 bf = *(const short8*)&Wb[(size_t)col * FF + k];
            acc[cf] = __builtin_amdgcn_mfma_f32_16x16x32_bf16(af, bf, acc[cf], 0, 0, 0);
        }
    }
    int kw = tile & 15;
    int half = w >> 1;
    int hg = (w & 1) * 2 + (ah >> 1);
    int q0 = (ah & 1) * 4;
#pragma unroll
    for (int cf = 0; cf < 4; ++cf) {
        size_t base = ((((size_t)bh * 16 + kw) * 4 + cf) * 2 + half) * 512 +
                      (hg * 16 + al) * 8 + q0;
        s16x4 v;
#pragma unroll
        for (int r = 0; r < 4; ++r) v[r] = bf16s(acc[cf][r]);
        *(s16x4*)&hF[base] = v;
    }
    int nb = n0 + w * 16 + ah * 4;
    float p1[4] = {0.f, 0.f, 0.f, 0.f}, p2[4] = {0.f, 0.f, 0.f, 0.f};
#pragma unroll
    for (int cf = 0; cf < 4; ++cf) {
        int col = cf * 16 + al;
        float a1 = aatt[hd * 2 * OO + col];
        float a2 = aatt[hd * 2 * OO + OO + col];
#pragma unroll
        for (int r = 0; r < 4; ++r) {
            p1[r] += acc[cf][r] * a1;
            p2[r] += acc[cf][r] * a2;
        }
    }
#pragma unroll
    for (int off = 1; off < 16; off <<= 1) {
#pragma unroll
        for (int r = 0; r < 4; ++r) {
            p1[r] += __shfl_xor(p1[r], off);
            p2[r] += __shfl_xor(p2[r], off);
        }
    }
    if (al == 0) {
#pragma unroll
        for (int r = 0; r < 4; ++r) {
            f1[(size_t)bh * NN + nb + r] = p1[r];
            f2[(size_t)bh * NN + nb + r] = p2[r];
        }
    }
}

// ---------- FUSED att v4: register A + fragment-major coalesced B reads ---------
__global__ void k_att_fused(const u64* __restrict__ adjbit, const float* __restrict__ f1,
                            const float* __restrict__ f2,
                            const __hip_bfloat16* __restrict__ hF,
                            __hip_bfloat16* __restrict__ ybf) {
    int orig = blockIdx.x;                     // 1024 blocks
    int wgid = (orig & 7) * 128 + (orig >> 3); // XCD-contiguous: 16 tiles/bh per XCD
    int bh = wgid >> 4;
    int n0 = (wgid & 15) * 64;
    int b = bh >> 3, hd = bh & 7;
    int t = threadIdx.x, lane = t & 63, w = t >> 6;
    __shared__ float Qs[1024], Ss[1024];
    __shared__ u64 bits[64 * 17];
    const float* f2b = f2 + (size_t)bh * NN;
    for (int j = t; j < 1024; j += 256) {
        float v = f2b[j];
        Qs[j] = __expf(v);
        Ss[j] = __expf(0.2f * v);
    }
    for (int e = t; e < 1024; e += 256) {
        int rr = e >> 4, c = e & 15;
        bits[rr * 17 + c] = adjbit[((size_t)b * NN + n0 + rr) * 16 + c];
    }
    int g = lane >> 4, r = lane & 15;
    int row = w * 16 + r;
    float fl = f1[(size_t)bh * NN + n0 + row];
    float P = __expf(fl), R = __expf(0.2f * fl);
    __syncthreads();
    const __hip_bfloat16* hFb = hF + (size_t)bh * 16 * 4 * 2 * 512 + lane * 8;
    f32x4 z4 = {0.f, 0.f, 0.f, 0.f};
    f32x4 acc[4] = {z4, z4, z4, z4};
    float ps = 0.f;
    int c0 = g * 8;
#pragma unroll 2
    for (int k0 = 0; k0 < NN; k0 += 64) {
        int kw = k0 >> 6;
        u64 m = bits[row * 17 + kw];
        unsigned bl0 = (unsigned)(m >> c0) & 0xffu;
        unsigned bl1 = (unsigned)(m >> (32 + c0)) & 0xffu;
        f32x4 qa0 = *(const f32x4*)&Qs[k0 + c0];
        f32x4 qb0 = *(const f32x4*)&Qs[k0 + c0 + 4];
        f32x4 sa0 = *(const f32x4*)&Ss[k0 + c0];
        f32x4 sb0 = *(const f32x4*)&Ss[k0 + c0 + 4];
        f32x4 qa1 = *(const f32x4*)&Qs[k0 + 32 + c0];
        f32x4 qb1 = *(const f32x4*)&Qs[k0 + 32 + c0 + 4];
        f32x4 sa1 = *(const f32x4*)&Ss[k0 + 32 + c0];
        f32x4 sb1 = *(const f32x4*)&Ss[k0 + 32 + c0 + 4];
        short8 a0, a1;
#pragma unroll
        for (int e = 0; e < 4; ++e) {
            float v0 = ((bl0 >> e) & 1) ? fmaxf(P * qa0[e], R * sa0[e]) : 0.f;
            float v1 = ((bl0 >> (4 + e)) & 1) ? fmaxf(P * qb0[e], R * sb0[e]) : 0.f;
            float v2 = ((bl1 >> e) & 1) ? fmaxf(P * qa1[e], R * sa1[e]) : 0.f;
            float v3 = ((bl1 >> (4 + e)) & 1) ? fmaxf(P * qb1[e], R * sb1[e]) : 0.f;
            ps += (v0 + v1) + (v2 + v3);
            a0[e] = bf16s(v0);
            a0[4 + e] = bf16s(v1);
            a1[e] = bf16s(v2);
            a1[4 + e] = bf16s(v3);
        }
#pragma unroll
        for (int cf = 0; cf < 4; ++cf) {
            const __hip_bfloat16* blk = hFb + ((size_t)(kw * 4 + cf) * 2) * 512;
            short8 b0 = *(const short8*)&blk[0];
            short8 b1 = *(const short8*)&blk[512];
            acc[cf] = __builtin_amdgcn_mfma_f32_16x16x32_bf16(a0, b0, acc[cf], 0, 0, 0);
            acc[cf] = __builtin_amdgcn_mfma_f32_16x16x32_bf16(a1, b1, acc[cf], 0, 0, 0);
        }
    }
    ps += __shfl_xor(ps, 16);
    ps += __shfl_xor(ps, 32);
#pragma unroll
    for (int rr = 0; rr < 4; ++rr) {
        int rloc = g * 4 + rr;
        float dn = __shfl(ps, rloc);
        float ids = 1.0f / dn;
        int nrow = n0 + w * 16 + rloc;
#pragma unroll
        for (int cf = 0; cf < 4; ++cf) {
            float v = acc[cf][rr] * ids;
            float e = v > 0.f ? v : expm1f(v);
            float yv = e > 0.f ? e : 0.01f * e;
            ybf[((size_t)b * NN + nrow) * 512 + hd * OO + cf * 16 + r] =
                __float2bfloat16(yv);
        }
    }
}

// ---------- MFMA outproj v2: 512 thr, 16-row tiles, 8 waves x 32 cols ----------
// hoF block (b, kw, cfB, half) of 512 bf16: elem (g*16+r)*8+q holds
// ho[n = kw*64 + half*32 + g*8 + q][c = cfB*16 + r].
__global__ void k_outproj_mfma(const __hip_bfloat16* __restrict__ ybf,
                               const __hip_bfloat16* __restrict__ WoT,
                               const float* __restrict__ ao,
                               __hip_bfloat16* __restrict__ hoF,
                               float* __restrict__ g1, float* __restrict__ g2) {
    int orig = blockIdx.x;                    // 512 blocks
    int tile = (orig & 7) * 64 + (orig >> 3); // XCD swizzle: all 64 tiles of a b together
    int t = threadIdx.x, lane = t & 63, w = t >> 6;   // 8 waves
    int r0 = tile * 16;
    int b = r0 >> 10;
    __shared__ __align__(16) __hip_bfloat16 As[16][520];
    __shared__ float pg1[8][16], pg2[8][16];
    for (int e = t; e < 1024; e += 512) {
        int row = e >> 6, k8 = (e & 63) * 8;
        *(short8*)&As[row][k8] = *(const short8*)&ybf[(size_t)(r0 + row) * 512 + k8];
    }
    __syncthreads();
    int al = lane & 15, ah = lane >> 4;
    f32x4 z4 = {0.f, 0.f, 0.f, 0.f};
    f32x4 acc[2] = {z4, z4};
    for (int k0 = 0; k0 < 512; k0 += 32) {
        int k = k0 + ah * 8;
        short8 a0 = *(const short8*)&As[al][k];
#pragma unroll
        for (int cf = 0; cf < 2; ++cf) {
            int col = w * 32 + cf * 16 + al;
            short8 bf = *(const short8*)&WoT[(size_t)col * 512 + k];
            acc[cf] = __builtin_amdgcn_mfma_f32_16x16x32_bf16(a0, bf, acc[cf], 0, 0, 0);
        }
    }
    // fragment-major hoF writes + g partials
    int kw = (tile & 63) >> 2;
    int half = (tile >> 1) & 1;
    int hg0 = (tile & 1) * 2 + (ah >> 1);
    int q0 = (ah & 1) * 4;
    float q1[4] = {0.f, 0.f, 0.f, 0.f};
    float q2[4] = {0.f, 0.f, 0.f, 0.f};
#pragma unroll
    for (int cf = 0; cf < 2; ++cf) {
        int col = w * 32 + cf * 16 + al;
        int cfB = w * 2 + cf;
        float a1v = ao[col], a2v = ao[CC + col];
        size_t base = ((((size_t)b * 16 + kw) * 16 + cfB) * 2 + half) * 512;
        s16x4 v0;
#pragma unroll
        for (int r = 0; r < 4; ++r) {
            v0[r] = bf16s(acc[cf][r]);
            q1[r] += acc[cf][r] * a1v;
            q2[r] += acc[cf][r] * a2v;
        }
        *(s16x4*)&hoF[base + (hg0 * 16 + al) * 8 + q0] = v0;
    }
#pragma unroll
    for (int off = 1; off < 16; off <<= 1) {
#pragma unroll
        for (int j = 0; j < 4; ++j) {
            q1[j] += __shfl_xor(q1[j], off);
            q2[j] += __shfl_xor(q2[j], off);
        }
    }
    if (al == 0) {
#pragma unroll
        for (int j = 0; j < 4; ++j) {
            pg1[w][ah * 4 + j] = q1[j];
            pg2[w][ah * 4 + j] = q2[j];
        }
    }
    __syncthreads();
    if (t < 16) {
        float s1 = 0.f, s2 = 0.f;
#pragma unroll
        for (int ww = 0; ww < 8; ++ww) {
            s1 += pg1[ww][t];
            s2 += pg2[ww][t];
        }
        g1[r0 + t] = s1;
        g2[r0 + t] = s2;
    }
}

// ---------- FUSED out v7: 512 thr (8 waves x 32 cols), register A, LN epilogue --
__global__ void k_out_fused(const u64* __restrict__ adjbit, const float* __restrict__ g1,
                            const float* __restrict__ g2,
                            const __hip_bfloat16* __restrict__ hoF,
                            const float* __restrict__ xin, const int* __restrict__ mask,
                            const float* __restrict__ lw, const float* __restrict__ lb,
                            float* __restrict__ xout, __hip_bfloat16* __restrict__ xbfout,
                            float* __restrict__ outf, int final_) {
    int orig = blockIdx.x;                    // 512 blocks
    int wgid = (orig & 7) * 64 + (orig >> 3);
    int b = wgid >> 6;
    int n0 = (wgid & 63) * 16;
    int t = threadIdx.x, lane = t & 63, w = t >> 6;   // 8 waves
    __shared__ float Qs[1024], Ss[1024];
    __shared__ u64 bits[16 * 17];
    __shared__ float lns[8][16], lnq[8][16];
    const float* g2b = g2 + (size_t)b * NN;
    for (int j = t; j < 1024; j += 512) {
        float v = g2b[j];
        Qs[j] = __expf(v);
        Ss[j] = __expf(0.2f * v);
    }
    if (t < 256) {
        int rr = t >> 4, c = t & 15;
        bits[rr * 17 + c] = adjbit[((size_t)b * NN + n0 + rr) * 16 + c];
    }
    int g = lane >> 4, r = lane & 15;
    float gl = g1[(size_t)b * NN + n0 + r];
    float P = __expf(gl);
    float R = __expf(0.2f * gl);
    __syncthreads();
    // wave w: cols w*32..+31 (cfB = w*2+cf); every wave builds the same A rows.
    const __hip_bfloat16* hoFb = hoF + (size_t)b * 16 * 16 * 2 * 512 + lane * 8;
    f32x4 z4 = {0.f, 0.f, 0.f, 0.f};
    f32x4 acc[2] = {z4, z4};
    float ps = 0.f;
    int c0 = g * 8;
#pragma unroll 2
    for (int k0 = 0; k0 < NN; k0 += 64) {
        int kw = k0 >> 6;
        u64 m = bits[r * 17 + kw];
        unsigned bl0 = (unsigned)(m >> c0) & 0xffu;
        unsigned bl1 = (unsigned)(m >> (32 + c0)) & 0xffu;
        f32x4 qa0 = *(const f32x4*)&Qs[k0 + c0];
        f32x4 qb0 = *(const f32x4*)&Qs[k0 + c0 + 4];
        f32x4 sa0 = *(const f32x4*)&Ss[k0 + c0];
        f32x4 sb0 = *(const f32x4*)&Ss[k0 + c0 + 4];
        f32x4 qa1 = *(const f32x4*)&Qs[k0 + 32 + c0];
        f32x4 qb1 = *(const f32x4*)&Qs[k0 + 32 + c0 + 4];
        f32x4 sa1 = *(const f32x4*)&Ss[k0 + 32 + c0];
        f32x4 sb1 = *(const f32x4*)&Ss[k0 + 32 + c0 + 4];
        short8 a0, a1;
#pragma unroll
        for (int e = 0; e < 4; ++e) {
            float v0 = ((bl0 >> e) & 1) ? fmaxf(P * qa0[e], R * sa0[e]) : 0.f;
            float v1 = ((bl0 >> (4 + e)) & 1) ? fmaxf(P * qb0[e], R * sb0[e]) : 0.f;
            float v2 = ((bl1 >> e) & 1) ? fmaxf(P * qa1[e], R * sa1[e]) : 0.f;
            float v3 = ((bl1 >> (4 + e)) & 1) ? fmaxf(P * qb1[e], R * sb1[e]) : 0.f;
            ps += (v0 + v1) + (v2 + v3);
            a0[e] = bf16s(v0);
            a0[4 + e] = bf16s(v1);
            a1[e] = bf16s(v2);
            a1[4 + e] = bf16s(v3);
        }
#pragma unroll
        for (int cf = 0; cf < 2; ++cf) {
            int cfB = w * 2 + cf;
            const __hip_bfloat16* blk = hoFb + ((size_t)(kw * 16 + cfB) * 2) * 512;
            short8 b0 = *(const short8*)&blk[0];
            short8 b1 = *(const short8*)&blk[512];
            acc[cf] = __builtin_amdgcn_mfma_f32_16x16x32_bf16(a0, b0, acc[cf], 0, 0, 0);
            acc[cf] = __builtin_amdgcn_mfma_f32_16x16x32_bf16(a1, b1, acc[cf], 0, 0, 0);
        }
    }
    // rowsum: butterfly over k-groups; lane rloc holds rowsum of row rloc&15
    ps += __shfl_xor(ps, 16);
    ps += __shfl_xor(ps, 32);
    // residual + mask, collect LN stats (row spans 8 waves -> LDS reduce)
    float tv[4][2];
#pragma unroll
    for (int rr = 0; rr < 4; ++rr) {
        int rloc = g * 4 + rr;
        float dn = __shfl(ps, rloc);
        float ids = 1.0f / dn;
        int nrow = n0 + rloc;
        int mk = mask[b * NN + nrow];
        size_t rowo = ((size_t)b * NN + nrow) * CC;
        float s1 = 0.f, s2 = 0.f;
#pragma unroll
        for (int cf = 0; cf < 2; ++cf) {
            int col = w * 32 + cf * 16 + r;
            float v = acc[cf][rr] * ids;
            float e = v > 0.f ? v : expm1f(v);
            float tvv = (mk == 0) ? 0.f : (xin[rowo + col] + e);
            tv[rr][cf] = tvv;
            s1 += tvv;
            s2 += tvv * tvv;
        }
#pragma unroll
        for (int off = 1; off < 16; off <<= 1) {
            s1 += __shfl_xor(s1, off);
            s2 += __shfl_xor(s2, off);
        }
        if (r == 0) {
            lns[w][rloc] = s1;
            lnq[w][rloc] = s2;
        }
    }
    __syncthreads();
#pragma unroll
    for (int rr = 0; rr < 4; ++rr) {
        int rloc = g * 4 + rr;
        int nrow = n0 + rloc;
        size_t rowo = ((size_t)b * NN + nrow) * CC;
        float su = 0.f, sq = 0.f;
#pragma unroll
        for (int ww = 0; ww < 8; ++ww) {
            su += lns[ww][rloc];
            sq += lnq[ww][rloc];
        }
        float mu = su * (1.0f / CC);
        float var = sq * (1.0f / CC) - mu * mu;
        float rstd = rsqrtf(var + 1e-5f);
#pragma unroll
        for (int cf = 0; cf < 2; ++cf) {
            int col = w * 32 + cf * 16 + r;
            float ln = (tv[rr][cf] - mu) * rstd * lw[col] + lb[col];
            if (final_) {
                float rv = ln > 0.f ? ln : 0.f;
                outf[rowo + col] = rv;
                if (nrow == 0) outf[(size_t)BB * NN * CC + b * CC + col] = rv;
            } else {
                xout[rowo + col] = ln;
                xbfout[rowo + col] = __float2bfloat16(ln);
            }
        }
    }
}

extern "C" void kernel_launch(void* const* d_in, const int* in_sizes, int n_in,
                              void* d_out, int out_size, void* d_ws, size_t ws_size,
                              hipStream_t stream) {
    const float* x = (const float*)d_in[0];
    const int* adj = (const int*)d_in[1];
    const int* mask = (const int*)d_in[2];
    const float* W_att = (const float*)d_in[3];
    const float* a_att = (const float*)d_in[4];
    const float* W_out = (const float*)d_in[5];
    const float* a_out = (const float*)d_in[6];
    const float* ln_w = (const float*)d_in[7];
    const float* ln_b = (const float*)d_in[8];
    float* out = (float*)d_out;

    float* ws = (float*)d_ws;
    float* xbuf = ws;                          // 2,097,152 f32
    float* xbfr = xbuf + 2097152;              // 2,097,152 f32 slot (xbf)
    float* f1   = xbfr + 2097152;              // 65,536
    float* f2   = f1 + 65536;                  // 65,536
    float* g1   = f2 + 65536;                  // 8,192
    float* g2   = g1 + 8192;                   // 8,192
    float* p    = g2 + 8192;
    __hip_bfloat16* xbf = (__hip_bfloat16*)xbfr;          // 2,097,152 bf16
    __hip_bfloat16* hF  = (__hip_bfloat16*)p;             // 4,194,304 bf16 (8 MB)
    __hip_bfloat16* ybf = (__hip_bfloat16*)(p + 2097152); // 4,194,304 bf16
    __hip_bfloat16* hoF = (__hip_bfloat16*)(p + 4194304); // 2,097,152 bf16 (4 MB)
    __hip_bfloat16* WaT = (__hip_bfloat16*)(p + 5242880); // 131,072 bf16
    __hip_bfloat16* WoT = (__hip_bfloat16*)(p + 5308416); // 131,072 bf16
    u64* adjbit = (u64*)(p + 5373952);                    // 131,072 u64 (1 MB)

    k_prep<<<32768 + 8192 + 1024, 256, 0, stream>>>(adj, x, W_att, W_out,
                                                    adjbit, xbf, WaT, WoT);

    for (int layer = 0; layer < 2; ++layer) {
        const float* xin_l = layer ? xbuf : x;
        k_proj_mfma<<<dim3(128, 8), 256, 0, stream>>>(xbf, WaT, a_att, hF, f1, f2);
        k_att_fused<<<1024, 256, 0, stream>>>(adjbit, f1, f2, hF, ybf);
        k_outproj_mfma<<<512, 512, 0, stream>>>(ybf, WoT, a_out, hoF, g1, g2);
        k_out_fused<<<512, 512, 0, stream>>>(adjbit, g1, g2, hoF, xin_l, mask,
                                             ln_w, ln_b, xbuf, xbf, out, layer == 1);
    }
}